// Round 1
// baseline (1216.736 us; speedup 1.0000x reference)
//
#include <hip/hip_runtime.h>
#include <hip/hip_bf16.h>

// Linear (softmax-free) self-attention, algebraically reassociated:
//   out = x + x * [ (Wq * Wk^T) * (x^T x) * (Wv * P) ]
// Shapes: x (B=4, S=4096, D=1024); all weights D x D (row-major, (in,out)).
//
// Workspace layout (floats):
//   G  : B*D*D   (x^T x per batch)      [reused later for N]
//   U  : D*D     (Wq Wk^T)
//   W2 : D*D     (Wv P)
//   H  : B*D*D   (U G_b)
// total 10M floats = 40 MB.

#define BATCH 4
#define SEQ   4096
#define DIM   1024

// Generic tiled fp32 GEMM: C[b] = A[b] (opA) @ B[b] (opB) (+ Res[b])
//  - LDS holds As[BK][BM], Bs[BK][BN] (k-major so fragment reads are contiguous)
//  - TA: A stored K x M (use A^T);  TB: B stored N x K (use B^T)
//  - 256 threads, (BM/TM) x (BN/TN) == 256 required
template<int BM, int BN, int BK, int TM, int TN, bool TA, bool TB, bool RES>
__global__ __launch_bounds__(256)
void gemm_f32(const float* __restrict__ Ag, const float* __restrict__ Bg,
              const float* __restrict__ Resg, float* __restrict__ Cg,
              int M, int N, int K, int lda, int ldb, int ldc,
              long sA, long sB, long sC, long sRes)
{
    static_assert((BM / TM) * (BN / TN) == 256, "need 256 threads");
    __shared__ float As[BK][BM];
    __shared__ float Bs[BK][BN];

    const int b = blockIdx.z;
    const float* A  = Ag + (long)b * sA;
    const float* Bp = Bg + (long)b * sB;
    float*       C  = Cg + (long)b * sC;

    const int i0 = blockIdx.y * BM;
    const int j0 = blockIdx.x * BN;

    const int tid = threadIdx.x;
    const int ntx = BN / TN;
    const int tx = tid % ntx;
    const int ty = tid / ntx;

    float acc[TM][TN];
#pragma unroll
    for (int i = 0; i < TM; ++i)
#pragma unroll
        for (int j = 0; j < TN; ++j) acc[i][j] = 0.f;

    for (int kk = 0; kk < K; kk += BK) {
        // ---- stage A tile -> As[k][m]
        if (TA) {
            // A is K x M: tile rows kk..kk+BK, cols i0..i0+BM (already k-major)
            constexpr int iters = (BK * BM) / (256 * 4);
#pragma unroll
            for (int it = 0; it < iters; ++it) {
                int idx = (it * 256 + tid) * 4;
                int k = idx / BM, m = idx % BM;
                float4 v = *(const float4*)&A[(long)(kk + k) * lda + i0 + m];
                *(float4*)&As[k][m] = v;
            }
        } else {
            // A is M x K: load float4 along k, transpose into LDS
            constexpr int iters = (BM * BK) / (256 * 4);
#pragma unroll
            for (int it = 0; it < iters; ++it) {
                int idx = (it * 256 + tid) * 4;
                int m = idx / BK, k = idx % BK;
                float4 v = *(const float4*)&A[(long)(i0 + m) * lda + kk + k];
                As[k + 0][m] = v.x; As[k + 1][m] = v.y;
                As[k + 2][m] = v.z; As[k + 3][m] = v.w;
            }
        }
        // ---- stage B tile -> Bs[k][n]
        if (!TB) {
            constexpr int iters = (BK * BN) / (256 * 4);
#pragma unroll
            for (int it = 0; it < iters; ++it) {
                int idx = (it * 256 + tid) * 4;
                int k = idx / BN, n = idx % BN;
                float4 v = *(const float4*)&Bp[(long)(kk + k) * ldb + j0 + n];
                *(float4*)&Bs[k][n] = v;
            }
        } else {
            // B stored N x K: load along k, transpose into LDS
            constexpr int iters = (BN * BK) / (256 * 4);
#pragma unroll
            for (int it = 0; it < iters; ++it) {
                int idx = (it * 256 + tid) * 4;
                int n = idx / BK, k = idx % BK;
                float4 v = *(const float4*)&Bp[(long)(j0 + n) * ldb + kk + k];
                Bs[k + 0][n] = v.x; Bs[k + 1][n] = v.y;
                Bs[k + 2][n] = v.z; Bs[k + 3][n] = v.w;
            }
        }
        __syncthreads();

#pragma unroll
        for (int k = 0; k < BK; ++k) {
            float a[TM], bv[TN];
#pragma unroll
            for (int i = 0; i < TM; ++i) a[i] = As[k][ty * TM + i];
#pragma unroll
            for (int j = 0; j < TN; ++j) bv[j] = Bs[k][tx * TN + j];
#pragma unroll
            for (int i = 0; i < TM; ++i)
#pragma unroll
                for (int j = 0; j < TN; ++j)
                    acc[i][j] = fmaf(a[i], bv[j], acc[i][j]);
        }
        __syncthreads();
    }

    // ---- epilogue (optional residual add), float4 stores
    const float* Res = RES ? (Resg + (long)b * sRes) : nullptr;
#pragma unroll
    for (int i = 0; i < TM; ++i) {
        int r = i0 + ty * TM + i;
#pragma unroll
        for (int j = 0; j < TN; j += 4) {
            int c = j0 + tx * TN + j;
            float4 v = make_float4(acc[i][j], acc[i][j + 1], acc[i][j + 2], acc[i][j + 3]);
            if (RES) {
                float4 rv = *(const float4*)&Res[(long)r * ldc + c];
                v.x += rv.x; v.y += rv.y; v.z += rv.z; v.w += rv.w;
            }
            *(float4*)&C[(long)r * ldc + c] = v;
        }
    }
}

extern "C" void kernel_launch(void* const* d_in, const int* in_sizes, int n_in,
                              void* d_out, int out_size, void* d_ws, size_t ws_size,
                              hipStream_t stream)
{
    const float* x  = (const float*)d_in[0];
    const float* Wq = (const float*)d_in[1];
    const float* Wk = (const float*)d_in[2];
    const float* Wv = (const float*)d_in[3];
    const float* P  = (const float*)d_in[4];
    float* out = (float*)d_out;

    const long DD = (long)DIM * DIM;       // 1M
    const long SD = (long)SEQ * DIM;       // 4M

    float* G  = (float*)d_ws;              // B*DD
    float* U  = G  + BATCH * DD;           // DD
    float* W2 = U  + DD;                   // DD
    float* H  = W2 + DD;                   // B*DD
    float* Nb = G;                         // reuse G once H is built

    // 1) G_b = x_b^T x_b        (M=N=1024, K=4096)
    gemm_f32<128, 64, 16, 8, 4, true, false, false>
        <<<dim3(16, 8, BATCH), 256, 0, stream>>>(
            x, x, nullptr, G, DIM, DIM, SEQ, DIM, DIM, DIM, SD, SD, DD, 0);

    // 2) U = Wq @ Wk^T
    gemm_f32<64, 64, 16, 4, 4, false, true, false>
        <<<dim3(16, 16, 1), 256, 0, stream>>>(
            Wq, Wk, nullptr, U, DIM, DIM, DIM, DIM, DIM, DIM, 0, 0, 0, 0);

    // 3) W2 = Wv @ P
    gemm_f32<64, 64, 16, 4, 4, false, false, false>
        <<<dim3(16, 16, 1), 256, 0, stream>>>(
            Wv, P, nullptr, W2, DIM, DIM, DIM, DIM, DIM, DIM, 0, 0, 0, 0);

    // 4) H_b = U @ G_b
    gemm_f32<64, 64, 16, 4, 4, false, false, false>
        <<<dim3(16, 16, BATCH), 256, 0, stream>>>(
            U, G, nullptr, H, DIM, DIM, DIM, DIM, DIM, DIM, 0, DD, DD, 0);

    // 5) N_b = H_b @ W2   (into G's buffer)
    gemm_f32<64, 64, 16, 4, 4, false, false, false>
        <<<dim3(16, 16, BATCH), 256, 0, stream>>>(
            H, W2, nullptr, Nb, DIM, DIM, DIM, DIM, DIM, DIM, DD, 0, DD, 0);

    // 6) out_b = x_b + x_b @ N_b    (M=4096, N=K=1024)
    gemm_f32<128, 128, 16, 8, 8, false, false, true>
        <<<dim3(8, 32, BATCH), 256, 0, stream>>>(
            x, Nb, x, out, SEQ, DIM, DIM, DIM, DIM, DIM, SD, DD, SD, SD);
}

// Round 2
// 611.340 us; speedup vs baseline: 1.9903x; 1.9903x over previous
//
#include <hip/hip_runtime.h>
#include <hip/hip_bf16.h>
#include <stdint.h>

// out = x + x * [ (Wq Wk^T) * (x^T x) * (Wv P) ]
// Big GEMMs (gram: x^T x, K=4096; final: x + x@N, M=4096) in bf16 MFMA
// (m97 structure: 128x128 tile, BK=64, global_load_lds w16, linear LDS).
// D x D chain stays fp32 this round (absmax calibration).

#define BATCH 4
#define SEQ   4096
#define DIM   1024

typedef __bf16 bf16x8 __attribute__((ext_vector_type(8)));
typedef float f32x4 __attribute__((ext_vector_type(4)));

static __device__ __forceinline__ unsigned short f2bf(float f) {
    unsigned int u = __builtin_bit_cast(unsigned int, f);
    u += 0x7fff + ((u >> 16) & 1);              // RNE
    return (unsigned short)(u >> 16);
}

// ---------------------------------------------------------------------------
// bf16 MFMA GEMM: C = A @ Bt^T (+ Res), fp32 out.
//  A : M x K row-major bf16 (lda = row stride)
//  Bt: N x K row-major bf16 (ldbt)          <- B already transposed
//  256 threads = 4 waves (2x2), tile 128x128, BK=64, 16x16x32 MFMA.
// M, N multiples of 128; K multiple of 64.
// ---------------------------------------------------------------------------
template<bool RES>
__global__ __launch_bounds__(256)
void gemm_mfma(const unsigned short* __restrict__ Ag,
               const unsigned short* __restrict__ Btg,
               const float* __restrict__ Resg, float* __restrict__ Cg,
               int K, int lda, int ldbt, int ldc,
               long sA, long sBt, long sC, long sRes)
{
    __shared__ unsigned short As[128][64];
    __shared__ unsigned short Bs[128][64];

    const int b = blockIdx.z;
    const unsigned short* A  = Ag  + (long)b * sA;
    const unsigned short* Bt = Btg + (long)b * sBt;
    float* C = Cg + (long)b * sC;

    const long i0 = (long)blockIdx.y * 128;
    const long j0 = (long)blockIdx.x * 128;

    const int tid  = threadIdx.x;
    const int lane = tid & 63;
    const int w    = tid >> 6;          // wave 0..3
    const int wr   = w >> 1, wc = w & 1;
    const int lrow = lane >> 3;         // 0..7 (row within 8-row group)
    const int lcol = lane & 7;          // 0..7 (16B granule within row)
    const int fr   = lane & 15;         // fragment row/col
    const int kg   = lane >> 4;         // 0..3 k-group

    f32x4 acc[4][4] = {};

    for (int kk = 0; kk < K; kk += 64) {
        // stage A(128x64) and Bt(128x64) tiles; wave w covers rows w*32..+32
#pragma unroll
        for (int inst = 0; inst < 4; ++inst) {
            const int row = w * 32 + inst * 8;
            const unsigned short* srcA = A  + (i0 + row + lrow) * lda  + kk + lcol * 8;
            const unsigned short* srcB = Bt + (j0 + row + lrow) * ldbt + kk + lcol * 8;
            __builtin_amdgcn_global_load_lds(
                (__attribute__((address_space(1))) void*)srcA,
                (__attribute__((address_space(3))) void*)&As[row][0], 16, 0, 0);
            __builtin_amdgcn_global_load_lds(
                (__attribute__((address_space(1))) void*)srcB,
                (__attribute__((address_space(3))) void*)&Bs[row][0], 16, 0, 0);
        }
        __syncthreads();

#pragma unroll
        for (int kk2 = 0; kk2 < 2; ++kk2) {
            bf16x8 af[4], bfv[4];
#pragma unroll
            for (int m = 0; m < 4; ++m)
                af[m] = *(const bf16x8*)&As[wr * 64 + m * 16 + fr][kk2 * 32 + kg * 8];
#pragma unroll
            for (int n = 0; n < 4; ++n)
                bfv[n] = *(const bf16x8*)&Bs[wc * 64 + n * 16 + fr][kk2 * 32 + kg * 8];
#pragma unroll
            for (int m = 0; m < 4; ++m)
#pragma unroll
                for (int n = 0; n < 4; ++n)
                    acc[m][n] = __builtin_amdgcn_mfma_f32_16x16x32_bf16(
                        af[m], bfv[n], acc[m][n], 0, 0, 0);
        }
        __syncthreads();
    }

    // epilogue: C/D layout col = lane&15, row = (lane>>4)*4 + q
    const float* Res = RES ? (Resg + (long)b * sRes) : nullptr;
#pragma unroll
    for (int m = 0; m < 4; ++m) {
        const long rbase = i0 + wr * 64 + m * 16 + kg * 4;
#pragma unroll
        for (int n = 0; n < 4; ++n) {
            const long col = j0 + wc * 64 + n * 16 + fr;
#pragma unroll
            for (int q = 0; q < 4; ++q) {
                const long r = rbase + q;
                float v = acc[m][n][q];
                if (RES) v += Res[r * ldc + col];
                C[r * ldc + col] = v;
            }
        }
    }
}

// ---------------------------------------------------------------------------
// fp32 tiled GEMM for the small D x D chain (unchanged from round 1)
// ---------------------------------------------------------------------------
template<int BM, int BN, int BK, int TM, int TN, bool TA, bool TB, bool RES>
__global__ __launch_bounds__(256)
void gemm_f32(const float* __restrict__ Ag, const float* __restrict__ Bg,
              const float* __restrict__ Resg, float* __restrict__ Cg,
              int M, int N, int K, int lda, int ldb, int ldc,
              long sA, long sB, long sC, long sRes)
{
    static_assert((BM / TM) * (BN / TN) == 256, "need 256 threads");
    __shared__ float As[BK][BM];
    __shared__ float Bs[BK][BN];

    const int b = blockIdx.z;
    const float* A  = Ag + (long)b * sA;
    const float* Bp = Bg + (long)b * sB;
    float*       C  = Cg + (long)b * sC;

    const int i0 = blockIdx.y * BM;
    const int j0 = blockIdx.x * BN;

    const int tid = threadIdx.x;
    const int ntx = BN / TN;
    const int tx = tid % ntx;
    const int ty = tid / ntx;

    float acc[TM][TN];
#pragma unroll
    for (int i = 0; i < TM; ++i)
#pragma unroll
        for (int j = 0; j < TN; ++j) acc[i][j] = 0.f;

    for (int kk = 0; kk < K; kk += BK) {
        if (TA) {
            constexpr int iters = (BK * BM) / (256 * 4);
#pragma unroll
            for (int it = 0; it < iters; ++it) {
                int idx = (it * 256 + tid) * 4;
                int k = idx / BM, m = idx % BM;
                float4 v = *(const float4*)&A[(long)(kk + k) * lda + i0 + m];
                *(float4*)&As[k][m] = v;
            }
        } else {
            constexpr int iters = (BM * BK) / (256 * 4);
#pragma unroll
            for (int it = 0; it < iters; ++it) {
                int idx = (it * 256 + tid) * 4;
                int m = idx / BK, k = idx % BK;
                float4 v = *(const float4*)&A[(long)(i0 + m) * lda + kk + k];
                As[k + 0][m] = v.x; As[k + 1][m] = v.y;
                As[k + 2][m] = v.z; As[k + 3][m] = v.w;
            }
        }
        if (!TB) {
            constexpr int iters = (BK * BN) / (256 * 4);
#pragma unroll
            for (int it = 0; it < iters; ++it) {
                int idx = (it * 256 + tid) * 4;
                int k = idx / BN, n = idx % BN;
                float4 v = *(const float4*)&Bp[(long)(kk + k) * ldb + j0 + n];
                *(float4*)&Bs[k][n] = v;
            }
        } else {
            constexpr int iters = (BN * BK) / (256 * 4);
#pragma unroll
            for (int it = 0; it < iters; ++it) {
                int idx = (it * 256 + tid) * 4;
                int n = idx / BK, k = idx % BK;
                float4 v = *(const float4*)&Bp[(long)(j0 + n) * ldb + kk + k];
                Bs[k + 0][n] = v.x; Bs[k + 1][n] = v.y;
                Bs[k + 2][n] = v.z; Bs[k + 3][n] = v.w;
            }
        }
        __syncthreads();

#pragma unroll
        for (int k = 0; k < BK; ++k) {
            float a[TM], bv[TN];
#pragma unroll
            for (int i = 0; i < TM; ++i) a[i] = As[k][ty * TM + i];
#pragma unroll
            for (int j = 0; j < TN; ++j) bv[j] = Bs[k][tx * TN + j];
#pragma unroll
            for (int i = 0; i < TM; ++i)
#pragma unroll
                for (int j = 0; j < TN; ++j)
                    acc[i][j] = fmaf(a[i], bv[j], acc[i][j]);
        }
        __syncthreads();
    }

    const float* Res = RES ? (Resg + (long)b * sRes) : nullptr;
#pragma unroll
    for (int i = 0; i < TM; ++i) {
        int r = i0 + ty * TM + i;
#pragma unroll
        for (int j = 0; j < TN; j += 4) {
            int c = j0 + tx * TN + j;
            float4 v = make_float4(acc[i][j], acc[i][j + 1], acc[i][j + 2], acc[i][j + 3]);
            if (RES) {
                float4 rv = *(const float4*)&Res[(long)r * ldc + c];
                v.x += rv.x; v.y += rv.y; v.z += rv.z; v.w += rv.w;
            }
            *(float4*)&C[(long)r * ldc + c] = v;
        }
    }
}

// ---------------------------------------------------------------------------
// x (fp32, S x D) -> x_bf16 (S x D) and xT_bf16 (D x S), per batch
// ---------------------------------------------------------------------------
__global__ __launch_bounds__(256)
void transpose_cast(const float* __restrict__ x, unsigned short* __restrict__ xb,
                    unsigned short* __restrict__ xTb)
{
    __shared__ unsigned short t[32][33];
    const int b = blockIdx.z;
    const float* xp = x + (long)b * SEQ * DIM;
    unsigned short* xbp = xb + (long)b * SEQ * DIM;
    unsigned short* xTp = xTb + (long)b * SEQ * DIM;
    const int r0 = blockIdx.y * 32;           // over S
    const int c0 = blockIdx.x * 32;           // over D
    const int tx = threadIdx.x & 31;
    const int ty = threadIdx.x >> 5;
#pragma unroll
    for (int i = 0; i < 4; ++i) {
        int r = ty + i * 8;
        float v = xp[(long)(r0 + r) * DIM + c0 + tx];
        unsigned short h = f2bf(v);
        xbp[(long)(r0 + r) * DIM + c0 + tx] = h;
        t[r][tx] = h;
    }
    __syncthreads();
#pragma unroll
    for (int i = 0; i < 4; ++i) {
        int r = ty + i * 8;
        xTp[(long)(c0 + r) * SEQ + r0 + tx] = t[tx][r];
    }
}

__global__ __launch_bounds__(256)
void cast_bf16_kernel(const float* __restrict__ in, unsigned short* __restrict__ out, int n4)
{
    int i = blockIdx.x * 256 + threadIdx.x;
    if (i >= n4) return;
    float4 v = ((const float4*)in)[i];
    ushort4 o;
    o.x = f2bf(v.x); o.y = f2bf(v.y); o.z = f2bf(v.z); o.w = f2bf(v.w);
    ((ushort4*)out)[i] = o;
}

// ---------------------------------------------------------------------------
extern "C" void kernel_launch(void* const* d_in, const int* in_sizes, int n_in,
                              void* d_out, int out_size, void* d_ws, size_t ws_size,
                              hipStream_t stream)
{
    const float* x  = (const float*)d_in[0];
    const float* Wq = (const float*)d_in[1];
    const float* Wk = (const float*)d_in[2];
    const float* Wv = (const float*)d_in[3];
    const float* P  = (const float*)d_in[4];
    float* out = (float*)d_out;

    const long DD = (long)DIM * DIM;   // 1M
    const long SD = (long)SEQ * DIM;   // 4M

    // workspace layout (88 MiB total, overlaid lifetimes):
    uint8_t* ws = (uint8_t*)d_ws;
    float* G    = (float*)(ws);                               // [0,16M)  B*DD f32
    float* U    = (float*)(ws + (16u << 20));                 // [16,20M) DD f32
    float* W2   = (float*)(ws + (20u << 20));                 // [20,24M) DD f32
    unsigned short* xb  = (unsigned short*)(ws + (24u << 20)); // [24,56M) B*SD bf16
    unsigned short* xTb = (unsigned short*)(ws + (56u << 20)); // [56,88M) B*SD bf16
    float* H    = (float*)xTb;                                // overlays xTb (dead after gram)
    float* Ntf  = (float*)(ws + (72u << 20));                 // overlays xTb upper half
    unsigned short* Ntb = (unsigned short*)U;                 // overlays U+W2 (8 MB)

    // 1) x -> x_bf16, xT_bf16
    transpose_cast<<<dim3(DIM / 32, SEQ / 32, BATCH), 256, 0, stream>>>(x, xb, xTb);

    // 2) G_b = x_b^T x_b   (MFMA: A = xT, Bt = xT; M=N=1024, K=4096)
    gemm_mfma<false><<<dim3(8, 8, BATCH), 256, 0, stream>>>(
        xTb, xTb, nullptr, G, SEQ, SEQ, SEQ, DIM, SD, SD, DD, 0);

    // 3) U = Wq @ Wk^T
    gemm_f32<128, 64, 16, 8, 4, false, true, false>
        <<<dim3(16, 8, 1), 256, 0, stream>>>(
            Wq, Wk, nullptr, U, DIM, DIM, DIM, DIM, DIM, DIM, 0, 0, 0, 0);

    // 4) W2 = Wv @ P
    gemm_f32<128, 64, 16, 8, 4, false, false, false>
        <<<dim3(16, 8, 1), 256, 0, stream>>>(
            Wv, P, nullptr, W2, DIM, DIM, DIM, DIM, DIM, DIM, 0, 0, 0, 0);

    // 5) H_b = U @ G_b      (H overlays xTb region; xTb dead after gram)
    gemm_f32<128, 64, 16, 8, 4, false, false, false>
        <<<dim3(16, 8, BATCH), 256, 0, stream>>>(
            U, G, nullptr, H, DIM, DIM, DIM, DIM, DIM, DIM, 0, DD, DD, 0);

    // 6) Nt_b = W2^T @ H_b^T  ( = (H_b W2)^T )
    gemm_f32<128, 64, 16, 8, 4, true, true, false>
        <<<dim3(16, 8, BATCH), 256, 0, stream>>>(
            W2, H, nullptr, Ntf, DIM, DIM, DIM, DIM, DIM, DIM, 0, DD, DD, 0);

    // 7) Nt -> bf16
    cast_bf16_kernel<<<dim3((int)(BATCH * DD / 4 / 256)), 256, 0, stream>>>(
        Ntf, Ntb, (int)(BATCH * DD / 4));

    // 8) out_b = x_b + x_b @ N_b  (MFMA: A = x_bf16, Bt = Nt_bf16, Res = x)
    gemm_mfma<true><<<dim3(8, 32, BATCH), 256, 0, stream>>>(
        xb, Ntb, x, out, DIM, DIM, DIM, DIM, SD, DD, SD, SD);
}

// Round 3
// 251.458 us; speedup vs baseline: 4.8387x; 2.4312x over previous
//
#include <hip/hip_runtime.h>
#include <hip/hip_bf16.h>
#include <stdint.h>

// out = x + x * [ (Wq Wk^T) * (x^T x) * (Wv P) ]
// ALL GEMMs in bf16 MFMA (m97 structure: 128x128 tile, BK=64,
// global_load_lds w16, linear LDS). Intermediates written bf16 directly
// from the MFMA epilogue (no standalone cast between stages).
//
// Chain in C = A @ Bt^T form:
//   G    = xT @ xT^T              (z=4, bf16 out; G symmetric)
//   U    = Wq @ Wk^T       \  packed contiguous -> one z=2 launch
//   W2T  = Pt @ Wv^T       /   (Pt = P^T, transpose-cast)
//   H_b  = U  @ G_b^T             (z=4; uses G symmetric)
//   Nt_b = W2T @ H_b^T            (z=4)   [= (H W2)^T]
//   out  = x + xb @ Nt^T          (z=4, fp32 out + residual)

#define BATCH 4
#define SEQ   4096
#define DIM   1024

typedef __bf16 bf16x8 __attribute__((ext_vector_type(8)));
typedef float f32x4 __attribute__((ext_vector_type(4)));

static __device__ __forceinline__ unsigned short f2bf(float f) {
    unsigned int u = __builtin_bit_cast(unsigned int, f);
    u += 0x7fff + ((u >> 16) & 1);              // RNE
    return (unsigned short)(u >> 16);
}

// ---------------------------------------------------------------------------
// bf16 MFMA GEMM: C = A @ Bt^T (+ Res), out fp32 or bf16.
//  A : M x K row-major bf16 (lda);  Bt: N x K row-major bf16 (ldbt)
//  256 threads = 4 waves (2x2), tile 128x128, BK=64, 16x16x32 MFMA.
//  M, N multiples of 128; K multiple of 64.
// ---------------------------------------------------------------------------
template<bool RES, bool OUT16>
__global__ __launch_bounds__(256)
void gemm_mfma(const unsigned short* __restrict__ Ag,
               const unsigned short* __restrict__ Btg,
               const float* __restrict__ Resg, void* __restrict__ Cg,
               int K, int lda, int ldbt, int ldc,
               long sA, long sBt, long sC, long sRes)
{
    __shared__ unsigned short As[128][64];
    __shared__ unsigned short Bs[128][64];

    const int b = blockIdx.z;
    const unsigned short* A  = Ag  + (long)b * sA;
    const unsigned short* Bt = Btg + (long)b * sBt;

    const long i0 = (long)blockIdx.y * 128;
    const long j0 = (long)blockIdx.x * 128;

    const int tid  = threadIdx.x;
    const int lane = tid & 63;
    const int w    = tid >> 6;          // wave 0..3
    const int wr   = w >> 1, wc = w & 1;
    const int lrow = lane >> 3;         // 0..7
    const int lcol = lane & 7;          // 0..7 (16B granule)
    const int fr   = lane & 15;
    const int kg   = lane >> 4;         // 0..3

    f32x4 acc[4][4] = {};

    for (int kk = 0; kk < K; kk += 64) {
#pragma unroll
        for (int inst = 0; inst < 4; ++inst) {
            const int row = w * 32 + inst * 8;
            const unsigned short* srcA = A  + (i0 + row + lrow) * lda  + kk + lcol * 8;
            const unsigned short* srcB = Bt + (j0 + row + lrow) * ldbt + kk + lcol * 8;
            __builtin_amdgcn_global_load_lds(
                (__attribute__((address_space(1))) void*)srcA,
                (__attribute__((address_space(3))) void*)&As[row][0], 16, 0, 0);
            __builtin_amdgcn_global_load_lds(
                (__attribute__((address_space(1))) void*)srcB,
                (__attribute__((address_space(3))) void*)&Bs[row][0], 16, 0, 0);
        }
        __syncthreads();

#pragma unroll
        for (int kk2 = 0; kk2 < 2; ++kk2) {
            bf16x8 af[4], bfv[4];
#pragma unroll
            for (int m = 0; m < 4; ++m)
                af[m] = *(const bf16x8*)&As[wr * 64 + m * 16 + fr][kk2 * 32 + kg * 8];
#pragma unroll
            for (int n = 0; n < 4; ++n)
                bfv[n] = *(const bf16x8*)&Bs[wc * 64 + n * 16 + fr][kk2 * 32 + kg * 8];
#pragma unroll
            for (int m = 0; m < 4; ++m)
#pragma unroll
                for (int n = 0; n < 4; ++n)
                    acc[m][n] = __builtin_amdgcn_mfma_f32_16x16x32_bf16(
                        af[m], bfv[n], acc[m][n], 0, 0, 0);
        }
        __syncthreads();
    }

    // epilogue: C/D layout col = lane&15, row = (lane>>4)*4 + q
    const float* Res = RES ? (Resg + (long)b * sRes) : nullptr;
    unsigned short* C16 = OUT16 ? ((unsigned short*)Cg + (long)b * sC) : nullptr;
    float*          C32 = OUT16 ? nullptr : ((float*)Cg + (long)b * sC);
#pragma unroll
    for (int m = 0; m < 4; ++m) {
        const long rbase = i0 + wr * 64 + m * 16 + kg * 4;
#pragma unroll
        for (int n = 0; n < 4; ++n) {
            const long col = j0 + wc * 64 + n * 16 + fr;
#pragma unroll
            for (int q = 0; q < 4; ++q) {
                const long r = rbase + q;
                float v = acc[m][n][q];
                if (RES) v += Res[r * ldc + col];
                if (OUT16) C16[r * ldc + col] = f2bf(v);
                else       C32[r * ldc + col] = v;
            }
        }
    }
}

// ---------------------------------------------------------------------------
// src (fp32, R x C, batched) -> dst bf16 (R x C, optional) + dstT bf16 (C x R)
// ---------------------------------------------------------------------------
__global__ __launch_bounds__(256)
void transpose_cast(const float* __restrict__ src, unsigned short* __restrict__ dst,
                    unsigned short* __restrict__ dstT, int R, int C)
{
    __shared__ unsigned short t[32][33];
    const int b = blockIdx.z;
    const long base = (long)b * R * C;
    const int r0 = blockIdx.y * 32;
    const int c0 = blockIdx.x * 32;
    const int tx = threadIdx.x & 31;
    const int ty = threadIdx.x >> 5;
#pragma unroll
    for (int i = 0; i < 4; ++i) {
        int r = ty + i * 8;
        float v = src[base + (long)(r0 + r) * C + c0 + tx];
        unsigned short h = f2bf(v);
        if (dst) dst[base + (long)(r0 + r) * C + c0 + tx] = h;
        t[r][tx] = h;
    }
    __syncthreads();
#pragma unroll
    for (int i = 0; i < 4; ++i) {
        int r = ty + i * 8;
        dstT[base + (long)(c0 + r) * R + r0 + tx] = t[tx][r];
    }
}

// three independent fp32 -> bf16 casts (Wq, Wk, Wv), select by blockIdx.y
__global__ __launch_bounds__(256)
void cast3(const float* __restrict__ s0, const float* __restrict__ s1,
           const float* __restrict__ s2, unsigned short* __restrict__ d0,
           unsigned short* __restrict__ d1, unsigned short* __restrict__ d2, int n4)
{
    const float* s = (blockIdx.y == 0) ? s0 : (blockIdx.y == 1) ? s1 : s2;
    unsigned short* d = (blockIdx.y == 0) ? d0 : (blockIdx.y == 1) ? d1 : d2;
    int i = blockIdx.x * 256 + threadIdx.x;
    if (i >= n4) return;
    float4 v = ((const float4*)s)[i];
    ushort4 o;
    o.x = f2bf(v.x); o.y = f2bf(v.y); o.z = f2bf(v.z); o.w = f2bf(v.w);
    ((ushort4*)d)[i] = o;
}

// ---------------------------------------------------------------------------
extern "C" void kernel_launch(void* const* d_in, const int* in_sizes, int n_in,
                              void* d_out, int out_size, void* d_ws, size_t ws_size,
                              hipStream_t stream)
{
    const float* x  = (const float*)d_in[0];
    const float* Wq = (const float*)d_in[1];
    const float* Wk = (const float*)d_in[2];
    const float* Wv = (const float*)d_in[3];
    const float* P  = (const float*)d_in[4];
    float* out = (float*)d_out;

    const long DD = (long)DIM * DIM;   // 1M elements
    const long SD = (long)SEQ * DIM;   // 4M elements

    // workspace (bf16 unless noted), 84 MiB total:
    uint8_t* ws = (uint8_t*)d_ws;
    unsigned short* xb   = (unsigned short*)(ws);                 // [0,32M)  B*SD
    unsigned short* xTb  = (unsigned short*)(ws + (32ul << 20));  // [32,64M) B*SD (dead after gram)
    unsigned short* Hb   = (unsigned short*)(ws + (32ul << 20));  // overlays xTb
    unsigned short* Ntb  = (unsigned short*)(ws + (40ul << 20));  // overlays xTb
    unsigned short* Gb   = (unsigned short*)(ws + (64ul << 20));  // [64,72M) B*DD
    unsigned short* Wqb  = (unsigned short*)(ws + (72ul << 20));  // A-array: Wqb,Ptb
    unsigned short* Ptb  = (unsigned short*)(ws + (74ul << 20));
    unsigned short* Wkb  = (unsigned short*)(ws + (76ul << 20));  // Bt-array: Wkb,Wvb
    unsigned short* Wvb  = (unsigned short*)(ws + (78ul << 20));
    unsigned short* Ub   = (unsigned short*)(ws + (80ul << 20));  // C-array: Ub,W2Tb
    unsigned short* W2Tb = (unsigned short*)(ws + (82ul << 20));

    // 1) x -> xb, xTb ; P -> Pt ; Wq/Wk/Wv -> bf16
    transpose_cast<<<dim3(DIM / 32, SEQ / 32, BATCH), 256, 0, stream>>>(
        x, xb, xTb, SEQ, DIM);
    transpose_cast<<<dim3(DIM / 32, DIM / 32, 1), 256, 0, stream>>>(
        P, nullptr, Ptb, DIM, DIM);
    cast3<<<dim3((int)(DD / 4 / 256), 3), 256, 0, stream>>>(
        Wq, Wk, Wv, Wqb, Wkb, Wvb, (int)(DD / 4));

    // 2) G_b = xT_b @ xT_b^T   (M=N=1024, K=4096, bf16 out)
    gemm_mfma<false, true><<<dim3(8, 8, BATCH), 256, 0, stream>>>(
        xTb, xTb, nullptr, Gb, SEQ, SEQ, SEQ, DIM, SD, SD, DD, 0);

    // 3) {U, W2T} in one z=2 launch: U = Wq@Wk^T ; W2T = Pt@Wv^T
    gemm_mfma<false, true><<<dim3(8, 8, 2), 256, 0, stream>>>(
        Wqb, Wkb, nullptr, Ub, DIM, DIM, DIM, DIM, DD, DD, DD, 0);

    // 4) H_b = U @ G_b^T  (G symmetric => H = U@G)
    gemm_mfma<false, true><<<dim3(8, 8, BATCH), 256, 0, stream>>>(
        Ub, Gb, nullptr, Hb, DIM, DIM, DIM, DIM, 0, DD, DD, 0);

    // 5) Nt_b = W2T @ H_b^T   (= (H_b W2)^T)
    gemm_mfma<false, true><<<dim3(8, 8, BATCH), 256, 0, stream>>>(
        W2Tb, Hb, nullptr, Ntb, DIM, DIM, DIM, DIM, 0, DD, DD, 0);

    // 6) out_b = x_b + xb_b @ Nt_b^T   (fp32 out + residual)
    gemm_mfma<true, false><<<dim3(8, 32, BATCH), 256, 0, stream>>>(
        xb, Ntb, x, out, DIM, DIM, DIM, DIM, SD, DD, SD, SD);
}

// Round 4
// 231.337 us; speedup vs baseline: 5.2596x; 1.0870x over previous
//
#include <hip/hip_runtime.h>
#include <hip/hip_bf16.h>
#include <stdint.h>

// out = x + x * [ (Wq Wk^T) * (x^T x) * (Wv P) ]
// All GEMMs bf16 MFMA (m97 structure: 128xBN tile, BK=64, global_load_lds w16).
// Gram split-K (fp32 partials + reduce) for 4 blocks/CU; chain uses BN=64
// tiles for 2 blocks/CU. Fallback to smaller split if ws_size is tight.

#define BATCH 4
#define SEQ   4096
#define DIM   1024

typedef __bf16 bf16x8 __attribute__((ext_vector_type(8)));
typedef float f32x4 __attribute__((ext_vector_type(4)));

static __device__ __forceinline__ unsigned short f2bf(float f) {
    unsigned int u = __builtin_bit_cast(unsigned int, f);
    u += 0x7fff + ((u >> 16) & 1);              // RNE
    return (unsigned short)(u >> 16);
}

// ---------------------------------------------------------------------------
// bf16 MFMA GEMM: C = A @ Bt^T (+ Res).
//  A : M x K row-major bf16 (lda);  Bt: N x K row-major bf16 (ldbt)
//  256 threads = 4 waves (2x2), tile 128 x BN, BK=64, 16x16x32 MFMA.
//  OUTMODE: 0 = fp32 out, 1 = bf16 out, 2 = fp32 partial (C indexed by raw z)
//  zdiv: blockIdx.z = b*zdiv + s; split s covers k-range [s*K, (s+1)*K).
// ---------------------------------------------------------------------------
template<bool RES, int OUTMODE, int BN>
__global__ __launch_bounds__(256)
void gemm_mfma(const unsigned short* __restrict__ Ag,
               const unsigned short* __restrict__ Btg,
               const float* __restrict__ Resg, void* __restrict__ Cg,
               int K, int zdiv, int lda, int ldbt, int ldc,
               long sA, long sBt, long sC, long sRes)
{
    constexpr int NF = BN / 32;             // B fragments per wave (2 or 4)
    __shared__ unsigned short As[128][64];
    __shared__ unsigned short Bs[BN][64];

    const int z = blockIdx.z;
    const int b = z / zdiv;
    const long koff = (long)(z % zdiv) * K;
    const unsigned short* A  = Ag  + (long)b * sA  + koff;
    const unsigned short* Bt = Btg + (long)b * sBt + koff;

    const long i0 = (long)blockIdx.y * 128;
    const long j0 = (long)blockIdx.x * BN;

    const int tid  = threadIdx.x;
    const int lane = tid & 63;
    const int w    = tid >> 6;          // wave 0..3
    const int wr   = w >> 1, wc = w & 1;
    const int lrow = lane >> 3;         // 0..7
    const int lcol = lane & 7;          // 0..7 (16B granule)
    const int fr   = lane & 15;
    const int kg   = lane >> 4;         // 0..3

    f32x4 acc[4][NF] = {};

    for (int kk = 0; kk < K; kk += 64) {
#pragma unroll
        for (int inst = 0; inst < 4; ++inst) {      // A tile: 128 rows
            const int row = w * 32 + inst * 8;
            const unsigned short* srcA = A + (i0 + row + lrow) * lda + kk + lcol * 8;
            __builtin_amdgcn_global_load_lds(
                (__attribute__((address_space(1))) void*)srcA,
                (__attribute__((address_space(3))) void*)&As[row][0], 16, 0, 0);
        }
#pragma unroll
        for (int inst = 0; inst < NF; ++inst) {     // B tile: BN rows
            const int row = w * (8 * NF) + inst * 8;
            const unsigned short* srcB = Bt + (j0 + row + lrow) * ldbt + kk + lcol * 8;
            __builtin_amdgcn_global_load_lds(
                (__attribute__((address_space(1))) void*)srcB,
                (__attribute__((address_space(3))) void*)&Bs[row][0], 16, 0, 0);
        }
        __syncthreads();

#pragma unroll
        for (int kk2 = 0; kk2 < 2; ++kk2) {
            bf16x8 af[4], bfv[NF];
#pragma unroll
            for (int m = 0; m < 4; ++m)
                af[m] = *(const bf16x8*)&As[wr * 64 + m * 16 + fr][kk2 * 32 + kg * 8];
#pragma unroll
            for (int n = 0; n < NF; ++n)
                bfv[n] = *(const bf16x8*)&Bs[wc * (BN / 2) + n * 16 + fr][kk2 * 32 + kg * 8];
#pragma unroll
            for (int m = 0; m < 4; ++m)
#pragma unroll
                for (int n = 0; n < NF; ++n)
                    acc[m][n] = __builtin_amdgcn_mfma_f32_16x16x32_bf16(
                        af[m], bfv[n], acc[m][n], 0, 0, 0);
        }
        __syncthreads();
    }

    // epilogue: C/D layout col = lane&15, row = (lane>>4)*4 + q
    const float* Res = RES ? (Resg + (long)b * sRes) : nullptr;
    unsigned short* C16 = (OUTMODE == 1) ? ((unsigned short*)Cg + (long)b * sC) : nullptr;
    float*          C32 = (OUTMODE == 0) ? ((float*)Cg + (long)b * sC)
                        : (OUTMODE == 2) ? ((float*)Cg + (long)z * sC) : nullptr;
#pragma unroll
    for (int m = 0; m < 4; ++m) {
        const long rbase = i0 + wr * 64 + m * 16 + kg * 4;
#pragma unroll
        for (int n = 0; n < NF; ++n) {
            const long col = j0 + wc * (BN / 2) + n * 16 + fr;
#pragma unroll
            for (int q = 0; q < 4; ++q) {
                const long r = rbase + q;
                float v = acc[m][n][q];
                if (RES) v += Res[r * ldc + col];
                if (OUTMODE == 1) C16[r * ldc + col] = f2bf(v);
                else              C32[r * ldc + col] = v;
            }
        }
    }
}

// ---------------------------------------------------------------------------
// Gb (bf16) = cast(sum_s Gpart[b*split+s])   over B*DD elements, float4-wide
// ---------------------------------------------------------------------------
__global__ __launch_bounds__(256)
void reduce_cast(const float* __restrict__ part, unsigned short* __restrict__ outG,
                 int split)
{
    const long q = (long)DIM * DIM / 4;
    long i = (long)blockIdx.x * 256 + threadIdx.x;   // over B*DD/4
    if (i >= (long)BATCH * q) return;
    long b = i / q, r = i % q;
    float4 s = make_float4(0.f, 0.f, 0.f, 0.f);
    for (int sp = 0; sp < split; ++sp) {
        float4 v = ((const float4*)part)[(b * split + sp) * q + r];
        s.x += v.x; s.y += v.y; s.z += v.z; s.w += v.w;
    }
    ushort4 o;
    o.x = f2bf(s.x); o.y = f2bf(s.y); o.z = f2bf(s.z); o.w = f2bf(s.w);
    ((ushort4*)outG)[i] = o;
}

// ---------------------------------------------------------------------------
// src (fp32, R x C, batched) -> dst bf16 (optional) + dstT bf16 (C x R)
// fully float4/ushort4 vectorized; 32x32 tiles.
// ---------------------------------------------------------------------------
__global__ __launch_bounds__(256)
void transpose_cast(const float* __restrict__ src, unsigned short* __restrict__ dst,
                    unsigned short* __restrict__ dstT, int R, int C)
{
    __shared__ unsigned short t[32][33];
    const int b = blockIdx.z;
    const long base = (long)b * R * C;
    const int r0 = blockIdx.y * 32;
    const int c0 = blockIdx.x * 32;
    const int row = threadIdx.x >> 3;        // 0..31
    const int cid = threadIdx.x & 7;         // 0..7 (float4 granule)

    float4 v = *(const float4*)&src[base + (long)(r0 + row) * C + c0 + cid * 4];
    ushort4 h;
    h.x = f2bf(v.x); h.y = f2bf(v.y); h.z = f2bf(v.z); h.w = f2bf(v.w);
    if (dst) *(ushort4*)&dst[base + (long)(r0 + row) * C + c0 + cid * 4] = h;
    t[row][cid * 4 + 0] = h.x; t[row][cid * 4 + 1] = h.y;
    t[row][cid * 4 + 2] = h.z; t[row][cid * 4 + 3] = h.w;
    __syncthreads();

    ushort4 o;
    o.x = t[cid * 4 + 0][row];
    o.y = t[cid * 4 + 1][row];
    o.z = t[cid * 4 + 2][row];
    o.w = t[cid * 4 + 3][row];
    *(ushort4*)&dstT[base + (long)(c0 + row) * R + r0 + cid * 4] = o;
}

// three independent fp32 -> bf16 casts (Wq, Wk, Wv), select by blockIdx.y
__global__ __launch_bounds__(256)
void cast3(const float* __restrict__ s0, const float* __restrict__ s1,
           const float* __restrict__ s2, unsigned short* __restrict__ d0,
           unsigned short* __restrict__ d1, unsigned short* __restrict__ d2, int n4)
{
    const float* s = (blockIdx.y == 0) ? s0 : (blockIdx.y == 1) ? s1 : s2;
    unsigned short* d = (blockIdx.y == 0) ? d0 : (blockIdx.y == 1) ? d1 : d2;
    int i = blockIdx.x * 256 + threadIdx.x;
    if (i >= n4) return;
    float4 v = ((const float4*)s)[i];
    ushort4 o;
    o.x = f2bf(v.x); o.y = f2bf(v.y); o.z = f2bf(v.z); o.w = f2bf(v.w);
    ((ushort4*)d)[i] = o;
}

// ---------------------------------------------------------------------------
extern "C" void kernel_launch(void* const* d_in, const int* in_sizes, int n_in,
                              void* d_out, int out_size, void* d_ws, size_t ws_size,
                              hipStream_t stream)
{
    const float* x  = (const float*)d_in[0];
    const float* Wq = (const float*)d_in[1];
    const float* Wk = (const float*)d_in[2];
    const float* Wv = (const float*)d_in[3];
    const float* P  = (const float*)d_in[4];
    float* out = (float*)d_out;

    const long DD = (long)DIM * DIM;   // 1M elements
    const long SD = (long)SEQ * DIM;   // 4M elements

    // workspace layout:
    //   [0,32M)   xb   bf16 B*SD
    //   [32,64M)  xTb  bf16 B*SD (dead after gram) -> Hb [32,40), Ntb [40,48)
    //   [64,72M)  Gb   bf16 B*DD
    //   [72,84M)  Wqb,Ptb | Wkb,Wvb | Ub,W2Tb  (2 MB each)
    //   [84,84+split*16M)  Gpart fp32 (gram split-K partials)
    uint8_t* ws = (uint8_t*)d_ws;
    unsigned short* xb   = (unsigned short*)(ws);
    unsigned short* xTb  = (unsigned short*)(ws + (32ul << 20));
    unsigned short* Hb   = (unsigned short*)(ws + (32ul << 20));
    unsigned short* Ntb  = (unsigned short*)(ws + (40ul << 20));
    unsigned short* Gb   = (unsigned short*)(ws + (64ul << 20));
    unsigned short* Wqb  = (unsigned short*)(ws + (72ul << 20));
    unsigned short* Ptb  = (unsigned short*)(ws + (74ul << 20));
    unsigned short* Wkb  = (unsigned short*)(ws + (76ul << 20));
    unsigned short* Wvb  = (unsigned short*)(ws + (78ul << 20));
    unsigned short* Ub   = (unsigned short*)(ws + (80ul << 20));
    unsigned short* W2Tb = (unsigned short*)(ws + (82ul << 20));
    float*          Gpart = (float*)(ws + (84ul << 20));

    const int split = (ws_size >= (148ul << 20)) ? 4
                    : (ws_size >= (116ul << 20)) ? 2 : 1;

    // 1) x -> xb, xTb ; P -> Pt ; Wq/Wk/Wv -> bf16
    transpose_cast<<<dim3(DIM / 32, SEQ / 32, BATCH), 256, 0, stream>>>(
        x, xb, xTb, SEQ, DIM);
    transpose_cast<<<dim3(DIM / 32, DIM / 32, 1), 256, 0, stream>>>(
        P, nullptr, Ptb, DIM, DIM);
    cast3<<<dim3((int)(DD / 4 / 256), 3), 256, 0, stream>>>(
        Wq, Wk, Wv, Wqb, Wkb, Wvb, (int)(DD / 4));

    // 2) G_b = xT_b @ xT_b^T   (M=N=1024, K=4096) with split-K when ws allows
    if (split > 1) {
        gemm_mfma<false, 2, 128><<<dim3(8, 8, BATCH * split), 256, 0, stream>>>(
            xTb, xTb, nullptr, Gpart, SEQ / split, split, SEQ, SEQ, DIM,
            SD, SD, DD, 0);
        reduce_cast<<<dim3((int)(BATCH * DD / 4 / 256)), 256, 0, stream>>>(
            Gpart, Gb, split);
    } else {
        gemm_mfma<false, 1, 128><<<dim3(8, 8, BATCH), 256, 0, stream>>>(
            xTb, xTb, nullptr, Gb, SEQ, 1, SEQ, SEQ, DIM, SD, SD, DD, 0);
    }

    // 3) {U, W2T} in one z=2 launch: U = Wq@Wk^T ; W2T = Pt@Wv^T   (BN=64)
    gemm_mfma<false, 1, 64><<<dim3(16, 8, 2), 256, 0, stream>>>(
        Wqb, Wkb, nullptr, Ub, DIM, 1, DIM, DIM, DIM, DD, DD, DD, 0);

    // 4) H_b = U @ G_b^T  (G symmetric => H = U@G)   (BN=64)
    gemm_mfma<false, 1, 64><<<dim3(16, 8, BATCH), 256, 0, stream>>>(
        Ub, Gb, nullptr, Hb, DIM, 1, DIM, DIM, DIM, 0, DD, DD, 0);

    // 5) Nt_b = W2T @ H_b^T   (= (H_b W2)^T)   (BN=64)
    gemm_mfma<false, 1, 64><<<dim3(16, 8, BATCH), 256, 0, stream>>>(
        W2Tb, Hb, nullptr, Ntb, DIM, 1, DIM, DIM, DIM, 0, DD, DD, 0);

    // 6) out_b = x_b + xb_b @ Nt_b^T   (fp32 out + residual)
    gemm_mfma<true, 0, 128><<<dim3(8, 32, BATCH), 256, 0, stream>>>(
        xb, Ntb, x, out, DIM, 1, DIM, DIM, DIM, SD, DD, SD, SD);
}

// Round 5
// 212.621 us; speedup vs baseline: 5.7226x; 1.0880x over previous
//
#include <hip/hip_runtime.h>
#include <hip/hip_bf16.h>
#include <stdint.h>

// out = x + x * [ (Wq Wk^T) * (x^T x) * (Wv P) ]
// All GEMMs bf16 MFMA (m97 structure: 128xBN tile, BK=64, global_load_lds w16).
// This round: triangular (symmetric) gram + XCD-chunk block swizzle (T1) in
// every GEMM launch + bf16 residual read in the final GEMM.

#define BATCH 4
#define SEQ   4096
#define DIM   1024

typedef __bf16 bf16x8 __attribute__((ext_vector_type(8)));
typedef float f32x4 __attribute__((ext_vector_type(4)));

static __device__ __forceinline__ unsigned short f2bf(float f) {
    unsigned int u = __builtin_bit_cast(unsigned int, f);
    u += 0x7fff + ((u >> 16) & 1);              // RNE
    return (unsigned short)(u >> 16);
}
static __device__ __forceinline__ float bf2f(unsigned short h) {
    unsigned int u = (unsigned int)h << 16;
    return __builtin_bit_cast(float, u);
}

// ---------------------------------------------------------------------------
// bf16 MFMA GEMM: C = A @ Bt^T (+ Res, bf16).
//  A : M x K row-major bf16 (lda);  Bt: N x K row-major bf16 (ldbt)
//  256 threads = 4 waves (2x2), tile 128 x BN, BK=64, 16x16x32 MFMA.
//  OUTMODE: 0 = fp32 out, 1 = bf16 out, 2 = fp32 partial (C indexed by raw z)
//  TRI: 1-D grid of 36 lower-triangle 128x128 tile pairs per z (BN must be 128).
//  zdiv: z = b*zdiv + s; split s covers k-range [s*K, (s+1)*K).
//  ALL grids must have nwg % 8 == 0 (XCD-chunk swizzle).
// ---------------------------------------------------------------------------
template<bool RES, int OUTMODE, int BN, bool TRI>
__global__ __launch_bounds__(256)
void gemm_mfma(const unsigned short* __restrict__ Ag,
               const unsigned short* __restrict__ Btg,
               const unsigned short* __restrict__ Resg, void* __restrict__ Cg,
               int K, int zdiv, int lda, int ldbt, int ldc,
               long sA, long sBt, long sC, long sRes)
{
    constexpr int NF = BN / 32;             // B fragments per wave (2 or 4)
    __shared__ unsigned short As[128][64];
    __shared__ unsigned short Bs[BN][64];

    // ---- XCD-chunk bijective swizzle over the whole grid (nwg % 8 == 0)
    const int gx = gridDim.x, gy = gridDim.y;
    const int nwg = gx * gy * gridDim.z;
    int id = blockIdx.x + gx * (blockIdx.y + gy * blockIdx.z);
    id = (id & 7) * (nwg >> 3) + (id >> 3);

    int z;
    long i0, j0;
    if (TRI) {
        z = id / 36;
        int t = id % 36;
        int ti = 0;
        while (t > ti) { t -= ti + 1; ++ti; }
        i0 = (long)ti * 128;                // row tile
        j0 = (long)t * 128;                 // col tile (t <= ti)
    } else {
        const int bx = id % gx;
        const int rest = id / gx;
        const int by = rest % gy;
        z = rest / gy;
        i0 = (long)by * 128;
        j0 = (long)bx * BN;
    }
    const int b = z / zdiv;
    const long koff = (long)(z % zdiv) * K;

    const unsigned short* A  = Ag  + (long)b * sA  + koff;
    const unsigned short* Bt = Btg + (long)b * sBt + koff;

    const int tid  = threadIdx.x;
    const int lane = tid & 63;
    const int w    = tid >> 6;          // wave 0..3
    const int wr   = w >> 1, wc = w & 1;
    const int lrow = lane >> 3;         // 0..7
    const int lcol = lane & 7;          // 0..7 (16B granule)
    const int fr   = lane & 15;
    const int kg   = lane >> 4;         // 0..3

    f32x4 acc[4][NF] = {};

    for (int kk = 0; kk < K; kk += 64) {
#pragma unroll
        for (int inst = 0; inst < 4; ++inst) {      // A tile: 128 rows
            const int row = w * 32 + inst * 8;
            const unsigned short* srcA = A + (i0 + row + lrow) * lda + kk + lcol * 8;
            __builtin_amdgcn_global_load_lds(
                (__attribute__((address_space(1))) void*)srcA,
                (__attribute__((address_space(3))) void*)&As[row][0], 16, 0, 0);
        }
#pragma unroll
        for (int inst = 0; inst < NF; ++inst) {     // B tile: BN rows
            const int row = w * (8 * NF) + inst * 8;
            const unsigned short* srcB = Bt + (j0 + row + lrow) * ldbt + kk + lcol * 8;
            __builtin_amdgcn_global_load_lds(
                (__attribute__((address_space(1))) void*)srcB,
                (__attribute__((address_space(3))) void*)&Bs[row][0], 16, 0, 0);
        }
        __syncthreads();

#pragma unroll
        for (int kk2 = 0; kk2 < 2; ++kk2) {
            bf16x8 af[4], bfv[NF];
#pragma unroll
            for (int m = 0; m < 4; ++m)
                af[m] = *(const bf16x8*)&As[wr * 64 + m * 16 + fr][kk2 * 32 + kg * 8];
#pragma unroll
            for (int n = 0; n < NF; ++n)
                bfv[n] = *(const bf16x8*)&Bs[wc * (BN / 2) + n * 16 + fr][kk2 * 32 + kg * 8];
#pragma unroll
            for (int m = 0; m < 4; ++m)
#pragma unroll
                for (int n = 0; n < NF; ++n)
                    acc[m][n] = __builtin_amdgcn_mfma_f32_16x16x32_bf16(
                        af[m], bfv[n], acc[m][n], 0, 0, 0);
        }
        __syncthreads();
    }

    // epilogue: C/D layout col = lane&15, row = (lane>>4)*4 + q
    const unsigned short* Res = RES ? (Resg + (long)b * sRes) : nullptr;
    unsigned short* C16 = (OUTMODE == 1) ? ((unsigned short*)Cg + (long)b * sC) : nullptr;
    float*          C32 = (OUTMODE == 0) ? ((float*)Cg + (long)b * sC)
                        : (OUTMODE == 2) ? ((float*)Cg + (long)z * sC) : nullptr;
#pragma unroll
    for (int m = 0; m < 4; ++m) {
        const long rbase = i0 + wr * 64 + m * 16 + kg * 4;
#pragma unroll
        for (int n = 0; n < NF; ++n) {
            const long col = j0 + wc * (BN / 2) + n * 16 + fr;
#pragma unroll
            for (int q = 0; q < 4; ++q) {
                const long r = rbase + q;
                float v = acc[m][n][q];
                if (RES) v += bf2f(Res[r * ldc + col]);
                if (OUTMODE == 1) C16[r * ldc + col] = f2bf(v);
                else              C32[r * ldc + col] = v;
            }
        }
    }
}

// ---------------------------------------------------------------------------
// Reduce split-K fp32 partials over the 36 lower-triangle tiles -> bf16 G.
// Exactly BATCH*36*128*128/4 float4 threads; grid = that / 256 = 2304.
// ---------------------------------------------------------------------------
__global__ __launch_bounds__(256)
void reduce_cast_tri(const float* __restrict__ part, unsigned short* __restrict__ outG,
                     int split)
{
    const long DD = (long)DIM * DIM;
    int id = blockIdx.x * 256 + threadIdx.x;
    const int b  = id / 147456;          // 36*128*32
    int rem      = id % 147456;
    int t        = rem / 4096;           // tile index 0..35
    const int rr = rem % 4096;
    const int r  = rr >> 5;
    const int c4 = rr & 31;
    int ti = 0;
    while (t > ti) { t -= ti + 1; ++ti; }
    const long row = (long)ti * 128 + r;
    const long col = (long)t * 128 + c4 * 4;
    const long off = row * DIM + col;

    float4 s = make_float4(0.f, 0.f, 0.f, 0.f);
    for (int sp = 0; sp < split; ++sp) {
        float4 v = *(const float4*)&part[(long)(b * split + sp) * DD + off];
        s.x += v.x; s.y += v.y; s.z += v.z; s.w += v.w;
    }
    ushort4 o;
    o.x = f2bf(s.x); o.y = f2bf(s.y); o.z = f2bf(s.z); o.w = f2bf(s.w);
    *(ushort4*)&outG[b * DD + off] = o;
}

// ---------------------------------------------------------------------------
// Mirror the 28 strict-upper 128x128 tiles of symmetric G from the lower ones.
// grid = (16 subtiles, 28 tiles, BATCH); 32x32 LDS transpose, ushort4 I/O.
// ---------------------------------------------------------------------------
__global__ __launch_bounds__(256)
void sym_mirror(unsigned short* __restrict__ G)
{
    __shared__ unsigned short t[32][36];
    const long DD = (long)DIM * DIM;
    unsigned short* Gb = G + (long)blockIdx.z * DD;

    int u = blockIdx.y;                  // strict-upper pair index 0..27
    int tj = 1;
    while (u >= tj) { u -= tj; ++tj; }
    const int ti = u;                    // ti < tj

    const int sr = blockIdx.x >> 2;      // 0..3 (32-row strip in source tile)
    const int sc = blockIdx.x & 3;       // 0..3 (32-col strip in source tile)
    const int row = threadIdx.x >> 3;    // 0..31
    const int cid = threadIdx.x & 7;     // 0..7

    // source = lower tile (tj, ti)
    const long srow = (long)tj * 128 + sr * 32 + row;
    const long scol = (long)ti * 128 + sc * 32 + cid * 4;
    ushort4 v = *(const ushort4*)&Gb[srow * DIM + scol];
    t[row][cid * 4 + 0] = v.x; t[row][cid * 4 + 1] = v.y;
    t[row][cid * 4 + 2] = v.z; t[row][cid * 4 + 3] = v.w;
    __syncthreads();

    // dest = upper tile (ti, tj), transposed
    const long drow = (long)ti * 128 + sc * 32 + row;
    const long dcol = (long)tj * 128 + sr * 32 + cid * 4;
    ushort4 o;
    o.x = t[cid * 4 + 0][row];
    o.y = t[cid * 4 + 1][row];
    o.z = t[cid * 4 + 2][row];
    o.w = t[cid * 4 + 3][row];
    *(ushort4*)&Gb[drow * DIM + dcol] = o;
}

// ---------------------------------------------------------------------------
// src (fp32, R x C, batched) -> dst bf16 (optional) + dstT bf16 (C x R)
// ---------------------------------------------------------------------------
__global__ __launch_bounds__(256)
void transpose_cast(const float* __restrict__ src, unsigned short* __restrict__ dst,
                    unsigned short* __restrict__ dstT, int R, int C)
{
    __shared__ unsigned short t[32][33];
    const int b = blockIdx.z;
    const long base = (long)b * R * C;
    const int r0 = blockIdx.y * 32;
    const int c0 = blockIdx.x * 32;
    const int row = threadIdx.x >> 3;        // 0..31
    const int cid = threadIdx.x & 7;         // 0..7 (float4 granule)

    float4 v = *(const float4*)&src[base + (long)(r0 + row) * C + c0 + cid * 4];
    ushort4 h;
    h.x = f2bf(v.x); h.y = f2bf(v.y); h.z = f2bf(v.z); h.w = f2bf(v.w);
    if (dst) *(ushort4*)&dst[base + (long)(r0 + row) * C + c0 + cid * 4] = h;
    t[row][cid * 4 + 0] = h.x; t[row][cid * 4 + 1] = h.y;
    t[row][cid * 4 + 2] = h.z; t[row][cid * 4 + 3] = h.w;
    __syncthreads();

    ushort4 o;
    o.x = t[cid * 4 + 0][row];
    o.y = t[cid * 4 + 1][row];
    o.z = t[cid * 4 + 2][row];
    o.w = t[cid * 4 + 3][row];
    *(ushort4*)&dstT[base + (long)(c0 + row) * R + r0 + cid * 4] = o;
}

// three independent fp32 -> bf16 casts (Wq, Wk, Wv), select by blockIdx.y
__global__ __launch_bounds__(256)
void cast3(const float* __restrict__ s0, const float* __restrict__ s1,
           const float* __restrict__ s2, unsigned short* __restrict__ d0,
           unsigned short* __restrict__ d1, unsigned short* __restrict__ d2, int n4)
{
    const float* s = (blockIdx.y == 0) ? s0 : (blockIdx.y == 1) ? s1 : s2;
    unsigned short* d = (blockIdx.y == 0) ? d0 : (blockIdx.y == 1) ? d1 : d2;
    int i = blockIdx.x * 256 + threadIdx.x;
    if (i >= n4) return;
    float4 v = ((const float4*)s)[i];
    ushort4 o;
    o.x = f2bf(v.x); o.y = f2bf(v.y); o.z = f2bf(v.z); o.w = f2bf(v.w);
    ((ushort4*)d)[i] = o;
}

// ---------------------------------------------------------------------------
extern "C" void kernel_launch(void* const* d_in, const int* in_sizes, int n_in,
                              void* d_out, int out_size, void* d_ws, size_t ws_size,
                              hipStream_t stream)
{
    const float* x  = (const float*)d_in[0];
    const float* Wq = (const float*)d_in[1];
    const float* Wk = (const float*)d_in[2];
    const float* Wv = (const float*)d_in[3];
    const float* P  = (const float*)d_in[4];
    float* out = (float*)d_out;

    const long DD = (long)DIM * DIM;   // 1M elements
    const long SD = (long)SEQ * DIM;   // 4M elements

    // workspace layout:
    //   [0,32M)   xb   bf16 B*SD
    //   [32,64M)  xTb  bf16 B*SD (dead after gram) -> Hb [32,40), Ntb [40,48)
    //   [64,72M)  Gb   bf16 B*DD
    //   [72,84M)  Wqb,Ptb | Wkb,Wvb | Ub,W2Tb  (2 MB each)
    //   [84,84+split*16M)  Gpart fp32 (gram split-K partials, lower tiles only)
    uint8_t* ws = (uint8_t*)d_ws;
    unsigned short* xb   = (unsigned short*)(ws);
    unsigned short* xTb  = (unsigned short*)(ws + (32ul << 20));
    unsigned short* Hb   = (unsigned short*)(ws + (32ul << 20));
    unsigned short* Ntb  = (unsigned short*)(ws + (40ul << 20));
    unsigned short* Gb   = (unsigned short*)(ws + (64ul << 20));
    unsigned short* Wqb  = (unsigned short*)(ws + (72ul << 20));
    unsigned short* Ptb  = (unsigned short*)(ws + (74ul << 20));
    unsigned short* Wkb  = (unsigned short*)(ws + (76ul << 20));
    unsigned short* Wvb  = (unsigned short*)(ws + (78ul << 20));
    unsigned short* Ub   = (unsigned short*)(ws + (80ul << 20));
    unsigned short* W2Tb = (unsigned short*)(ws + (82ul << 20));
    float*          Gpart = (float*)(ws + (84ul << 20));

    const int split = (ws_size >= (148ul << 20)) ? 4
                    : (ws_size >= (116ul << 20)) ? 2 : 1;

    // 1) x -> xb, xTb ; P -> Pt ; Wq/Wk/Wv -> bf16
    transpose_cast<<<dim3(DIM / 32, SEQ / 32, BATCH), 256, 0, stream>>>(
        x, xb, xTb, SEQ, DIM);
    transpose_cast<<<dim3(DIM / 32, DIM / 32, 1), 256, 0, stream>>>(
        P, nullptr, Ptb, DIM, DIM);
    cast3<<<dim3((int)(DD / 4 / 256), 3), 256, 0, stream>>>(
        Wq, Wk, Wv, Wqb, Wkb, Wvb, (int)(DD / 4));

    // 2) G_b = xT_b @ xT_b^T  — lower-triangle tiles only, split-K partials
    gemm_mfma<false, 2, 128, true>
        <<<dim3(36 * split * BATCH, 1, 1), 256, 0, stream>>>(
            xTb, xTb, nullptr, Gpart, SEQ / split, split, SEQ, SEQ, DIM,
            SD, SD, DD, 0);
    reduce_cast_tri<<<dim3(BATCH * 36 * 128 * 32 / 256), 256, 0, stream>>>(
        Gpart, Gb, split);
    sym_mirror<<<dim3(16, 28, BATCH), 256, 0, stream>>>(Gb);

    // 3) {U, W2T} in one z=2 launch: U = Wq@Wk^T ; W2T = Pt@Wv^T   (BN=64)
    gemm_mfma<false, 1, 64, false><<<dim3(16, 8, 2), 256, 0, stream>>>(
        Wqb, Wkb, nullptr, Ub, DIM, 1, DIM, DIM, DIM, DD, DD, DD, 0);

    // 4) H_b = U @ G_b^T  (G symmetric => H = U@G)   (BN=64)
    gemm_mfma<false, 1, 64, false><<<dim3(16, 8, BATCH), 256, 0, stream>>>(
        Ub, Gb, nullptr, Hb, DIM, 1, DIM, DIM, DIM, 0, DD, DD, 0);

    // 5) Nt_b = W2T @ H_b^T   (= (H_b W2)^T)   (BN=64)
    gemm_mfma<false, 1, 64, false><<<dim3(16, 8, BATCH), 256, 0, stream>>>(
        W2Tb, Hb, nullptr, Ntb, DIM, 1, DIM, DIM, DIM, 0, DD, DD, 0);

    // 6) out_b = x_b + xb_b @ Nt_b^T  (fp32 out, bf16 residual from xb)
    gemm_mfma<true, 0, 128, false><<<dim3(8, 32, BATCH), 256, 0, stream>>>(
        xb, Ntb, xb, out, DIM, 1, DIM, DIM, DIM, SD, DD, SD, SD);
}

// Round 7
// 209.553 us; speedup vs baseline: 5.8063x; 1.0146x over previous
//
#include <hip/hip_runtime.h>
#include <hip/hip_bf16.h>
#include <stdint.h>

// out = x + x * [ (Wq Wk^T) * (x^T x) * (Wv P) ]  ==  x @ (I + N),  N = U G W2
// All GEMMs bf16 MFMA (m97 structure: 128xBN tile, BK=64, global_load_lds w16,
// XCD-chunk swizzle). Gram = triangular + split-K, COMPACT fp32 partials in a
// SINGLE region (no aliasing with live buffers — round-6 bug was partials
// overlapping xTb). Residual folded into Nt's diagonal.

#define BATCH 4
#define SEQ   4096
#define DIM   1024

#define TRI_SLICE 589824l       // 36 tiles * 128*128 floats per gram slice

typedef __bf16 bf16x8 __attribute__((ext_vector_type(8)));
typedef float f32x4 __attribute__((ext_vector_type(4)));

static __device__ __forceinline__ unsigned short f2bf(float f) {
    unsigned int u = __builtin_bit_cast(unsigned int, f);
    u += 0x7fff + ((u >> 16) & 1);              // RNE
    return (unsigned short)(u >> 16);
}

// ---------------------------------------------------------------------------
// bf16 MFMA GEMM: C = A @ Bt^T.
//  A : M x K row-major bf16 (lda);  Bt: N x K row-major bf16 (ldbt)
//  256 threads = 4 waves (2x2), tile 128 x BN, BK=64, 16x16x32 MFMA.
//  OUTMODE: 0 = fp32 out (Cg + b*sC)
//           1 = bf16 out (Cg + b*sC), optional identity add (ADD_I)
//           2 = fp32 partial, slice-indexed (Cg + z*sC)
//           3 = TRI compact fp32 partial (Cg + z*TRI_SLICE + tile*16384)
//  TRI: 1-D grid of 36 lower-triangle 128x128 tiles per z (BN must be 128).
//  zdiv: z = b*zdiv + s; split s covers k-range [s*K, (s+1)*K).
//  ALL grids must have nwg % 8 == 0 (XCD-chunk swizzle).
// ---------------------------------------------------------------------------
template<int OUTMODE, int BN, bool TRI, bool ADD_I>
__global__ __launch_bounds__(256)
void gemm_mfma(const unsigned short* __restrict__ Ag,
               const unsigned short* __restrict__ Btg,
               void* __restrict__ Cg,
               int K, int zdiv, int lda, int ldbt, int ldc,
               long sA, long sBt, long sC)
{
    constexpr int NF = BN / 32;             // B fragments per wave (2 or 4)
    __shared__ unsigned short As[128][64];
    __shared__ unsigned short Bs[BN][64];

    // ---- XCD-chunk bijective swizzle over the whole grid (nwg % 8 == 0)
    const int gx = gridDim.x, gy = gridDim.y;
    const int nwg = gx * gy * gridDim.z;
    int id = blockIdx.x + gx * (blockIdx.y + gy * blockIdx.z);
    id = (id & 7) * (nwg >> 3) + (id >> 3);

    int z, tlin = 0;
    long i0, j0;
    if (TRI) {
        z = id / 36;
        tlin = id % 36;
        int t = tlin, ti = 0;
        while (t > ti) { t -= ti + 1; ++ti; }
        i0 = (long)ti * 128;                // row tile
        j0 = (long)t * 128;                 // col tile (t <= ti)
    } else {
        const int bx = id % gx;
        const int rest = id / gx;
        const int by = rest % gy;
        z = rest / gy;
        i0 = (long)by * 128;
        j0 = (long)bx * BN;
    }
    const int b = z / zdiv;
    const long koff = (long)(z % zdiv) * K;

    const unsigned short* A  = Ag  + (long)b * sA  + koff;
    const unsigned short* Bt = Btg + (long)b * sBt + koff;

    const int tid  = threadIdx.x;
    const int lane = tid & 63;
    const int w    = tid >> 6;          // wave 0..3
    const int wr   = w >> 1, wc = w & 1;
    const int lrow = lane >> 3;         // 0..7
    const int lcol = lane & 7;          // 0..7 (16B granule)
    const int fr   = lane & 15;
    const int kg   = lane >> 4;         // 0..3

    f32x4 acc[4][NF] = {};

    for (int kk = 0; kk < K; kk += 64) {
#pragma unroll
        for (int inst = 0; inst < 4; ++inst) {      // A tile: 128 rows
            const int row = w * 32 + inst * 8;
            const unsigned short* srcA = A + (i0 + row + lrow) * lda + kk + lcol * 8;
            __builtin_amdgcn_global_load_lds(
                (__attribute__((address_space(1))) void*)srcA,
                (__attribute__((address_space(3))) void*)&As[row][0], 16, 0, 0);
        }
#pragma unroll
        for (int inst = 0; inst < NF; ++inst) {     // B tile: BN rows
            const int row = w * (8 * NF) + inst * 8;
            const unsigned short* srcB = Bt + (j0 + row + lrow) * ldbt + kk + lcol * 8;
            __builtin_amdgcn_global_load_lds(
                (__attribute__((address_space(1))) void*)srcB,
                (__attribute__((address_space(3))) void*)&Bs[row][0], 16, 0, 0);
        }
        __syncthreads();

#pragma unroll
        for (int kk2 = 0; kk2 < 2; ++kk2) {
            bf16x8 af[4], bfv[NF];
#pragma unroll
            for (int m = 0; m < 4; ++m)
                af[m] = *(const bf16x8*)&As[wr * 64 + m * 16 + fr][kk2 * 32 + kg * 8];
#pragma unroll
            for (int n = 0; n < NF; ++n)
                bfv[n] = *(const bf16x8*)&Bs[wc * (BN / 2) + n * 16 + fr][kk2 * 32 + kg * 8];
#pragma unroll
            for (int m = 0; m < 4; ++m)
#pragma unroll
                for (int n = 0; n < NF; ++n)
                    acc[m][n] = __builtin_amdgcn_mfma_f32_16x16x32_bf16(
                        af[m], bfv[n], acc[m][n], 0, 0, 0);
        }
        __syncthreads();
    }

    // epilogue: C/D layout col = lane&15, row = (lane>>4)*4 + q
    if (OUTMODE == 3) {
        float* Cp = (float*)Cg + (long)z * TRI_SLICE + (long)tlin * 16384;
#pragma unroll
        for (int m = 0; m < 4; ++m) {
            const int lrb = wr * 64 + m * 16 + kg * 4;
#pragma unroll
            for (int n = 0; n < NF; ++n) {
                const int lc = wc * (BN / 2) + n * 16 + fr;
#pragma unroll
                for (int q = 0; q < 4; ++q)
                    Cp[(lrb + q) * 128 + lc] = acc[m][n][q];
            }
        }
        return;
    }

    unsigned short* C16 = (OUTMODE == 1) ? ((unsigned short*)Cg + (long)b * sC) : nullptr;
    float*          C32 = (OUTMODE == 0) ? ((float*)Cg + (long)b * sC)
                        : (OUTMODE == 2) ? ((float*)Cg + (long)z * sC) : nullptr;
#pragma unroll
    for (int m = 0; m < 4; ++m) {
        const long rbase = i0 + wr * 64 + m * 16 + kg * 4;
#pragma unroll
        for (int n = 0; n < NF; ++n) {
            const long col = j0 + wc * (BN / 2) + n * 16 + fr;
#pragma unroll
            for (int q = 0; q < 4; ++q) {
                const long r = rbase + q;
                float v = acc[m][n][q];
                if (ADD_I && r == col) v += 1.0f;
                if (OUTMODE == 1) C16[r * ldc + col] = f2bf(v);
                else              C32[r * ldc + col] = v;
            }
        }
    }
}

// ---------------------------------------------------------------------------
// Reduce gram split-K fp32 compact partials (single region) -> bf16 G (lower
// triangle tiles). grid = BATCH*36*128*32/256 = 2304 blocks.
// ---------------------------------------------------------------------------
__global__ __launch_bounds__(256)
void reduce_cast_tri(const float* __restrict__ part, unsigned short* __restrict__ outG,
                     int split)
{
    const long DD = (long)DIM * DIM;
    int id = blockIdx.x * 256 + threadIdx.x;
    const int b  = id / 147456;          // 36*128*32
    int rem      = id % 147456;
    const int tlin = rem / 4096;         // tile index 0..35
    const int rr = rem % 4096;
    const int r  = rr >> 5;
    const int c4 = rr & 31;
    int t = tlin, ti = 0;
    while (t > ti) { t -= ti + 1; ++ti; }
    const long off = (long)tlin * 16384 + r * 128 + c4 * 4;

    float4 s = make_float4(0.f, 0.f, 0.f, 0.f);
    for (int sp = 0; sp < split; ++sp) {
        float4 v = *(const float4*)&part[(long)(b * split + sp) * TRI_SLICE + off];
        s.x += v.x; s.y += v.y; s.z += v.z; s.w += v.w;
    }
    ushort4 o;
    o.x = f2bf(s.x); o.y = f2bf(s.y); o.z = f2bf(s.z); o.w = f2bf(s.w);
    *(ushort4*)&outG[b * DD + ((long)ti * 128 + r) * DIM + (long)t * 128 + c4 * 4] = o;
}

// ---------------------------------------------------------------------------
// Reduce contiguous split-K fp32 partials -> bf16 (weights chain).
// ---------------------------------------------------------------------------
__global__ __launch_bounds__(256)
void reduce_cast_lin(const float* __restrict__ part, unsigned short* __restrict__ out,
                     int split, long len4 /* len/4 */)
{
    long i = (long)blockIdx.x * 256 + threadIdx.x;
    const long slab = i / len4;
    const long r = i % len4;
    float4 s = make_float4(0.f, 0.f, 0.f, 0.f);
    for (int sp = 0; sp < split; ++sp) {
        float4 v = ((const float4*)part)[(slab * split + sp) * len4 + r];
        s.x += v.x; s.y += v.y; s.z += v.z; s.w += v.w;
    }
    ushort4 o;
    o.x = f2bf(s.x); o.y = f2bf(s.y); o.z = f2bf(s.z); o.w = f2bf(s.w);
    ((ushort4*)out)[i] = o;
}

// ---------------------------------------------------------------------------
// Mirror the 28 strict-upper 128x128 tiles of symmetric G from the lower ones.
// ---------------------------------------------------------------------------
__global__ __launch_bounds__(256)
void sym_mirror(unsigned short* __restrict__ G)
{
    __shared__ unsigned short t[32][36];
    const long DD = (long)DIM * DIM;
    unsigned short* Gb = G + (long)blockIdx.z * DD;

    int u = blockIdx.y;                  // strict-upper pair index 0..27
    int tj = 1;
    while (u >= tj) { u -= tj; ++tj; }
    const int ti = u;                    // ti < tj

    const int sr = blockIdx.x >> 2;      // 0..3
    const int sc = blockIdx.x & 3;       // 0..3
    const int row = threadIdx.x >> 3;    // 0..31
    const int cid = threadIdx.x & 7;     // 0..7

    const long srow = (long)tj * 128 + sr * 32 + row;
    const long scol = (long)ti * 128 + sc * 32 + cid * 4;
    ushort4 v = *(const ushort4*)&Gb[srow * DIM + scol];
    t[row][cid * 4 + 0] = v.x; t[row][cid * 4 + 1] = v.y;
    t[row][cid * 4 + 2] = v.z; t[row][cid * 4 + 3] = v.w;
    __syncthreads();

    const long drow = (long)ti * 128 + sc * 32 + row;
    const long dcol = (long)tj * 128 + sr * 32 + cid * 4;
    ushort4 o;
    o.x = t[cid * 4 + 0][row];
    o.y = t[cid * 4 + 1][row];
    o.z = t[cid * 4 + 2][row];
    o.w = t[cid * 4 + 3][row];
    *(ushort4*)&Gb[drow * DIM + dcol] = o;
}

// ---------------------------------------------------------------------------
// src (fp32, R x C, batched) -> dst bf16 (optional) + dstT bf16 (C x R)
// ---------------------------------------------------------------------------
__global__ __launch_bounds__(256)
void transpose_cast(const float* __restrict__ src, unsigned short* __restrict__ dst,
                    unsigned short* __restrict__ dstT, int R, int C)
{
    __shared__ unsigned short t[32][33];
    const int b = blockIdx.z;
    const long base = (long)b * R * C;
    const int r0 = blockIdx.y * 32;
    const int c0 = blockIdx.x * 32;
    const int row = threadIdx.x >> 3;        // 0..31
    const int cid = threadIdx.x & 7;         // 0..7 (float4 granule)

    float4 v = *(const float4*)&src[base + (long)(r0 + row) * C + c0 + cid * 4];
    ushort4 h;
    h.x = f2bf(v.x); h.y = f2bf(v.y); h.z = f2bf(v.z); h.w = f2bf(v.w);
    if (dst) *(ushort4*)&dst[base + (long)(r0 + row) * C + c0 + cid * 4] = h;
    t[row][cid * 4 + 0] = h.x; t[row][cid * 4 + 1] = h.y;
    t[row][cid * 4 + 2] = h.z; t[row][cid * 4 + 3] = h.w;
    __syncthreads();

    ushort4 o;
    o.x = t[cid * 4 + 0][row];
    o.y = t[cid * 4 + 1][row];
    o.z = t[cid * 4 + 2][row];
    o.w = t[cid * 4 + 3][row];
    *(ushort4*)&dstT[base + (long)(c0 + row) * R + r0 + cid * 4] = o;
}

// three independent fp32 -> bf16 casts (Wq, Wk, Wv)
__global__ __launch_bounds__(256)
void cast3(const float* __restrict__ s0, const float* __restrict__ s1,
           const float* __restrict__ s2, unsigned short* __restrict__ d0,
           unsigned short* __restrict__ d1, unsigned short* __restrict__ d2, int n4)
{
    const float* s = (blockIdx.y == 0) ? s0 : (blockIdx.y == 1) ? s1 : s2;
    unsigned short* d = (blockIdx.y == 0) ? d0 : (blockIdx.y == 1) ? d1 : d2;
    int i = blockIdx.x * 256 + threadIdx.x;
    if (i >= n4) return;
    float4 v = ((const float4*)s)[i];
    ushort4 o;
    o.x = f2bf(v.x); o.y = f2bf(v.y); o.z = f2bf(v.z); o.w = f2bf(v.w);
    ((ushort4*)d)[i] = o;
}

// ---------------------------------------------------------------------------
extern "C" void kernel_launch(void* const* d_in, const int* in_sizes, int n_in,
                              void* d_out, int out_size, void* d_ws, size_t ws_size,
                              hipStream_t stream)
{
    const float* x  = (const float*)d_in[0];
    const float* Wq = (const float*)d_in[1];
    const float* Wk = (const float*)d_in[2];
    const float* Wv = (const float*)d_in[3];
    const float* P  = (const float*)d_in[4];
    float* out = (float*)d_out;

    const long DD = (long)DIM * DIM;   // 1M elements
    const long SD = (long)SEQ * DIM;   // 4M elements

    // workspace layout (MiB offsets):
    //   [0,32)    xb   bf16 B*SD                      (live: whole pass)
    //   [32,64)   xTb  bf16 B*SD (live: steps 1-2) -> Hb [32,40), Ntb [40,48),
    //             regB fp32 [48,64)  (live: step 3 only, after xTb is dead)
    //   [64,72)   Gb   bf16 B*DD
    //   [72,84)   Wqb,Ptb | Wkb,Wvb | Ub,W2Tb  (2 MiB each)
    //   [84, 84+split*9)  regA: gram fp32 compact partials (single region;
    //             split=4 -> [84,120) always safe; split=8 -> [84,156) only
    //             when ws_size >= 156 MiB)
    uint8_t* ws = (uint8_t*)d_ws;
    unsigned short* xb   = (unsigned short*)(ws);
    unsigned short* xTb  = (unsigned short*)(ws + (32ul << 20));
    unsigned short* Hb   = (unsigned short*)(ws + (32ul << 20));
    unsigned short* Ntb  = (unsigned short*)(ws + (40ul << 20));
    float*          regB = (float*)(ws + (48ul << 20));
    unsigned short* Gb   = (unsigned short*)(ws + (64ul << 20));
    unsigned short* Wqb  = (unsigned short*)(ws + (72ul << 20));
    unsigned short* Ptb  = (unsigned short*)(ws + (74ul << 20));
    unsigned short* Wkb  = (unsigned short*)(ws + (76ul << 20));
    unsigned short* Wvb  = (unsigned short*)(ws + (78ul << 20));
    unsigned short* Ub   = (unsigned short*)(ws + (80ul << 20));
    unsigned short* W2Tb = (unsigned short*)(ws + (82ul << 20));
    float*          regA = (float*)(ws + (84ul << 20));

    const int split = (ws_size >= (156ul << 20)) ? 8 : 4;

    // 1) x -> xb, xTb ; P -> Pt ; Wq/Wk/Wv -> bf16
    transpose_cast<<<dim3(DIM / 32, SEQ / 32, BATCH), 256, 0, stream>>>(
        x, xb, xTb, SEQ, DIM);
    transpose_cast<<<dim3(DIM / 32, DIM / 32, 1), 256, 0, stream>>>(
        P, nullptr, Ptb, DIM, DIM);
    cast3<<<dim3((int)(DD / 4 / 256), 3), 256, 0, stream>>>(
        Wq, Wk, Wv, Wqb, Wkb, Wvb, (int)(DD / 4));

    // 2) G_b = xT_b @ xT_b^T — lower-triangle tiles, split-K compact partials
    gemm_mfma<3, 128, true, false>
        <<<dim3(36 * split * BATCH, 1, 1), 256, 0, stream>>>(
            xTb, xTb, regA, SEQ / split, split, SEQ, SEQ, DIM, SD, SD, 0);
    reduce_cast_tri<<<dim3(BATCH * 36 * 128 * 32 / 256), 256, 0, stream>>>(
        regA, Gb, split);
    sym_mirror<<<dim3(16, 28, BATCH), 256, 0, stream>>>(Gb);

    // 3) {U, W2T} split-K2: U = Wq@Wk^T ; W2T = Pt@Wv^T  (partials in regB;
    //    xTb is dead by now, so [48,64) is free)
    gemm_mfma<2, 64, false, false><<<dim3(16, 8, 4), 256, 0, stream>>>(
        Wqb, Wkb, regB, DIM / 2, 2, DIM, DIM, DIM, DD, DD, DD);
    reduce_cast_lin<<<dim3((int)(2 * DD / 4 / 256)), 256, 0, stream>>>(
        regB, Ub, 2, DD / 4);

    // 4) H_b = U @ G_b^T  (G symmetric => H = U@G)   (BN=64)
    gemm_mfma<1, 64, false, false><<<dim3(16, 8, BATCH), 256, 0, stream>>>(
        Ub, Gb, Hb, DIM, 1, DIM, DIM, DIM, 0, DD, DD);

    // 5) Nt_b = W2T @ H_b^T + I   (= (H_b W2)^T + I; residual folded in)
    gemm_mfma<1, 64, false, true><<<dim3(16, 8, BATCH), 256, 0, stream>>>(
        W2Tb, Hb, Ntb, DIM, 1, DIM, DIM, DIM, 0, DD, DD);

    // 6) out_b = xb_b @ Nt_b^T   (pure GEMM, fp32 out)
    gemm_mfma<0, 128, false, false><<<dim3(8, 32, BATCH), 256, 0, stream>>>(
        xb, Ntb, out, DIM, 1, DIM, DIM, DIM, SD, DD, SD);
}

// Round 8
// 196.732 us; speedup vs baseline: 6.1847x; 1.0652x over previous
//
#include <hip/hip_runtime.h>
#include <hip/hip_bf16.h>
#include <stdint.h>

// out = x + x * [ (Wq Wk^T) * (x^T x) * (Wv P) ]  ==  x @ (I + N),  N = U G W2
// Big GEMMs (gram partials, final) use a counted-vmcnt double-buffered MFMA
// pipeline (prefetch-2, vmcnt(8), raw s_barrier, XOR-swizzled LDS via
// pre-swizzled global source). Chain/prep kernels unchanged (proven).

#define BATCH 4
#define SEQ   4096
#define DIM   1024

#define TRI_SLICE 589824l       // 36 tiles * 128*128 floats per gram slice

typedef __bf16 bf16x8 __attribute__((ext_vector_type(8)));
typedef float f32x4 __attribute__((ext_vector_type(4)));

static __device__ __forceinline__ unsigned short f2bf(float f) {
    unsigned int u = __builtin_bit_cast(unsigned int, f);
    u += 0x7fff + ((u >> 16) & 1);              // RNE
    return (unsigned short)(u >> 16);
}

// ---------------------------------------------------------------------------
// Deep-pipelined bf16 MFMA GEMM: C = A @ Bt^T.  Tile 128x128, BK=64, 4 waves.
//  LDS [2][128][64] double-buffer (64 KiB -> 2 blocks/CU). Prefetch distance 2,
//  s_waitcnt vmcnt(8) (counted, never 0 in-loop), raw s_barrier + mem fences.
//  XOR swizzle: global src chunk = lcol^lrow (linear LDS dest, rule #21);
//  ds_read chunk = (kk2*4+kg)^(fr&7). 16-way bank conflict -> uniform floor.
//  OUTMODE: 0 = fp32 out (Cg + b*sC);  3 = TRI compact fp32 partial.
//  TRI: 1-D grid of 36 lower-triangle tiles per z.  zdiv: z = b*zdiv + s.
//  Grid (flattened) must be a multiple of 8 (XCD swizzle). K/64 >= 2.
// ---------------------------------------------------------------------------
template<int OUTMODE, bool TRI>
__global__ __launch_bounds__(256)
void gemm_db(const unsigned short* __restrict__ Ag,
             const unsigned short* __restrict__ Btg,
             void* __restrict__ Cg,
             int K, int zdiv, int lda, int ldbt, int ldc,
             long sA, long sBt, long sC)
{
    __shared__ unsigned short As[2][128][64];
    __shared__ unsigned short Bs[2][128][64];

    // ---- XCD-chunk bijective swizzle over the whole grid (nwg % 8 == 0)
    const int gx = gridDim.x, gy = gridDim.y;
    const int nwg = gx * gy * gridDim.z;
    int id = blockIdx.x + gx * (blockIdx.y + gy * blockIdx.z);
    id = (id & 7) * (nwg >> 3) + (id >> 3);

    int z, tlin = 0;
    long i0, j0;
    if (TRI) {
        z = id / 36;
        tlin = id % 36;
        int t = tlin, ti = 0;
        while (t > ti) { t -= ti + 1; ++ti; }
        i0 = (long)ti * 128;
        j0 = (long)t * 128;
    } else {
        const int bx = id % gx;
        const int rest = id / gx;
        const int by = rest % gy;
        z = rest / gy;
        i0 = (long)by * 128;
        j0 = (long)bx * 128;
    }
    const int b = z / zdiv;
    const long koff = (long)(z % zdiv) * K;

    const unsigned short* A  = Ag  + (long)b * sA  + koff;
    const unsigned short* Bt = Btg + (long)b * sBt + koff;

    const int tid  = threadIdx.x;
    const int lane = tid & 63;
    const int w    = tid >> 6;          // wave 0..3
    const int wr   = w >> 1, wc = w & 1;
    const int lrow = lane >> 3;         // 0..7
    const int lcol = lane & 7;          // 0..7 (16B granule)
    const int fr   = lane & 15;
    const int kg   = lane >> 4;         // 0..3
    const int scol = (lcol ^ lrow) * 8; // pre-swizzled global source chunk

    f32x4 acc[4][4] = {};

    const int nt = K / 64;              // >= 2 always (K >= 512)

    // stage K-tile t into buffer buf: 8 global_load_lds issues per thread
    auto stage = [&](int t, int buf) {
        const long kk = (long)t * 64;
#pragma unroll
        for (int inst = 0; inst < 4; ++inst) {
            const int row = w * 32 + inst * 8;
            const unsigned short* srcA = A + (i0 + row + lrow) * lda + kk + scol;
            __builtin_amdgcn_global_load_lds(
                (const __attribute__((address_space(1))) void*)srcA,
                (__attribute__((address_space(3))) void*)&As[buf][row][0], 16, 0, 0);
            const unsigned short* srcB = Bt + (j0 + row + lrow) * ldbt + kk + scol;
            __builtin_amdgcn_global_load_lds(
                (const __attribute__((address_space(1))) void*)srcB,
                (__attribute__((address_space(3))) void*)&Bs[buf][row][0], 16, 0, 0);
        }
    };

    auto compute = [&](int buf) {
#pragma unroll
        for (int kk2 = 0; kk2 < 2; ++kk2) {
            const int ch = ((kk2 * 4 + kg) ^ (fr & 7)) * 8;   // swizzled read chunk
            bf16x8 af[4], bfv[4];
#pragma unroll
            for (int m = 0; m < 4; ++m)
                af[m] = *(const bf16x8*)&As[buf][wr * 64 + m * 16 + fr][ch];
#pragma unroll
            for (int n = 0; n < 4; ++n)
                bfv[n] = *(const bf16x8*)&Bs[buf][wc * 64 + n * 16 + fr][ch];
            __builtin_amdgcn_s_setprio(1);
#pragma unroll
            for (int m = 0; m < 4; ++m)
#pragma unroll
                for (int n = 0; n < 4; ++n)
                    acc[m][n] = __builtin_amdgcn_mfma_f32_16x16x32_bf16(
                        af[m], bfv[n], acc[m][n], 0, 0, 0);
            __builtin_amdgcn_s_setprio(0);
        }
    };

    // ---- prologue: prefetch tiles 0 and 1
    stage(0, 0);
    stage(1, 1);

    // ---- main loop (tiles 0 .. nt-2): wait own 8 oldest, sync, compute, sync
    for (int t = 0; t < nt - 1; ++t) {
        asm volatile("s_waitcnt vmcnt(8)" ::: "memory");
        __builtin_amdgcn_s_barrier();
        asm volatile("" ::: "memory");
        compute(t & 1);
        asm volatile("" ::: "memory");
        __builtin_amdgcn_s_barrier();
        asm volatile("" ::: "memory");
        if (t + 2 < nt) stage(t + 2, t & 1);  // buf free: all waves done reading
    }
    // ---- last tile: full drain (outstanding < 8 here, vmcnt(8) wouldn't wait)
    asm volatile("s_waitcnt vmcnt(0)" ::: "memory");
    __builtin_amdgcn_s_barrier();
    asm volatile("" ::: "memory");
    compute((nt - 1) & 1);

    // ---- epilogue: C/D layout col = lane&15, row = (lane>>4)*4 + q
    if (OUTMODE == 3) {
        float* Cp = (float*)Cg + (long)z * TRI_SLICE + (long)tlin * 16384;
#pragma unroll
        for (int m = 0; m < 4; ++m) {
            const int lrb = wr * 64 + m * 16 + kg * 4;
#pragma unroll
            for (int n = 0; n < 4; ++n) {
                const int lc = wc * 64 + n * 16 + fr;
#pragma unroll
                for (int q = 0; q < 4; ++q)
                    Cp[(lrb + q) * 128 + lc] = acc[m][n][q];
            }
        }
        return;
    }
    float* C32 = (float*)Cg + (long)b * sC;
#pragma unroll
    for (int m = 0; m < 4; ++m) {
        const long rbase = i0 + wr * 64 + m * 16 + kg * 4;
#pragma unroll
        for (int n = 0; n < 4; ++n) {
            const long col = j0 + wc * 64 + n * 16 + fr;
#pragma unroll
            for (int q = 0; q < 4; ++q)
                C32[(rbase + q) * ldc + col] = acc[m][n][q];
        }
    }
}

// ---------------------------------------------------------------------------
// Original 2-barrier bf16 MFMA GEMM (proven) — kept for the small D x D chain.
//  OUTMODE: 1 = bf16 out (+ optional identity add), 2 = fp32 slice partials.
// ---------------------------------------------------------------------------
template<int OUTMODE, int BN, bool ADD_I>
__global__ __launch_bounds__(256)
void gemm_mfma(const unsigned short* __restrict__ Ag,
               const unsigned short* __restrict__ Btg,
               void* __restrict__ Cg,
               int K, int zdiv, int lda, int ldbt, int ldc,
               long sA, long sBt, long sC)
{
    constexpr int NF = BN / 32;
    __shared__ unsigned short As[128][64];
    __shared__ unsigned short Bs[BN][64];

    const int gx = gridDim.x, gy = gridDim.y;
    const int nwg = gx * gy * gridDim.z;
    int id = blockIdx.x + gx * (blockIdx.y + gy * blockIdx.z);
    id = (id & 7) * (nwg >> 3) + (id >> 3);

    const int bx = id % gx;
    const int rest = id / gx;
    const int by = rest % gy;
    const int z = rest / gy;
    const long i0 = (long)by * 128;
    const long j0 = (long)bx * BN;

    const int b = z / zdiv;
    const long koff = (long)(z % zdiv) * K;
    const unsigned short* A  = Ag  + (long)b * sA  + koff;
    const unsigned short* Bt = Btg + (long)b * sBt + koff;

    const int tid  = threadIdx.x;
    const int lane = tid & 63;
    const int w    = tid >> 6;
    const int wr   = w >> 1, wc = w & 1;
    const int lrow = lane >> 3;
    const int lcol = lane & 7;
    const int fr   = lane & 15;
    const int kg   = lane >> 4;

    f32x4 acc[4][NF] = {};

    for (int kk = 0; kk < K; kk += 64) {
#pragma unroll
        for (int inst = 0; inst < 4; ++inst) {
            const int row = w * 32 + inst * 8;
            const unsigned short* srcA = A + (i0 + row + lrow) * lda + kk + lcol * 8;
            __builtin_amdgcn_global_load_lds(
                (const __attribute__((address_space(1))) void*)srcA,
                (__attribute__((address_space(3))) void*)&As[row][0], 16, 0, 0);
        }
#pragma unroll
        for (int inst = 0; inst < NF; ++inst) {
            const int row = w * (8 * NF) + inst * 8;
            const unsigned short* srcB = Bt + (j0 + row + lrow) * ldbt + kk + lcol * 8;
            __builtin_amdgcn_global_load_lds(
                (const __attribute__((address_space(1))) void*)srcB,
                (__attribute__((address_space(3))) void*)&Bs[row][0], 16, 0, 0);
        }
        __syncthreads();

#pragma unroll
        for (int kk2 = 0; kk2 < 2; ++kk2) {
            bf16x8 af[4], bfv[NF];
#pragma unroll
            for (int m = 0; m < 4; ++m)
                af[m] = *(const bf16x8*)&As[wr * 64 + m * 16 + fr][kk2 * 32 + kg * 8];
#pragma unroll
            for (int n = 0; n < NF; ++n)
                bfv[n] = *(const bf16x8*)&Bs[wc * (BN / 2) + n * 16 + fr][kk2 * 32 + kg * 8];
#pragma unroll
            for (int m = 0; m < 4; ++m)
#pragma unroll
                for (int n = 0; n < NF; ++n)
                    acc[m][n] = __builtin_amdgcn_mfma_f32_16x16x32_bf16(
                        af[m], bfv[n], acc[m][n], 0, 0, 0);
        }
        __syncthreads();
    }

    unsigned short* C16 = (OUTMODE == 1) ? ((unsigned short*)Cg + (long)b * sC) : nullptr;
    float*          C32 = (OUTMODE == 2) ? ((float*)Cg + (long)z * sC) : nullptr;
#pragma unroll
    for (int m = 0; m < 4; ++m) {
        const long rbase = i0 + wr * 64 + m * 16 + kg * 4;
#pragma unroll
        for (int n = 0; n < NF; ++n) {
            const long col = j0 + wc * (BN / 2) + n * 16 + fr;
#pragma unroll
            for (int q = 0; q < 4; ++q) {
                const long r = rbase + q;
                float v = acc[m][n][q];
                if (ADD_I && r == col) v += 1.0f;
                if (OUTMODE == 1) C16[r * ldc + col] = f2bf(v);
                else              C32[r * ldc + col] = v;
            }
        }
    }
}

// ---------------------------------------------------------------------------
__global__ __launch_bounds__(256)
void reduce_cast_tri(const float* __restrict__ part, unsigned short* __restrict__ outG,
                     int split)
{
    const long DD = (long)DIM * DIM;
    int id = blockIdx.x * 256 + threadIdx.x;
    const int b  = id / 147456;          // 36*128*32
    int rem      = id % 147456;
    const int tlin = rem / 4096;
    const int rr = rem % 4096;
    const int r  = rr >> 5;
    const int c4 = rr & 31;
    int t = tlin, ti = 0;
    while (t > ti) { t -= ti + 1; ++ti; }
    const long off = (long)tlin * 16384 + r * 128 + c4 * 4;

    float4 s = make_float4(0.f, 0.f, 0.f, 0.f);
    for (int sp = 0; sp < split; ++sp) {
        float4 v = *(const float4*)&part[(long)(b * split + sp) * TRI_SLICE + off];
        s.x += v.x; s.y += v.y; s.z += v.z; s.w += v.w;
    }
    ushort4 o;
    o.x = f2bf(s.x); o.y = f2bf(s.y); o.z = f2bf(s.z); o.w = f2bf(s.w);
    *(ushort4*)&outG[b * DD + ((long)ti * 128 + r) * DIM + (long)t * 128 + c4 * 4] = o;
}

__global__ __launch_bounds__(256)
void reduce_cast_lin(const float* __restrict__ part, unsigned short* __restrict__ out,
                     int split, long len4)
{
    long i = (long)blockIdx.x * 256 + threadIdx.x;
    const long slab = i / len4;
    const long r = i % len4;
    float4 s = make_float4(0.f, 0.f, 0.f, 0.f);
    for (int sp = 0; sp < split; ++sp) {
        float4 v = ((const float4*)part)[(slab * split + sp) * len4 + r];
        s.x += v.x; s.y += v.y; s.z += v.z; s.w += v.w;
    }
    ushort4 o;
    o.x = f2bf(s.x); o.y = f2bf(s.y); o.z = f2bf(s.z); o.w = f2bf(s.w);
    ((ushort4*)out)[i] = o;
}

__global__ __launch_bounds__(256)
void sym_mirror(unsigned short* __restrict__ G)
{
    __shared__ unsigned short t[32][36];
    const long DD = (long)DIM * DIM;
    unsigned short* Gb = G + (long)blockIdx.z * DD;

    int u = blockIdx.y;
    int tj = 1;
    while (u >= tj) { u -= tj; ++tj; }
    const int ti = u;                    // ti < tj

    const int sr = blockIdx.x >> 2;
    const int sc = blockIdx.x & 3;
    const int row = threadIdx.x >> 3;
    const int cid = threadIdx.x & 7;

    const long srow = (long)tj * 128 + sr * 32 + row;
    const long scol = (long)ti * 128 + sc * 32 + cid * 4;
    ushort4 v = *(const ushort4*)&Gb[srow * DIM + scol];
    t[row][cid * 4 + 0] = v.x; t[row][cid * 4 + 1] = v.y;
    t[row][cid * 4 + 2] = v.z; t[row][cid * 4 + 3] = v.w;
    __syncthreads();

    const long drow = (long)ti * 128 + sc * 32 + row;
    const long dcol = (long)tj * 128 + sr * 32 + cid * 4;
    ushort4 o;
    o.x = t[cid * 4 + 0][row];
    o.y = t[cid * 4 + 1][row];
    o.z = t[cid * 4 + 2][row];
    o.w = t[cid * 4 + 3][row];
    *(ushort4*)&Gb[drow * DIM + dcol] = o;
}

__global__ __launch_bounds__(256)
void transpose_cast(const float* __restrict__ src, unsigned short* __restrict__ dst,
                    unsigned short* __restrict__ dstT, int R, int C)
{
    __shared__ unsigned short t[32][33];
    const int b = blockIdx.z;
    const long base = (long)b * R * C;
    const int r0 = blockIdx.y * 32;
    const int c0 = blockIdx.x * 32;
    const int row = threadIdx.x >> 3;
    const int cid = threadIdx.x & 7;

    float4 v = *(const float4*)&src[base + (long)(r0 + row) * C + c0 + cid * 4];
    ushort4 h;
    h.x = f2bf(v.x); h.y = f2bf(v.y); h.z = f2bf(v.z); h.w = f2bf(v.w);
    if (dst) *(ushort4*)&dst[base + (long)(r0 + row) * C + c0 + cid * 4] = h;
    t[row][cid * 4 + 0] = h.x; t[row][cid * 4 + 1] = h.y;
    t[row][cid * 4 + 2] = h.z; t[row][cid * 4 + 3] = h.w;
    __syncthreads();

    ushort4 o;
    o.x = t[cid * 4 + 0][row];
    o.y = t[cid * 4 + 1][row];
    o.z = t[cid * 4 + 2][row];
    o.w = t[cid * 4 + 3][row];
    *(ushort4*)&dstT[base + (long)(c0 + row) * R + r0 + cid * 4] = o;
}

__global__ __launch_bounds__(256)
void cast3(const float* __restrict__ s0, const float* __restrict__ s1,
           const float* __restrict__ s2, unsigned short* __restrict__ d0,
           unsigned short* __restrict__ d1, unsigned short* __restrict__ d2, int n4)
{
    const float* s = (blockIdx.y == 0) ? s0 : (blockIdx.y == 1) ? s1 : s2;
    unsigned short* d = (blockIdx.y == 0) ? d0 : (blockIdx.y == 1) ? d1 : d2;
    int i = blockIdx.x * 256 + threadIdx.x;
    if (i >= n4) return;
    float4 v = ((const float4*)s)[i];
    ushort4 o;
    o.x = f2bf(v.x); o.y = f2bf(v.y); o.z = f2bf(v.z); o.w = f2bf(v.w);
    ((ushort4*)d)[i] = o;
}

// ---------------------------------------------------------------------------
extern "C" void kernel_launch(void* const* d_in, const int* in_sizes, int n_in,
                              void* d_out, int out_size, void* d_ws, size_t ws_size,
                              hipStream_t stream)
{
    const float* x  = (const float*)d_in[0];
    const float* Wq = (const float*)d_in[1];
    const float* Wk = (const float*)d_in[2];
    const float* Wv = (const float*)d_in[3];
    const float* P  = (const float*)d_in[4];
    float* out = (float*)d_out;

    const long DD = (long)DIM * DIM;
    const long SD = (long)SEQ * DIM;

    // workspace layout (MiB offsets) — identical to round 7 (proven):
    //   [0,32) xb | [32,64) xTb -> Hb[32,40) Ntb[40,48) regB[48,64)
    //   [64,72) Gb | [72,84) weights | [84,84+split*9) regA gram partials
    uint8_t* ws = (uint8_t*)d_ws;
    unsigned short* xb   = (unsigned short*)(ws);
    unsigned short* xTb  = (unsigned short*)(ws + (32ul << 20));
    unsigned short* Hb   = (unsigned short*)(ws + (32ul << 20));
    unsigned short* Ntb  = (unsigned short*)(ws + (40ul << 20));
    float*          regB = (float*)(ws + (48ul << 20));
    unsigned short* Gb   = (unsigned short*)(ws + (64ul << 20));
    unsigned short* Wqb  = (unsigned short*)(ws + (72ul << 20));
    unsigned short* Ptb  = (unsigned short*)(ws + (74ul << 20));
    unsigned short* Wkb  = (unsigned short*)(ws + (76ul << 20));
    unsigned short* Wvb  = (unsigned short*)(ws + (78ul << 20));
    unsigned short* Ub   = (unsigned short*)(ws + (80ul << 20));
    unsigned short* W2Tb = (unsigned short*)(ws + (82ul << 20));
    float*          regA = (float*)(ws + (84ul << 20));

    const int split = (ws_size >= (156ul << 20)) ? 8 : 4;

    // 1) x -> xb, xTb ; P -> Pt ; Wq/Wk/Wv -> bf16
    transpose_cast<<<dim3(DIM / 32, SEQ / 32, BATCH), 256, 0, stream>>>(
        x, xb, xTb, SEQ, DIM);
    transpose_cast<<<dim3(DIM / 32, DIM / 32, 1), 256, 0, stream>>>(
        P, nullptr, Ptb, DIM, DIM);
    cast3<<<dim3((int)(DD / 4 / 256), 3), 256, 0, stream>>>(
        Wq, Wk, Wv, Wqb, Wkb, Wvb, (int)(DD / 4));

    // 2) G_b = xT_b @ xT_b^T — lower-triangle tiles, split-K compact partials
    gemm_db<3, true><<<dim3(36 * split * BATCH, 1, 1), 256, 0, stream>>>(
        xTb, xTb, regA, SEQ / split, split, SEQ, SEQ, DIM, SD, SD, 0);
    reduce_cast_tri<<<dim3(BATCH * 36 * 128 * 32 / 256), 256, 0, stream>>>(
        regA, Gb, split);
    sym_mirror<<<dim3(16, 28, BATCH), 256, 0, stream>>>(Gb);

    // 3) {U, W2T} split-K2: U = Wq@Wk^T ; W2T = Pt@Wv^T  (partials in regB)
    gemm_mfma<2, 64, false><<<dim3(16, 8, 4), 256, 0, stream>>>(
        Wqb, Wkb, regB, DIM / 2, 2, DIM, DIM, DIM, DD, DD, DD);
    reduce_cast_lin<<<dim3((int)(2 * DD / 4 / 256)), 256, 0, stream>>>(
        regB, Ub, 2, DD / 4);

    // 4) H_b = U @ G_b^T  (G symmetric)
    gemm_mfma<1, 64, false><<<dim3(16, 8, BATCH), 256, 0, stream>>>(
        Ub, Gb, Hb, DIM, 1, DIM, DIM, DIM, 0, DD, DD);

    // 5) Nt_b = W2T @ H_b^T + I   (residual folded in)
    gemm_mfma<1, 64, true><<<dim3(16, 8, BATCH), 256, 0, stream>>>(
        W2Tb, Hb, Ntb, DIM, 1, DIM, DIM, DIM, 0, DD, DD);

    // 6) out_b = xb_b @ Nt_b^T   (pure GEMM, fp32 out, deep pipeline)
    gemm_db<0, false><<<dim3(8, 32, BATCH), 256, 0, stream>>>(
        xb, Ntb, out, DIM, 1, DIM, DIM, DIM, SD, DD, SD);
}

// Round 9
// 184.583 us; speedup vs baseline: 6.5918x; 1.0658x over previous
//
#include <hip/hip_runtime.h>
#include <hip/hip_bf16.h>
#include <stdint.h>

// out = x + x * [ (Wq Wk^T) * (x^T x) * (Wv P) ]  ==  x @ (I + N),  N = U G W2
// Big GEMMs (gram partials, final) use a counted-vmcnt double-buffered MFMA
// pipeline with STAGE-BEFORE-MFMA (T3 minimum recipe): per tile,
//   vmcnt(8) -> bar -> ds_read 16xb128 -> lgkmcnt(0) -> bar -> stage(t+2)
//   -> setprio(1) MFMA x32 setprio(0)
// XOR-swizzled LDS via pre-swizzled global source (conflicts measured 0).
// Chain/prep kernels unchanged (proven).

#define BATCH 4
#define SEQ   4096
#define DIM   1024

#define TRI_SLICE 589824l       // 36 tiles * 128*128 floats per gram slice

typedef __bf16 bf16x8 __attribute__((ext_vector_type(8)));
typedef float f32x4 __attribute__((ext_vector_type(4)));

static __device__ __forceinline__ unsigned short f2bf(float f) {
    unsigned int u = __builtin_bit_cast(unsigned int, f);
    u += 0x7fff + ((u >> 16) & 1);              // RNE
    return (unsigned short)(u >> 16);
}

// ---------------------------------------------------------------------------
// Deep-pipelined bf16 MFMA GEMM: C = A @ Bt^T.  Tile 128x128, BK=64, 4 waves.
//  LDS [2][128][64] double-buffer (64 KiB -> 2 blocks/CU). Prefetch distance 2.
//  OUTMODE: 0 = fp32 out (Cg + b*sC);  3 = TRI compact fp32 partial.
//  TRI: 1-D grid of 36 lower-triangle tiles per z.  zdiv: z = b*zdiv + s.
//  Grid (flattened) must be a multiple of 8 (XCD swizzle). K/64 >= 2.
// ---------------------------------------------------------------------------
template<int OUTMODE, bool TRI>
__global__ __launch_bounds__(256)
void gemm_db(const unsigned short* __restrict__ Ag,
             const unsigned short* __restrict__ Btg,
             void* __restrict__ Cg,
             int K, int zdiv, int lda, int ldbt, int ldc,
             long sA, long sBt, long sC)
{
    __shared__ unsigned short As[2][128][64];
    __shared__ unsigned short Bs[2][128][64];

    // ---- XCD-chunk bijective swizzle over the whole grid (nwg % 8 == 0)
    const int gx = gridDim.x, gy = gridDim.y;
    const int nwg = gx * gy * gridDim.z;
    int id = blockIdx.x + gx * (blockIdx.y + gy * blockIdx.z);
    id = (id & 7) * (nwg >> 3) + (id >> 3);

    int z, tlin = 0;
    long i0, j0;
    if (TRI) {
        z = id / 36;
        tlin = id % 36;
        int t = tlin, ti = 0;
        while (t > ti) { t -= ti + 1; ++ti; }
        i0 = (long)ti * 128;
        j0 = (long)t * 128;
    } else {
        const int bx = id % gx;
        const int rest = id / gx;
        const int by = rest % gy;
        z = rest / gy;
        i0 = (long)by * 128;
        j0 = (long)bx * 128;
    }
    const int b = z / zdiv;
    const long koff = (long)(z % zdiv) * K;

    const unsigned short* A  = Ag  + (long)b * sA  + koff;
    const unsigned short* Bt = Btg + (long)b * sBt + koff;

    const int tid  = threadIdx.x;
    const int lane = tid & 63;
    const int w    = tid >> 6;          // wave 0..3
    const int wr   = w >> 1, wc = w & 1;
    const int lrow = lane >> 3;         // 0..7
    const int lcol = lane & 7;          // 0..7 (16B granule)
    const int fr   = lane & 15;
    const int kg   = lane >> 4;         // 0..3
    const int scol = (lcol ^ lrow) * 8; // pre-swizzled global source chunk

    f32x4 acc[4][4] = {};

    const int nt = K / 64;              // >= 2 always

    // stage K-tile t into buffer buf: 8 global_load_lds issues per thread
    auto stage = [&](int t, int buf) {
        const long kk = (long)t * 64;
#pragma unroll
        for (int inst = 0; inst < 4; ++inst) {
            const int row = w * 32 + inst * 8;
            const unsigned short* srcA = A + (i0 + row + lrow) * lda + kk + scol;
            __builtin_amdgcn_global_load_lds(
                (const __attribute__((address_space(1))) void*)srcA,
                (__attribute__((address_space(3))) void*)&As[buf][row][0], 16, 0, 0);
            const unsigned short* srcB = Bt + (j0 + row + lrow) * ldbt + kk + scol;
            __builtin_amdgcn_global_load_lds(
                (const __attribute__((address_space(1))) void*)srcB,
                (__attribute__((address_space(3))) void*)&Bs[buf][row][0], 16, 0, 0);
        }
    };

    // ---- prologue: prefetch tiles 0 and 1
    stage(0, 0);
    stage(1, 1);

    // ---- main loop: stage-before-MFMA, counted vmcnt
    for (int t = 0; t < nt; ++t) {
        const int buf = t & 1;
        if (t < nt - 1) asm volatile("s_waitcnt vmcnt(8)" ::: "memory");
        else            asm volatile("s_waitcnt vmcnt(0)" ::: "memory");
        __builtin_amdgcn_s_barrier();
        asm volatile("" ::: "memory");

        // read ALL fragments of this tile into registers (16 x ds_read_b128)
        bf16x8 af[2][4], bfv[2][4];
#pragma unroll
        for (int kk2 = 0; kk2 < 2; ++kk2) {
            const int ch = ((kk2 * 4 + kg) ^ (fr & 7)) * 8;   // swizzled chunk
#pragma unroll
            for (int m = 0; m < 4; ++m)
                af[kk2][m] = *(const bf16x8*)&As[buf][wr * 64 + m * 16 + fr][ch];
#pragma unroll
            for (int n = 0; n < 4; ++n)
                bfv[kk2][n] = *(const bf16x8*)&Bs[buf][wc * 64 + n * 16 + fr][ch];
        }
        asm volatile("s_waitcnt lgkmcnt(0)" ::: "memory");
        __builtin_amdgcn_s_barrier();      // all waves done reading buf
        asm volatile("" ::: "memory");

        if (t + 2 < nt) stage(t + 2, buf); // loads fly under the MFMA cluster

        __builtin_amdgcn_s_setprio(1);
#pragma unroll
        for (int kk2 = 0; kk2 < 2; ++kk2)
#pragma unroll
            for (int m = 0; m < 4; ++m)
#pragma unroll
                for (int n = 0; n < 4; ++n)
                    acc[m][n] = __builtin_amdgcn_mfma_f32_16x16x32_bf16(
                        af[kk2][m], bfv[kk2][n], acc[m][n], 0, 0, 0);
        __builtin_amdgcn_s_setprio(0);
    }

    // ---- epilogue: C/D layout col = lane&15, row = (lane>>4)*4 + q
    if (OUTMODE == 3) {
        float* Cp = (float*)Cg + (long)z * TRI_SLICE + (long)tlin * 16384;
#pragma unroll
        for (int m = 0; m < 4; ++m) {
            const int lrb = wr * 64 + m * 16 + kg * 4;
#pragma unroll
            for (int n = 0; n < 4; ++n) {
                const int lc = wc * 64 + n * 16 + fr;
#pragma unroll
                for (int q = 0; q < 4; ++q)
                    Cp[(lrb + q) * 128 + lc] = acc[m][n][q];
            }
        }
        return;
    }
    float* C32 = (float*)Cg + (long)b * sC;
#pragma unroll
    for (int m = 0; m < 4; ++m) {
        const long rbase = i0 + wr * 64 + m * 16 + kg * 4;
#pragma unroll
        for (int n = 0; n < 4; ++n) {
            const long col = j0 + wc * 64 + n * 16 + fr;
#pragma unroll
            for (int q = 0; q < 4; ++q)
                C32[(rbase + q) * ldc + col] = acc[m][n][q];
        }
    }
}

// ---------------------------------------------------------------------------
// Original 2-barrier bf16 MFMA GEMM (proven) — kept for the small D x D chain.
//  OUTMODE: 1 = bf16 out (+ optional identity add), 2 = fp32 slice partials.
// ---------------------------------------------------------------------------
template<int OUTMODE, int BN, bool ADD_I>
__global__ __launch_bounds__(256)
void gemm_mfma(const unsigned short* __restrict__ Ag,
               const unsigned short* __restrict__ Btg,
               void* __restrict__ Cg,
               int K, int zdiv, int lda, int ldbt, int ldc,
               long sA, long sBt, long sC)
{
    constexpr int NF = BN / 32;
    __shared__ unsigned short As[128][64];
    __shared__ unsigned short Bs[BN][64];

    const int gx = gridDim.x, gy = gridDim.y;
    const int nwg = gx * gy * gridDim.z;
    int id = blockIdx.x + gx * (blockIdx.y + gy * blockIdx.z);
    id = (id & 7) * (nwg >> 3) + (id >> 3);

    const int bx = id % gx;
    const int rest = id / gx;
    const int by = rest % gy;
    const int z = rest / gy;
    const long i0 = (long)by * 128;
    const long j0 = (long)bx * BN;

    const int b = z / zdiv;
    const long koff = (long)(z % zdiv) * K;
    const unsigned short* A  = Ag  + (long)b * sA  + koff;
    const unsigned short* Bt = Btg + (long)b * sBt + koff;

    const int tid  = threadIdx.x;
    const int lane = tid & 63;
    const int w    = tid >> 6;
    const int wr   = w >> 1, wc = w & 1;
    const int lrow = lane >> 3;
    const int lcol = lane & 7;
    const int fr   = lane & 15;
    const int kg   = lane >> 4;

    f32x4 acc[4][NF] = {};

    for (int kk = 0; kk < K; kk += 64) {
#pragma unroll
        for (int inst = 0; inst < 4; ++inst) {
            const int row = w * 32 + inst * 8;
            const unsigned short* srcA = A + (i0 + row + lrow) * lda + kk + lcol * 8;
            __builtin_amdgcn_global_load_lds(
                (const __attribute__((address_space(1))) void*)srcA,
                (__attribute__((address_space(3))) void*)&As[row][0], 16, 0, 0);
        }
#pragma unroll
        for (int inst = 0; inst < NF; ++inst) {
            const int row = w * (8 * NF) + inst * 8;
            const unsigned short* srcB = Bt + (j0 + row + lrow) * ldbt + kk + lcol * 8;
            __builtin_amdgcn_global_load_lds(
                (const __attribute__((address_space(1))) void*)srcB,
                (__attribute__((address_space(3))) void*)&Bs[row][0], 16, 0, 0);
        }
        __syncthreads();

#pragma unroll
        for (int kk2 = 0; kk2 < 2; ++kk2) {
            bf16x8 af[4], bfv[NF];
#pragma unroll
            for (int m = 0; m < 4; ++m)
                af[m] = *(const bf16x8*)&As[wr * 64 + m * 16 + fr][kk2 * 32 + kg * 8];
#pragma unroll
            for (int n = 0; n < NF; ++n)
                bfv[n] = *(const bf16x8*)&Bs[wc * (BN / 2) + n * 16 + fr][kk2 * 32 + kg * 8];
#pragma unroll
            for (int m = 0; m < 4; ++m)
#pragma unroll
                for (int n = 0; n < NF; ++n)
                    acc[m][n] = __builtin_amdgcn_mfma_f32_16x16x32_bf16(
                        af[m], bfv[n], acc[m][n], 0, 0, 0);
        }
        __syncthreads();
    }

    unsigned short* C16 = (OUTMODE == 1) ? ((unsigned short*)Cg + (long)b * sC) : nullptr;
    float*          C32 = (OUTMODE == 2) ? ((float*)Cg + (long)z * sC) : nullptr;
#pragma unroll
    for (int m = 0; m < 4; ++m) {
        const long rbase = i0 + wr * 64 + m * 16 + kg * 4;
#pragma unroll
        for (int n = 0; n < NF; ++n) {
            const long col = j0 + wc * (BN / 2) + n * 16 + fr;
#pragma unroll
            for (int q = 0; q < 4; ++q) {
                const long r = rbase + q;
                float v = acc[m][n][q];
                if (ADD_I && r == col) v += 1.0f;
                if (OUTMODE == 1) C16[r * ldc + col] = f2bf(v);
                else              C32[r * ldc + col] = v;
            }
        }
    }
}

// ---------------------------------------------------------------------------
__global__ __launch_bounds__(256)
void reduce_cast_tri(const float* __restrict__ part, unsigned short* __restrict__ outG,
                     int split)
{
    const long DD = (long)DIM * DIM;
    int id = blockIdx.x * 256 + threadIdx.x;
    const int b  = id / 147456;          // 36*128*32
    int rem      = id % 147456;
    const int tlin = rem / 4096;
    const int rr = rem % 4096;
    const int r  = rr >> 5;
    const int c4 = rr & 31;
    int t = tlin, ti = 0;
    while (t > ti) { t -= ti + 1; ++ti; }
    const long off = (long)tlin * 16384 + r * 128 + c4 * 4;

    float4 s = make_float4(0.f, 0.f, 0.f, 0.f);
    for (int sp = 0; sp < split; ++sp) {
        float4 v = *(const float4*)&part[(long)(b * split + sp) * TRI_SLICE + off];
        s.x += v.x; s.y += v.y; s.z += v.z; s.w += v.w;
    }
    ushort4 o;
    o.x = f2bf(s.x); o.y = f2bf(s.y); o.z = f2bf(s.z); o.w = f2bf(s.w);
    *(ushort4*)&outG[b * DD + ((long)ti * 128 + r) * DIM + (long)t * 128 + c4 * 4] = o;
}

__global__ __launch_bounds__(256)
void reduce_cast_lin(const float* __restrict__ part, unsigned short* __restrict__ out,
                     int split, long len4)
{
    long i = (long)blockIdx.x * 256 + threadIdx.x;
    const long slab = i / len4;
    const long r = i % len4;
    float4 s = make_float4(0.f, 0.f, 0.f, 0.f);
    for (int sp = 0; sp < split; ++sp) {
        float4 v = ((const float4*)part)[(slab * split + sp) * len4 + r];
        s.x += v.x; s.y += v.y; s.z += v.z; s.w += v.w;
    }
    ushort4 o;
    o.x = f2bf(s.x); o.y = f2bf(s.y); o.z = f2bf(s.z); o.w = f2bf(s.w);
    ((ushort4*)out)[i] = o;
}

__global__ __launch_bounds__(256)
void sym_mirror(unsigned short* __restrict__ G)
{
    __shared__ unsigned short t[32][36];
    const long DD = (long)DIM * DIM;
    unsigned short* Gb = G + (long)blockIdx.z * DD;

    int u = blockIdx.y;
    int tj = 1;
    while (u >= tj) { u -= tj; ++tj; }
    const int ti = u;                    // ti < tj

    const int sr = blockIdx.x >> 2;
    const int sc = blockIdx.x & 3;
    const int row = threadIdx.x >> 3;
    const int cid = threadIdx.x & 7;

    const long srow = (long)tj * 128 + sr * 32 + row;
    const long scol = (long)ti * 128 + sc * 32 + cid * 4;
    ushort4 v = *(const ushort4*)&Gb[srow * DIM + scol];
    t[row][cid * 4 + 0] = v.x; t[row][cid * 4 + 1] = v.y;
    t[row][cid * 4 + 2] = v.z; t[row][cid * 4 + 3] = v.w;
    __syncthreads();

    const long drow = (long)ti * 128 + sc * 32 + row;
    const long dcol = (long)tj * 128 + sr * 32 + cid * 4;
    ushort4 o;
    o.x = t[cid * 4 + 0][row];
    o.y = t[cid * 4 + 1][row];
    o.z = t[cid * 4 + 2][row];
    o.w = t[cid * 4 + 3][row];
    *(ushort4*)&Gb[drow * DIM + dcol] = o;
}

__global__ __launch_bounds__(256)
void transpose_cast(const float* __restrict__ src, unsigned short* __restrict__ dst,
                    unsigned short* __restrict__ dstT, int R, int C)
{
    __shared__ unsigned short t[32][33];
    const int b = blockIdx.z;
    const long base = (long)b * R * C;
    const int r0 = blockIdx.y * 32;
    const int c0 = blockIdx.x * 32;
    const int row = threadIdx.x >> 3;
    const int cid = threadIdx.x & 7;

    float4 v = *(const float4*)&src[base + (long)(r0 + row) * C + c0 + cid * 4];
    ushort4 h;
    h.x = f2bf(v.x); h.y = f2bf(v.y); h.z = f2bf(v.z); h.w = f2bf(v.w);
    if (dst) *(ushort4*)&dst[base + (long)(r0 + row) * C + c0 + cid * 4] = h;
    t[row][cid * 4 + 0] = h.x; t[row][cid * 4 + 1] = h.y;
    t[row][cid * 4 + 2] = h.z; t[row][cid * 4 + 3] = h.w;
    __syncthreads();

    ushort4 o;
    o.x = t[cid * 4 + 0][row];
    o.y = t[cid * 4 + 1][row];
    o.z = t[cid * 4 + 2][row];
    o.w = t[cid * 4 + 3][row];
    *(ushort4*)&dstT[base + (long)(c0 + row) * R + r0 + cid * 4] = o;
}

__global__ __launch_bounds__(256)
void cast3(const float* __restrict__ s0, const float* __restrict__ s1,
           const float* __restrict__ s2, unsigned short* __restrict__ d0,
           unsigned short* __restrict__ d1, unsigned short* __restrict__ d2, int n4)
{
    const float* s = (blockIdx.y == 0) ? s0 : (blockIdx.y == 1) ? s1 : s2;
    unsigned short* d = (blockIdx.y == 0) ? d0 : (blockIdx.y == 1) ? d1 : d2;
    int i = blockIdx.x * 256 + threadIdx.x;
    if (i >= n4) return;
    float4 v = ((const float4*)s)[i];
    ushort4 o;
    o.x = f2bf(v.x); o.y = f2bf(v.y); o.z = f2bf(v.z); o.w = f2bf(v.w);
    ((ushort4*)d)[i] = o;
}

// ---------------------------------------------------------------------------
extern "C" void kernel_launch(void* const* d_in, const int* in_sizes, int n_in,
                              void* d_out, int out_size, void* d_ws, size_t ws_size,
                              hipStream_t stream)
{
    const float* x  = (const float*)d_in[0];
    const float* Wq = (const float*)d_in[1];
    const float* Wk = (const float*)d_in[2];
    const float* Wv = (const float*)d_in[3];
    const float* P  = (const float*)d_in[4];
    float* out = (float*)d_out;

    const long DD = (long)DIM * DIM;
    const long SD = (long)SEQ * DIM;

    // workspace layout (MiB offsets) — identical to round 7/8 (proven):
    //   [0,32) xb | [32,64) xTb -> Hb[32,40) Ntb[40,48) regB[48,64)
    //   [64,72) Gb | [72,84) weights | [84,84+split*9) regA gram partials
    uint8_t* ws = (uint8_t*)d_ws;
    unsigned short* xb   = (unsigned short*)(ws);
    unsigned short* xTb  = (unsigned short*)(ws + (32ul << 20));
    unsigned short* Hb   = (unsigned short*)(ws + (32ul << 20));
    unsigned short* Ntb  = (unsigned short*)(ws + (40ul << 20));
    float*          regB = (float*)(ws + (48ul << 20));
    unsigned short* Gb   = (unsigned short*)(ws + (64ul << 20));
    unsigned short* Wqb  = (unsigned short*)(ws + (72ul << 20));
    unsigned short* Ptb  = (unsigned short*)(ws + (74ul << 20));
    unsigned short* Wkb  = (unsigned short*)(ws + (76ul << 20));
    unsigned short* Wvb  = (unsigned short*)(ws + (78ul << 20));
    unsigned short* Ub   = (unsigned short*)(ws + (80ul << 20));
    unsigned short* W2Tb = (unsigned short*)(ws + (82ul << 20));
    float*          regA = (float*)(ws + (84ul << 20));

    const int split = (ws_size >= (156ul << 20)) ? 8 : 4;

    // 1) x -> xb, xTb ; P -> Pt ; Wq/Wk/Wv -> bf16
    transpose_cast<<<dim3(DIM / 32, SEQ / 32, BATCH), 256, 0, stream>>>(
        x, xb, xTb, SEQ, DIM);
    transpose_cast<<<dim3(DIM / 32, DIM / 32, 1), 256, 0, stream>>>(
        P, nullptr, Ptb, DIM, DIM);
    cast3<<<dim3((int)(DD / 4 / 256), 3), 256, 0, stream>>>(
        Wq, Wk, Wv, Wqb, Wkb, Wvb, (int)(DD / 4));

    // 2) G_b = xT_b @ xT_b^T — lower-triangle tiles, split-K compact partials
    gemm_db<3, true><<<dim3(36 * split * BATCH, 1, 1), 256, 0, stream>>>(
        xTb, xTb, regA, SEQ / split, split, SEQ, SEQ, DIM, SD, SD, 0);
    reduce_cast_tri<<<dim3(BATCH * 36 * 128 * 32 / 256), 256, 0, stream>>>(
        regA, Gb, split);
    sym_mirror<<<dim3(16, 28, BATCH), 256, 0, stream>>>(Gb);

    // 3) {U, W2T} split-K2: U = Wq@Wk^T ; W2T = Pt@Wv^T  (partials in regB)
    gemm_mfma<2, 64, false><<<dim3(16, 8, 4), 256, 0, stream>>>(
        Wqb, Wkb, regB, DIM / 2, 2, DIM, DIM, DIM, DD, DD, DD);
    reduce_cast_lin<<<dim3((int)(2 * DD / 4 / 256)), 256, 0, stream>>>(
        regB, Ub, 2, DD / 4);

    // 4) H_b = U @ G_b^T  (G symmetric)
    gemm_mfma<1, 64, false><<<dim3(16, 8, BATCH), 256, 0, stream>>>(
        Ub, Gb, Hb, DIM, 1, DIM, DIM, DIM, 0, DD, DD);

    // 5) Nt_b = W2T @ H_b^T + I   (residual folded in)
    gemm_mfma<1, 64, true><<<dim3(16, 8, BATCH), 256, 0, stream>>>(
        W2Tb, Hb, Ntb, DIM, 1, DIM, DIM, DIM, 0, DD, DD);

    // 6) out_b = xb_b @ Nt_b^T   (pure GEMM, fp32 out, deep pipeline)
    gemm_db<0, false><<<dim3(8, 32, BATCH), 256, 0, stream>>>(
        xb, Ntb, out, DIM, 1, DIM, DIM, DIM, SD, DD, SD);
}

// Round 10
// 176.979 us; speedup vs baseline: 6.8750x; 1.0430x over previous
//
#include <hip/hip_runtime.h>
#include <hip/hip_bf16.h>
#include <stdint.h>

// out = x + x * [ (Wq Wk^T) * (x^T x) * (Wv P) ]  ==  x @ (I + N),  N = U G W2
// All GEMMs use one deep-pipelined bf16 MFMA kernel (128xBN tile, BK=64,
// double-buffered LDS, counted vmcnt, stage-before-MFMA, split read||MFMA
// clusters, XOR-swizzled LDS via pre-swizzled global source, setprio).

#define BATCH 4
#define SEQ   4096
#define DIM   1024

#define TRI_SLICE 589824l       // 36 tiles * 128*128 floats per gram slice

typedef __bf16 bf16x8 __attribute__((ext_vector_type(8)));
typedef float f32x4 __attribute__((ext_vector_type(4)));

static __device__ __forceinline__ unsigned short f2bf(float f) {
    unsigned int u = __builtin_bit_cast(unsigned int, f);
    u += 0x7fff + ((u >> 16) & 1);              // RNE
    return (unsigned short)(u >> 16);
}

// ---------------------------------------------------------------------------
// Deep-pipelined bf16 MFMA GEMM: C = A @ Bt^T.  Tile 128 x BN, BK=64, 4 waves.
//  LDS [2][128][64]+[2][BN][64] double-buffer. Prefetch distance 2,
//  counted vmcnt(4+NF), per-tile schedule:
//    vmcnt -> bar -> reads0+reads1 -> MFMA0 (reads1 in flight)
//    -> lgkmcnt(0) -> SGB -> bar -> stage(t+2) -> SGB -> MFMA1
//  OUTMODE: 0 = fp32 out (Cg + b*sC)
//           1 = bf16 out (Cg + b*sC), optional identity add (ADD_I)
//           2 = fp32 partial, slice-indexed (Cg + z*sC)
//           3 = TRI compact fp32 partial (Cg + z*TRI_SLICE + tile*16384)
//  TRI: 1-D grid of 36 lower-triangle tiles per z (BN must be 128).
//  zdiv: z = b*zdiv + s; split s covers k-range [s*K, (s+1)*K).
//  Grid (flattened) must be a multiple of 8 (XCD swizzle). K/64 >= 2.
// ---------------------------------------------------------------------------
template<int OUTMODE, int BN, bool TRI, bool ADD_I>
__global__ __launch_bounds__(256)
void gemm_db(const unsigned short* __restrict__ Ag,
             const unsigned short* __restrict__ Btg,
             void* __restrict__ Cg,
             int K, int zdiv, int lda, int ldbt, int ldc,
             long sA, long sBt, long sC)
{
    constexpr int NF = BN / 32;             // B fragments per wave (2 or 4)
    __shared__ unsigned short As[2][128][64];
    __shared__ unsigned short Bs[2][BN][64];

    // ---- XCD-chunk bijective swizzle over the whole grid (nwg % 8 == 0)
    const int gx = gridDim.x, gy = gridDim.y;
    const int nwg = gx * gy * gridDim.z;
    int id = blockIdx.x + gx * (blockIdx.y + gy * blockIdx.z);
    id = (id & 7) * (nwg >> 3) + (id >> 3);

    int z, tlin = 0;
    long i0, j0;
    if (TRI) {
        z = id / 36;
        tlin = id % 36;
        int t = tlin, ti = 0;
        while (t > ti) { t -= ti + 1; ++ti; }
        i0 = (long)ti * 128;
        j0 = (long)t * 128;
    } else {
        const int bx = id % gx;
        const int rest = id / gx;
        const int by = rest % gy;
        z = rest / gy;
        i0 = (long)by * 128;
        j0 = (long)bx * BN;
    }
    const int b = z / zdiv;
    const long koff = (long)(z % zdiv) * K;

    const unsigned short* A  = Ag  + (long)b * sA  + koff;
    const unsigned short* Bt = Btg + (long)b * sBt + koff;

    const int tid  = threadIdx.x;
    const int lane = tid & 63;
    const int w    = tid >> 6;          // wave 0..3
    const int wr   = w >> 1, wc = w & 1;
    const int lrow = lane >> 3;         // 0..7
    const int lcol = lane & 7;          // 0..7 (16B granule)
    const int fr   = lane & 15;
    const int kg   = lane >> 4;         // 0..3
    const int scol = (lcol ^ lrow) * 8; // pre-swizzled global source chunk

    f32x4 acc[4][NF] = {};

    const int nt = K / 64;              // >= 2 always

    // stage K-tile t into buffer buf: (4 + NF) global_load_lds per thread
    auto stage = [&](int t, int buf) {
        const long kk = (long)t * 64;
#pragma unroll
        for (int inst = 0; inst < 4; ++inst) {
            const int row = w * 32 + inst * 8;
            const unsigned short* srcA = A + (i0 + row + lrow) * lda + kk + scol;
            __builtin_amdgcn_global_load_lds(
                (const __attribute__((address_space(1))) void*)srcA,
                (__attribute__((address_space(3))) void*)&As[buf][row][0], 16, 0, 0);
        }
#pragma unroll
        for (int inst = 0; inst < NF; ++inst) {
            const int row = w * (8 * NF) + inst * 8;
            const unsigned short* srcB = Bt + (j0 + row + lrow) * ldbt + kk + scol;
            __builtin_amdgcn_global_load_lds(
                (const __attribute__((address_space(1))) void*)srcB,
                (__attribute__((address_space(3))) void*)&Bs[buf][row][0], 16, 0, 0);
        }
    };

    // ---- prologue: prefetch tiles 0 and 1
    stage(0, 0);
    stage(1, 1);

    for (int t = 0; t < nt; ++t) {
        const int buf = t & 1;
        if (t < nt - 1) {
            if constexpr (BN == 128)
                asm volatile("s_waitcnt vmcnt(8)" ::: "memory");
            else
                asm volatile("s_waitcnt vmcnt(6)" ::: "memory");
        } else {
            asm volatile("s_waitcnt vmcnt(0)" ::: "memory");
        }
        __builtin_amdgcn_s_barrier();
        asm volatile("" ::: "memory");

        // issue both half-tile read bursts back-to-back
        bf16x8 af0[4], bf0[NF], af1[4], bf1[NF];
        const int ch0 = (kg ^ (fr & 7)) * 8;
        const int ch1 = ((4 + kg) ^ (fr & 7)) * 8;
#pragma unroll
        for (int m = 0; m < 4; ++m)
            af0[m] = *(const bf16x8*)&As[buf][wr * 64 + m * 16 + fr][ch0];
#pragma unroll
        for (int n = 0; n < NF; ++n)
            bf0[n] = *(const bf16x8*)&Bs[buf][wc * (BN / 2) + n * 16 + fr][ch0];
#pragma unroll
        for (int m = 0; m < 4; ++m)
            af1[m] = *(const bf16x8*)&As[buf][wr * 64 + m * 16 + fr][ch1];
#pragma unroll
        for (int n = 0; n < NF; ++n)
            bf1[n] = *(const bf16x8*)&Bs[buf][wc * (BN / 2) + n * 16 + fr][ch1];

        // MFMA cluster 0 — compiler inserts the partial lgkmcnt for af0/bf0,
        // reads of cluster 1 complete in flight underneath
        __builtin_amdgcn_s_setprio(1);
#pragma unroll
        for (int m = 0; m < 4; ++m)
#pragma unroll
            for (int n = 0; n < NF; ++n)
                acc[m][n] = __builtin_amdgcn_mfma_f32_16x16x32_bf16(
                    af0[m], bf0[n], acc[m][n], 0, 0, 0);
        __builtin_amdgcn_s_setprio(0);

        asm volatile("s_waitcnt lgkmcnt(0)" ::: "memory");
        __builtin_amdgcn_sched_barrier(0);       // rule #18: pin the wait
        __builtin_amdgcn_s_barrier();            // all waves done reading buf
        asm volatile("" ::: "memory");

        if (t + 2 < nt) stage(t + 2, buf);       // loads fly under MFMA1
        __builtin_amdgcn_sched_barrier(0);       // pin: stage issued first

        __builtin_amdgcn_s_setprio(1);
#pragma unroll
        for (int m = 0; m < 4; ++m)
#pragma unroll
            for (int n = 0; n < NF; ++n)
                acc[m][n] = __builtin_amdgcn_mfma_f32_16x16x32_bf16(
                    af1[m], bf1[n], acc[m][n], 0, 0, 0);
        __builtin_amdgcn_s_setprio(0);
    }

    // ---- epilogue: C/D layout col = lane&15, row = (lane>>4)*4 + q
    if (OUTMODE == 3) {
        float* Cp = (float*)Cg + (long)z * TRI_SLICE + (long)tlin * 16384;
#pragma unroll
        for (int m = 0; m < 4; ++m) {
            const int lrb = wr * 64 + m * 16 + kg * 4;
#pragma unroll
            for (int n = 0; n < NF; ++n) {
                const int lc = wc * (BN / 2) + n * 16 + fr;
#pragma unroll
                for (int q = 0; q < 4; ++q)
                    Cp[(lrb + q) * 128 + lc] = acc[m][n][q];
            }
        }
        return;
    }

    unsigned short* C16 = (OUTMODE == 1) ? ((unsigned short*)Cg + (long)b * sC) : nullptr;
    float*          C32 = (OUTMODE == 0) ? ((float*)Cg + (long)b * sC)
                        : (OUTMODE == 2) ? ((float*)Cg + (long)z * sC) : nullptr;
#pragma unroll
    for (int m = 0; m < 4; ++m) {
        const long rbase = i0 + wr * 64 + m * 16 + kg * 4;
#pragma unroll
        for (int n = 0; n < NF; ++n) {
            const long col = j0 + wc * (BN / 2) + n * 16 + fr;
#pragma unroll
            for (int q = 0; q < 4; ++q) {
                const long r = rbase + q;
                float v = acc[m][n][q];
                if (ADD_I && r == col) v += 1.0f;
                if (OUTMODE == 1) C16[r * ldc + col] = f2bf(v);
                else              C32[r * ldc + col] = v;
            }
        }
    }
}

// ---------------------------------------------------------------------------
__global__ __launch_bounds__(256)
void reduce_cast_tri(const float* __restrict__ part, unsigned short* __restrict__ outG,
                     int split)
{
    const long DD = (long)DIM * DIM;
    int id = blockIdx.x * 256 + threadIdx.x;
    const int b  = id / 147456;          // 36*128*32
    int rem      = id % 147456;
    const int tlin = rem / 4096;
    const int rr = rem % 4096;
    const int r  = rr >> 5;
    const int c4 = rr & 31;
    int t = tlin, ti = 0;
    while (t > ti) { t -= ti + 1; ++ti; }
    const long off = (long)tlin * 16384 + r * 128 + c4 * 4;

    float4 s = make_float4(0.f, 0.f, 0.f, 0.f);
    for (int sp = 0; sp < split; ++sp) {
        float4 v = *(const float4*)&part[(long)(b * split + sp) * TRI_SLICE + off];
        s.x += v.x; s.y += v.y; s.z += v.z; s.w += v.w;
    }
    ushort4 o;
    o.x = f2bf(s.x); o.y = f2bf(s.y); o.z = f2bf(s.z); o.w = f2bf(s.w);
    *(ushort4*)&outG[b * DD + ((long)ti * 128 + r) * DIM + (long)t * 128 + c4 * 4] = o;
}

__global__ __launch_bounds__(256)
void reduce_cast_lin(const float* __restrict__ part, unsigned short* __restrict__ out,
                     int split, long len4)
{
    long i = (long)blockIdx.x * 256 + threadIdx.x;
    const long slab = i / len4;
    const long r = i % len4;
    float4 s = make_float4(0.f, 0.f, 0.f, 0.f);
    for (int sp = 0; sp < split; ++sp) {
        float4 v = ((const float4*)part)[(slab * split + sp) * len4 + r];
        s.x += v.x; s.y += v.y; s.z += v.z; s.w += v.w;
    }
    ushort4 o;
    o.x = f2bf(s.x); o.y = f2bf(s.y); o.z = f2bf(s.z); o.w = f2bf(s.w);
    ((ushort4*)out)[i] = o;
}

__global__ __launch_bounds__(256)
void sym_mirror(unsigned short* __restrict__ G)
{
    __shared__ unsigned short t[32][36];
    const long DD = (long)DIM * DIM;
    unsigned short* Gb = G + (long)blockIdx.z * DD;

    int u = blockIdx.y;
    int tj = 1;
    while (u >= tj) { u -= tj; ++tj; }
    const int ti = u;                    // ti < tj

    const int sr = blockIdx.x >> 2;
    const int sc = blockIdx.x & 3;
    const int row = threadIdx.x >> 3;
    const int cid = threadIdx.x & 7;

    const long srow = (long)tj * 128 + sr * 32 + row;
    const long scol = (long)ti * 128 + sc * 32 + cid * 4;
    ushort4 v = *(const ushort4*)&Gb[srow * DIM + scol];
    t[row][cid * 4 + 0] = v.x; t[row][cid * 4 + 1] = v.y;
    t[row][cid * 4 + 2] = v.z; t[row][cid * 4 + 3] = v.w;
    __syncthreads();

    const long drow = (long)ti * 128 + sc * 32 + row;
    const long dcol = (long)tj * 128 + sr * 32 + cid * 4;
    ushort4 o;
    o.x = t[cid * 4 + 0][row];
    o.y = t[cid * 4 + 1][row];
    o.z = t[cid * 4 + 2][row];
    o.w = t[cid * 4 + 3][row];
    *(ushort4*)&Gb[drow * DIM + dcol] = o;
}

__global__ __launch_bounds__(256)
void transpose_cast(const float* __restrict__ src, unsigned short* __restrict__ dst,
                    unsigned short* __restrict__ dstT, int R, int C)
{
    __shared__ unsigned short t[32][33];
    const int b = blockIdx.z;
    const long base = (long)b * R * C;
    const int r0 = blockIdx.y * 32;
    const int c0 = blockIdx.x * 32;
    const int row = threadIdx.x >> 3;
    const int cid = threadIdx.x & 7;

    float4 v = *(const float4*)&src[base + (long)(r0 + row) * C + c0 + cid * 4];
    ushort4 h;
    h.x = f2bf(v.x); h.y = f2bf(v.y); h.z = f2bf(v.z); h.w = f2bf(v.w);
    if (dst) *(ushort4*)&dst[base + (long)(r0 + row) * C + c0 + cid * 4] = h;
    t[row][cid * 4 + 0] = h.x; t[row][cid * 4 + 1] = h.y;
    t[row][cid * 4 + 2] = h.z; t[row][cid * 4 + 3] = h.w;
    __syncthreads();

    ushort4 o;
    o.x = t[cid * 4 + 0][row];
    o.y = t[cid * 4 + 1][row];
    o.z = t[cid * 4 + 2][row];
    o.w = t[cid * 4 + 3][row];
    *(ushort4*)&dstT[base + (long)(c0 + row) * R + r0 + cid * 4] = o;
}

__global__ __launch_bounds__(256)
void cast3(const float* __restrict__ s0, const float* __restrict__ s1,
           const float* __restrict__ s2, unsigned short* __restrict__ d0,
           unsigned short* __restrict__ d1, unsigned short* __restrict__ d2, int n4)
{
    const float* s = (blockIdx.y == 0) ? s0 : (blockIdx.y == 1) ? s1 : s2;
    unsigned short* d = (blockIdx.y == 0) ? d0 : (blockIdx.y == 1) ? d1 : d2;
    int i = blockIdx.x * 256 + threadIdx.x;
    if (i >= n4) return;
    float4 v = ((const float4*)s)[i];
    ushort4 o;
    o.x = f2bf(v.x); o.y = f2bf(v.y); o.z = f2bf(v.z); o.w = f2bf(v.w);
    ((ushort4*)d)[i] = o;
}

// ---------------------------------------------------------------------------
extern "C" void kernel_launch(void* const* d_in, const int* in_sizes, int n_in,
                              void* d_out, int out_size, void* d_ws, size_t ws_size,
                              hipStream_t stream)
{
    const float* x  = (const float*)d_in[0];
    const float* Wq = (const float*)d_in[1];
    const float* Wk = (const float*)d_in[2];
    const float* Wv = (const float*)d_in[3];
    const float* P  = (const float*)d_in[4];
    float* out = (float*)d_out;

    const long DD = (long)DIM * DIM;
    const long SD = (long)SEQ * DIM;

    // workspace layout (MiB offsets) — identical to rounds 7-9 (proven):
    //   [0,32) xb | [32,64) xTb -> Hb[32,40) Ntb[40,48) regB[48,64)
    //   [64,72) Gb | [72,84) weights | [84,84+split*9) regA gram partials
    uint8_t* ws = (uint8_t*)d_ws;
    unsigned short* xb   = (unsigned short*)(ws);
    unsigned short* xTb  = (unsigned short*)(ws + (32ul << 20));
    unsigned short* Hb   = (unsigned short*)(ws + (32ul << 20));
    unsigned short* Ntb  = (unsigned short*)(ws + (40ul << 20));
    float*          regB = (float*)(ws + (48ul << 20));
    unsigned short* Gb   = (unsigned short*)(ws + (64ul << 20));
    unsigned short* Wqb  = (unsigned short*)(ws + (72ul << 20));
    unsigned short* Ptb  = (unsigned short*)(ws + (74ul << 20));
    unsigned short* Wkb  = (unsigned short*)(ws + (76ul << 20));
    unsigned short* Wvb  = (unsigned short*)(ws + (78ul << 20));
    unsigned short* Ub   = (unsigned short*)(ws + (80ul << 20));
    unsigned short* W2Tb = (unsigned short*)(ws + (82ul << 20));
    float*          regA = (float*)(ws + (84ul << 20));

    const int split = (ws_size >= (156ul << 20)) ? 8 : 4;

    // 1) x -> xb, xTb ; P -> Pt ; Wq/Wk/Wv -> bf16
    transpose_cast<<<dim3(DIM / 32, SEQ / 32, BATCH), 256, 0, stream>>>(
        x, xb, xTb, SEQ, DIM);
    transpose_cast<<<dim3(DIM / 32, DIM / 32, 1), 256, 0, stream>>>(
        P, nullptr, Ptb, DIM, DIM);
    cast3<<<dim3((int)(DD / 4 / 256), 3), 256, 0, stream>>>(
        Wq, Wk, Wv, Wqb, Wkb, Wvb, (int)(DD / 4));

    // 2) G_b = xT_b @ xT_b^T — lower-triangle tiles, split-K compact partials
    gemm_db<3, 128, true, false><<<dim3(36 * split * BATCH, 1, 1), 256, 0, stream>>>(
        xTb, xTb, regA, SEQ / split, split, SEQ, SEQ, DIM, SD, SD, 0);
    reduce_cast_tri<<<dim3(BATCH * 36 * 128 * 32 / 256), 256, 0, stream>>>(
        regA, Gb, split);
    sym_mirror<<<dim3(16, 28, BATCH), 256, 0, stream>>>(Gb);

    // 3) {U, W2T} split-K2: U = Wq@Wk^T ; W2T = Pt@Wv^T  (partials in regB)
    gemm_db<2, 64, false, false><<<dim3(16, 8, 4), 256, 0, stream>>>(
        Wqb, Wkb, regB, DIM / 2, 2, DIM, DIM, DIM, DD, DD, DD);
    reduce_cast_lin<<<dim3((int)(2 * DD / 4 / 256)), 256, 0, stream>>>(
        regB, Ub, 2, DD / 4);

    // 4) H_b = U @ G_b^T  (G symmetric)
    gemm_db<1, 64, false, false><<<dim3(16, 8, BATCH), 256, 0, stream>>>(
        Ub, Gb, Hb, DIM, 1, DIM, DIM, DIM, 0, DD, DD);

    // 5) Nt_b = W2T @ H_b^T + I   (residual folded in)
    gemm_db<1, 64, false, true><<<dim3(16, 8, BATCH), 256, 0, stream>>>(
        W2Tb, Hb, Ntb, DIM, 1, DIM, DIM, DIM, 0, DD, DD);

    // 6) out_b = xb_b @ Nt_b^T   (pure GEMM, fp32 out)
    gemm_db<0, 128, false, false><<<dim3(8, 32, BATCH), 256, 0, stream>>>(
        xb, Ntb, out, DIM, 1, DIM, DIM, DIM, SD, DD, SD);
}

// Round 11
// 176.767 us; speedup vs baseline: 6.8833x; 1.0012x over previous
//
#include <hip/hip_runtime.h>
#include <hip/hip_bf16.h>
#include <stdint.h>

// out = x + x * [ (Wq Wk^T) * (x^T x) * (Wv P) ]  ==  x @ (I + N),  N = U G W2
// Final GEMM: 256x256 tile, 8 waves, per-wave 128x64 (1.33x better FLOP/LDS-byte),
// counted-vmcnt double-buffered pipeline. Gram/chain: proven 128xBN pipeline.

#define BATCH 4
#define SEQ   4096
#define DIM   1024

#define TRI_SLICE 589824l       // 36 tiles * 128*128 floats per gram slice

typedef __bf16 bf16x8 __attribute__((ext_vector_type(8)));
typedef float f32x4 __attribute__((ext_vector_type(4)));

static __device__ __forceinline__ unsigned short f2bf(float f) {
    unsigned int u = __builtin_bit_cast(unsigned int, f);
    u += 0x7fff + ((u >> 16) & 1);              // RNE
    return (unsigned short)(u >> 16);
}

// ---------------------------------------------------------------------------
// 256x256-tile deep-pipelined bf16 MFMA GEMM: C = A @ Bt^T (fp32 out).
//  512 threads = 8 waves (2M x 4N), per-wave 128x64 output.
//  LDS [2][256][64] x2 = 128 KiB (1 block/CU). Same vmcnt(8) protocol as the
//  128-tile kernel (8 global_load_lds per thread per K-tile).
//  Grid: (N/256, M/256, BATCH); flattened nwg % 8 == 0. K/64 >= 2.
// ---------------------------------------------------------------------------
__global__ __launch_bounds__(512)
void gemm_db256(const unsigned short* __restrict__ Ag,
                const unsigned short* __restrict__ Btg,
                float* __restrict__ Cg,
                int K, int lda, int ldbt, int ldc,
                long sA, long sBt, long sC)
{
    __shared__ unsigned short As[2][256][64];
    __shared__ unsigned short Bs[2][256][64];

    const int gx = gridDim.x, gy = gridDim.y;
    const int nwg = gx * gy * gridDim.z;
    int id = blockIdx.x + gx * (blockIdx.y + gy * blockIdx.z);
    id = (id & 7) * (nwg >> 3) + (id >> 3);

    const int bx = id % gx;
    const int rest = id / gx;
    const int by = rest % gy;
    const int b = rest / gy;
    const long i0 = (long)by * 256;
    const long j0 = (long)bx * 256;

    const unsigned short* A  = Ag  + (long)b * sA;
    const unsigned short* Bt = Btg + (long)b * sBt;

    const int tid  = threadIdx.x;
    const int lane = tid & 63;
    const int w    = tid >> 6;          // wave 0..7
    const int wr   = w >> 2;            // 0..1  (M half)
    const int wc   = w & 3;             // 0..3  (N quarter)
    const int lrow = lane >> 3;         // 0..7
    const int lcol = lane & 7;          // 0..7 (16B granule)
    const int fr   = lane & 15;
    const int kg   = lane >> 4;         // 0..3
    const int scol = (lcol ^ lrow) * 8; // pre-swizzled global source chunk

    f32x4 acc[8][4] = {};

    const int nt = K / 64;

    // stage K-tile t: wave w stages 32 rows of A and 32 rows of B (8 loads)
    auto stage = [&](int t, int buf) {
        const long kk = (long)t * 64;
#pragma unroll
        for (int inst = 0; inst < 4; ++inst) {
            const int row = w * 32 + inst * 8;
            const unsigned short* srcA = A + (i0 + row + lrow) * lda + kk + scol;
            __builtin_amdgcn_global_load_lds(
                (const __attribute__((address_space(1))) void*)srcA,
                (__attribute__((address_space(3))) void*)&As[buf][row][0], 16, 0, 0);
            const unsigned short* srcB = Bt + (j0 + row + lrow) * ldbt + kk + scol;
            __builtin_amdgcn_global_load_lds(
                (const __attribute__((address_space(1))) void*)srcB,
                (__attribute__((address_space(3))) void*)&Bs[buf][row][0], 16, 0, 0);
        }
    };

    stage(0, 0);
    stage(1, 1);

    for (int t = 0; t < nt; ++t) {
        const int buf = t & 1;
        if (t < nt - 1) asm volatile("s_waitcnt vmcnt(8)" ::: "memory");
        else            asm volatile("s_waitcnt vmcnt(0)" ::: "memory");
        __builtin_amdgcn_s_barrier();
        asm volatile("" ::: "memory");

        // ---- cluster 0: reads (12 x b128) + MFMA (32)
        const int ch0 = (kg ^ (fr & 7)) * 8;
        bf16x8 af0[8], bf0[4];
#pragma unroll
        for (int m = 0; m < 8; ++m)
            af0[m] = *(const bf16x8*)&As[buf][wr * 128 + m * 16 + fr][ch0];
#pragma unroll
        for (int n = 0; n < 4; ++n)
            bf0[n] = *(const bf16x8*)&Bs[buf][wc * 64 + n * 16 + fr][ch0];
        __builtin_amdgcn_s_setprio(1);
#pragma unroll
        for (int m = 0; m < 8; ++m)
#pragma unroll
            for (int n = 0; n < 4; ++n)
                acc[m][n] = __builtin_amdgcn_mfma_f32_16x16x32_bf16(
                    af0[m], bf0[n], acc[m][n], 0, 0, 0);
        __builtin_amdgcn_s_setprio(0);

        // ---- cluster 1 reads
        const int ch1 = ((4 + kg) ^ (fr & 7)) * 8;
        bf16x8 af1[8], bf1[4];
#pragma unroll
        for (int m = 0; m < 8; ++m)
            af1[m] = *(const bf16x8*)&As[buf][wr * 128 + m * 16 + fr][ch1];
#pragma unroll
        for (int n = 0; n < 4; ++n)
            bf1[n] = *(const bf16x8*)&Bs[buf][wc * 64 + n * 16 + fr][ch1];

        asm volatile("s_waitcnt lgkmcnt(0)" ::: "memory");
        __builtin_amdgcn_sched_barrier(0);
        __builtin_amdgcn_s_barrier();          // all waves done reading buf
        asm volatile("" ::: "memory");

        if (t + 2 < nt) stage(t + 2, buf);     // loads fly under MFMA cluster 1
        __builtin_amdgcn_sched_barrier(0);

        __builtin_amdgcn_s_setprio(1);
#pragma unroll
        for (int m = 0; m < 8; ++m)
#pragma unroll
            for (int n = 0; n < 4; ++n)
                acc[m][n] = __builtin_amdgcn_mfma_f32_16x16x32_bf16(
                    af1[m], bf1[n], acc[m][n], 0, 0, 0);
        __builtin_amdgcn_s_setprio(0);
    }

    // ---- epilogue: C/D layout col = lane&15, row = (lane>>4)*4 + q
    float* C32 = Cg + (long)b * sC;
#pragma unroll
    for (int m = 0; m < 8; ++m) {
        const long rbase = i0 + wr * 128 + m * 16 + kg * 4;
#pragma unroll
        for (int n = 0; n < 4; ++n) {
            const long col = j0 + wc * 64 + n * 16 + fr;
#pragma unroll
            for (int q = 0; q < 4; ++q)
                C32[(rbase + q) * ldc + col] = acc[m][n][q];
        }
    }
}

// ---------------------------------------------------------------------------
// 128 x BN deep-pipelined bf16 MFMA GEMM (proven rounds 9-10) — gram + chain.
//  OUTMODE: 0 fp32 out; 1 bf16 out (+ADD_I); 2 fp32 slice partials;
//           3 TRI compact fp32 partial.
// ---------------------------------------------------------------------------
template<int OUTMODE, int BN, bool TRI, bool ADD_I>
__global__ __launch_bounds__(256)
void gemm_db(const unsigned short* __restrict__ Ag,
             const unsigned short* __restrict__ Btg,
             void* __restrict__ Cg,
             int K, int zdiv, int lda, int ldbt, int ldc,
             long sA, long sBt, long sC)
{
    constexpr int NF = BN / 32;             // B fragments per wave (2 or 4)
    __shared__ unsigned short As[2][128][64];
    __shared__ unsigned short Bs[2][BN][64];

    const int gx = gridDim.x, gy = gridDim.y;
    const int nwg = gx * gy * gridDim.z;
    int id = blockIdx.x + gx * (blockIdx.y + gy * blockIdx.z);
    id = (id & 7) * (nwg >> 3) + (id >> 3);

    int z, tlin = 0;
    long i0, j0;
    if (TRI) {
        z = id / 36;
        tlin = id % 36;
        int t = tlin, ti = 0;
        while (t > ti) { t -= ti + 1; ++ti; }
        i0 = (long)ti * 128;
        j0 = (long)t * 128;
    } else {
        const int bx = id % gx;
        const int rest = id / gx;
        const int by = rest % gy;
        z = rest / gy;
        i0 = (long)by * 128;
        j0 = (long)bx * BN;
    }
    const int b = z / zdiv;
    const long koff = (long)(z % zdiv) * K;

    const unsigned short* A  = Ag  + (long)b * sA  + koff;
    const unsigned short* Bt = Btg + (long)b * sBt + koff;

    const int tid  = threadIdx.x;
    const int lane = tid & 63;
    const int w    = tid >> 6;          // wave 0..3
    const int wr   = w >> 1, wc = w & 1;
    const int lrow = lane >> 3;         // 0..7
    const int lcol = lane & 7;          // 0..7 (16B granule)
    const int fr   = lane & 15;
    const int kg   = lane >> 4;         // 0..3
    const int scol = (lcol ^ lrow) * 8; // pre-swizzled global source chunk

    f32x4 acc[4][NF] = {};

    const int nt = K / 64;              // >= 2 always

    auto stage = [&](int t, int buf) {
        const long kk = (long)t * 64;
#pragma unroll
        for (int inst = 0; inst < 4; ++inst) {
            const int row = w * 32 + inst * 8;
            const unsigned short* srcA = A + (i0 + row + lrow) * lda + kk + scol;
            __builtin_amdgcn_global_load_lds(
                (const __attribute__((address_space(1))) void*)srcA,
                (__attribute__((address_space(3))) void*)&As[buf][row][0], 16, 0, 0);
        }
#pragma unroll
        for (int inst = 0; inst < NF; ++inst) {
            const int row = w * (8 * NF) + inst * 8;
            const unsigned short* srcB = Bt + (j0 + row + lrow) * ldbt + kk + scol;
            __builtin_amdgcn_global_load_lds(
                (const __attribute__((address_space(1))) void*)srcB,
                (__attribute__((address_space(3))) void*)&Bs[buf][row][0], 16, 0, 0);
        }
    };

    stage(0, 0);
    stage(1, 1);

    for (int t = 0; t < nt; ++t) {
        const int buf = t & 1;
        if (t < nt - 1) {
            if constexpr (BN == 128)
                asm volatile("s_waitcnt vmcnt(8)" ::: "memory");
            else
                asm volatile("s_waitcnt vmcnt(6)" ::: "memory");
        } else {
            asm volatile("s_waitcnt vmcnt(0)" ::: "memory");
        }
        __builtin_amdgcn_s_barrier();
        asm volatile("" ::: "memory");

        bf16x8 af0[4], bf0[NF], af1[4], bf1[NF];
        const int ch0 = (kg ^ (fr & 7)) * 8;
        const int ch1 = ((4 + kg) ^ (fr & 7)) * 8;
#pragma unroll
        for (int m = 0; m < 4; ++m)
            af0[m] = *(const bf16x8*)&As[buf][wr * 64 + m * 16 + fr][ch0];
#pragma unroll
        for (int n = 0; n < NF; ++n)
            bf0[n] = *(const bf16x8*)&Bs[buf][wc * (BN / 2) + n * 16 + fr][ch0];
#pragma unroll
        for (int m = 0; m < 4; ++m)
            af1[m] = *(const bf16x8*)&As[buf][wr * 64 + m * 16 + fr][ch1];
#pragma unroll
        for (int n = 0; n < NF; ++n)
            bf1[n] = *(const bf16x8*)&Bs[buf][wc * (BN / 2) + n * 16 + fr][ch1];

        __builtin_amdgcn_s_setprio(1);
#pragma unroll
        for (int m = 0; m < 4; ++m)
#pragma unroll
            for (int n = 0; n < NF; ++n)
                acc[m][n] = __builtin_amdgcn_mfma_f32_16x16x32_bf16(
                    af0[m], bf0[n], acc[m][n], 0, 0, 0);
        __builtin_amdgcn_s_setprio(0);

        asm volatile("s_waitcnt lgkmcnt(0)" ::: "memory");
        __builtin_amdgcn_sched_barrier(0);
        __builtin_amdgcn_s_barrier();
        asm volatile("" ::: "memory");

        if (t + 2 < nt) stage(t + 2, buf);
        __builtin_amdgcn_sched_barrier(0);

        __builtin_amdgcn_s_setprio(1);
#pragma unroll
        for (int m = 0; m < 4; ++m)
#pragma unroll
            for (int n = 0; n < NF; ++n)
                acc[m][n] = __builtin_amdgcn_mfma_f32_16x16x32_bf16(
                    af1[m], bf1[n], acc[m][n], 0, 0, 0);
        __builtin_amdgcn_s_setprio(0);
    }

    if (OUTMODE == 3) {
        float* Cp = (float*)Cg + (long)z * TRI_SLICE + (long)tlin * 16384;
#pragma unroll
        for (int m = 0; m < 4; ++m) {
            const int lrb = wr * 64 + m * 16 + kg * 4;
#pragma unroll
            for (int n = 0; n < NF; ++n) {
                const int lc = wc * (BN / 2) + n * 16 + fr;
#pragma unroll
                for (int q = 0; q < 4; ++q)
                    Cp[(lrb + q) * 128 + lc] = acc[m][n][q];
            }
        }
        return;
    }

    unsigned short* C16 = (OUTMODE == 1) ? ((unsigned short*)Cg + (long)b * sC) : nullptr;
    float*          C32 = (OUTMODE == 0) ? ((float*)Cg + (long)b * sC)
                        : (OUTMODE == 2) ? ((float*)Cg + (long)z * sC) : nullptr;
#pragma unroll
    for (int m = 0; m < 4; ++m) {
        const long rbase = i0 + wr * 64 + m * 16 + kg * 4;
#pragma unroll
        for (int n = 0; n < NF; ++n) {
            const long col = j0 + wc * (BN / 2) + n * 16 + fr;
#pragma unroll
            for (int q = 0; q < 4; ++q) {
                const long r = rbase + q;
                float v = acc[m][n][q];
                if (ADD_I && r == col) v += 1.0f;
                if (OUTMODE == 1) C16[r * ldc + col] = f2bf(v);
                else              C32[r * ldc + col] = v;
            }
        }
    }
}

// ---------------------------------------------------------------------------
__global__ __launch_bounds__(256)
void reduce_cast_tri(const float* __restrict__ part, unsigned short* __restrict__ outG,
                     int split)
{
    const long DD = (long)DIM * DIM;
    int id = blockIdx.x * 256 + threadIdx.x;
    const int b  = id / 147456;          // 36*128*32
    int rem      = id % 147456;
    const int tlin = rem / 4096;
    const int rr = rem % 4096;
    const int r  = rr >> 5;
    const int c4 = rr & 31;
    int t = tlin, ti = 0;
    while (t > ti) { t -= ti + 1; ++ti; }
    const long off = (long)tlin * 16384 + r * 128 + c4 * 4;

    float4 s = make_float4(0.f, 0.f, 0.f, 0.f);
    for (int sp = 0; sp < split; ++sp) {
        float4 v = *(const float4*)&part[(long)(b * split + sp) * TRI_SLICE + off];
        s.x += v.x; s.y += v.y; s.z += v.z; s.w += v.w;
    }
    ushort4 o;
    o.x = f2bf(s.x); o.y = f2bf(s.y); o.z = f2bf(s.z); o.w = f2bf(s.w);
    *(ushort4*)&outG[b * DD + ((long)ti * 128 + r) * DIM + (long)t * 128 + c4 * 4] = o;
}

__global__ __launch_bounds__(256)
void reduce_cast_lin(const float* __restrict__ part, unsigned short* __restrict__ out,
                     int split, long len4)
{
    long i = (long)blockIdx.x * 256 + threadIdx.x;
    const long slab = i / len4;
    const long r = i % len4;
    float4 s = make_float4(0.f, 0.f, 0.f, 0.f);
    for (int sp = 0; sp < split; ++sp) {
        float4 v = ((const float4*)part)[(slab * split + sp) * len4 + r];
        s.x += v.x; s.y += v.y; s.z += v.z; s.w += v.w;
    }
    ushort4 o;
    o.x = f2bf(s.x); o.y = f2bf(s.y); o.z = f2bf(s.z); o.w = f2bf(s.w);
    ((ushort4*)out)[i] = o;
}

__global__ __launch_bounds__(256)
void sym_mirror(unsigned short* __restrict__ G)
{
    __shared__ unsigned short t[32][36];
    const long DD = (long)DIM * DIM;
    unsigned short* Gb = G + (long)blockIdx.z * DD;

    int u = blockIdx.y;
    int tj = 1;
    while (u >= tj) { u -= tj; ++tj; }
    const int ti = u;                    // ti < tj

    const int sr = blockIdx.x >> 2;
    const int sc = blockIdx.x & 3;
    const int row = threadIdx.x >> 3;
    const int cid = threadIdx.x & 7;

    const long srow = (long)tj * 128 + sr * 32 + row;
    const long scol = (long)ti * 128 + sc * 32 + cid * 4;
    ushort4 v = *(const ushort4*)&Gb[srow * DIM + scol];
    t[row][cid * 4 + 0] = v.x; t[row][cid * 4 + 1] = v.y;
    t[row][cid * 4 + 2] = v.z; t[row][cid * 4 + 3] = v.w;
    __syncthreads();

    const long drow = (long)ti * 128 + sc * 32 + row;
    const long dcol = (long)tj * 128 + sr * 32 + cid * 4;
    ushort4 o;
    o.x = t[cid * 4 + 0][row];
    o.y = t[cid * 4 + 1][row];
    o.z = t[cid * 4 + 2][row];
    o.w = t[cid * 4 + 3][row];
    *(ushort4*)&Gb[drow * DIM + dcol] = o;
}

__global__ __launch_bounds__(256)
void transpose_cast(const float* __restrict__ src, unsigned short* __restrict__ dst,
                    unsigned short* __restrict__ dstT, int R, int C)
{
    __shared__ unsigned short t[32][33];
    const int b = blockIdx.z;
    const long base = (long)b * R * C;
    const int r0 = blockIdx.y * 32;
    const int c0 = blockIdx.x * 32;
    const int row = threadIdx.x >> 3;
    const int cid = threadIdx.x & 7;

    float4 v = *(const float4*)&src[base + (long)(r0 + row) * C + c0 + cid * 4];
    ushort4 h;
    h.x = f2bf(v.x); h.y = f2bf(v.y); h.z = f2bf(v.z); h.w = f2bf(v.w);
    if (dst) *(ushort4*)&dst[base + (long)(r0 + row) * C + c0 + cid * 4] = h;
    t[row][cid * 4 + 0] = h.x; t[row][cid * 4 + 1] = h.y;
    t[row][cid * 4 + 2] = h.z; t[row][cid * 4 + 3] = h.w;
    __syncthreads();

    ushort4 o;
    o.x = t[cid * 4 + 0][row];
    o.y = t[cid * 4 + 1][row];
    o.z = t[cid * 4 + 2][row];
    o.w = t[cid * 4 + 3][row];
    *(ushort4*)&dstT[base + (long)(c0 + row) * R + r0 + cid * 4] = o;
}

__global__ __launch_bounds__(256)
void cast3(const float* __restrict__ s0, const float* __restrict__ s1,
           const float* __restrict__ s2, unsigned short* __restrict__ d0,
           unsigned short* __restrict__ d1, unsigned short* __restrict__ d2, int n4)
{
    const float* s = (blockIdx.y == 0) ? s0 : (blockIdx.y == 1) ? s1 : s2;
    unsigned short* d = (blockIdx.y == 0) ? d0 : (blockIdx.y == 1) ? d1 : d2;
    int i = blockIdx.x * 256 + threadIdx.x;
    if (i >= n4) return;
    float4 v = ((const float4*)s)[i];
    ushort4 o;
    o.x = f2bf(v.x); o.y = f2bf(v.y); o.z = f2bf(v.z); o.w = f2bf(v.w);
    ((ushort4*)d)[i] = o;
}

// ---------------------------------------------------------------------------
extern "C" void kernel_launch(void* const* d_in, const int* in_sizes, int n_in,
                              void* d_out, int out_size, void* d_ws, size_t ws_size,
                              hipStream_t stream)
{
    const float* x  = (const float*)d_in[0];
    const float* Wq = (const float*)d_in[1];
    const float* Wk = (const float*)d_in[2];
    const float* Wv = (const float*)d_in[3];
    const float* P  = (const float*)d_in[4];
    float* out = (float*)d_out;

    const long DD = (long)DIM * DIM;
    const long SD = (long)SEQ * DIM;

    // workspace layout (MiB offsets) — identical to rounds 7-10 (proven):
    //   [0,32) xb | [32,64) xTb -> Hb[32,40) Ntb[40,48) regB[48,64)
    //   [64,72) Gb | [72,84) weights | [84,84+split*9) regA gram partials
    uint8_t* ws = (uint8_t*)d_ws;
    unsigned short* xb   = (unsigned short*)(ws);
    unsigned short* xTb  = (unsigned short*)(ws + (32ul << 20));
    unsigned short* Hb   = (unsigned short*)(ws + (32ul << 20));
    unsigned short* Ntb  = (unsigned short*)(ws + (40ul << 20));
    float*          regB = (float*)(ws + (48ul << 20));
    unsigned short* Gb   = (unsigned short*)(ws + (64ul << 20));
    unsigned short* Wqb  = (unsigned short*)(ws + (72ul << 20));
    unsigned short* Ptb  = (unsigned short*)(ws + (74ul << 20));
    unsigned short* Wkb  = (unsigned short*)(ws + (76ul << 20));
    unsigned short* Wvb  = (unsigned short*)(ws + (78ul << 20));
    unsigned short* Ub   = (unsigned short*)(ws + (80ul << 20));
    unsigned short* W2Tb = (unsigned short*)(ws + (82ul << 20));
    float*          regA = (float*)(ws + (84ul << 20));

    const int split = (ws_size >= (156ul << 20)) ? 8 : 4;

    // 1) x -> xb, xTb ; P -> Pt ; Wq/Wk/Wv -> bf16
    transpose_cast<<<dim3(DIM / 32, SEQ / 32, BATCH), 256, 0, stream>>>(
        x, xb, xTb, SEQ, DIM);
    transpose_cast<<<dim3(DIM / 32, DIM / 32, 1), 256, 0, stream>>>(
        P, nullptr, Ptb, DIM, DIM);
    cast3<<<dim3((int)(DD / 4 / 256), 3), 256, 0, stream>>>(
        Wq, Wk, Wv, Wqb, Wkb, Wvb, (int)(DD / 4));

    // 2) G_b = xT_b @ xT_b^T — lower-triangle tiles, split-K compact partials
    gemm_db<3, 128, true, false><<<dim3(36 * split * BATCH, 1, 1), 256, 0, stream>>>(
        xTb, xTb, regA, SEQ / split, split, SEQ, SEQ, DIM, SD, SD, 0);
    reduce_cast_tri<<<dim3(BATCH * 36 * 128 * 32 / 256), 256, 0, stream>>>(
        regA, Gb, split);
    sym_mirror<<<dim3(16, 28, BATCH), 256, 0, stream>>>(Gb);

    // 3) {U, W2T} split-K2: U = Wq@Wk^T ; W2T = Pt@Wv^T  (partials in regB)
    gemm_db<2, 64, false, false><<<dim3(16, 8, 4), 256, 0, stream>>>(
        Wqb, Wkb, regB, DIM / 2, 2, DIM, DIM, DIM, DD, DD, DD);
    reduce_cast_lin<<<dim3((int)(2 * DD / 4 / 256)), 256, 0, stream>>>(
        regB, Ub, 2, DD / 4);

    // 4) H_b = U @ G_b^T  (G symmetric)
    gemm_db<1, 64, false, false><<<dim3(16, 8, BATCH), 256, 0, stream>>>(
        Ub, Gb, Hb, DIM, 1, DIM, DIM, DIM, 0, DD, DD);

    // 5) Nt_b = W2T @ H_b^T + I   (residual folded in)
    gemm_db<1, 64, false, true><<<dim3(16, 8, BATCH), 256, 0, stream>>>(
        W2Tb, Hb, Ntb, DIM, 1, DIM, DIM, DIM, 0, DD, DD);

    // 6) out_b = xb_b @ Nt_b^T  (fp32 out, 256x256 8-wave pipeline)
    gemm_db256<<<dim3(DIM / 256, SEQ / 256, BATCH), 512, 0, stream>>>(
        xb, Ntb, out, DIM, DIM, DIM, DIM, SD, DD, SD);
}

// Round 12
// 174.806 us; speedup vs baseline: 6.9605x; 1.0112x over previous
//
#include <hip/hip_runtime.h>
#include <hip/hip_bf16.h>
#include <stdint.h>

// out = x + x * [ (Wq Wk^T) * (x^T x) * (Wv P) ]  ==  x @ (I + N),  N = U G W2
// Final GEMM: 256x256 8-wave 8-phase schedule (T3+T4: per-phase ds||stage||MFMA
// interleave, counted vmcnt(4), 2 barriers/phase). Gram/chain: proven pipeline.

#define BATCH 4
#define SEQ   4096
#define DIM   1024

#define TRI_SLICE 589824l       // 36 tiles * 128*128 floats per gram slice

typedef __bf16 bf16x8 __attribute__((ext_vector_type(8)));
typedef float f32x4 __attribute__((ext_vector_type(4)));

static __device__ __forceinline__ unsigned short f2bf(float f) {
    unsigned int u = __builtin_bit_cast(unsigned int, f);
    u += 0x7fff + ((u >> 16) & 1);              // RNE
    return (unsigned short)(u >> 16);
}

// ---------------------------------------------------------------------------
// 256x256-tile 8-phase bf16 MFMA GEMM: C = A @ Bt^T (fp32 out).
//  512 threads = 8 waves (2M x 4N), per-wave 128x64 output.
//  Per K-tile: 4 phases (kk2 x m-half), each {reads; stage-slot; bar;
//  lgkm(0); 16 MFMA; bar}. Stage A(t+1)@P0, B(t+2)@P3; vmcnt(4)@P3.
//  Grid: (N/256, M/256, BATCH); flattened nwg % 8 == 0. K/64 >= 2.
// ---------------------------------------------------------------------------
__global__ __launch_bounds__(512)
void gemm_8p(const unsigned short* __restrict__ Ag,
             const unsigned short* __restrict__ Btg,
             float* __restrict__ Cg,
             int K, int lda, int ldbt, int ldc,
             long sA, long sBt, long sC)
{
    __shared__ unsigned short As[2][256][64];
    __shared__ unsigned short Bs[2][256][64];

    const int gx = gridDim.x, gy = gridDim.y;
    const int nwg = gx * gy * gridDim.z;
    int id = blockIdx.x + gx * (blockIdx.y + gy * blockIdx.z);
    id = (id & 7) * (nwg >> 3) + (id >> 3);

    const int bx = id % gx;
    const int rest = id / gx;
    const int by = rest % gy;
    const int b = rest / gy;
    const long i0 = (long)by * 256;
    const long j0 = (long)bx * 256;

    const unsigned short* A  = Ag  + (long)b * sA;
    const unsigned short* Bt = Btg + (long)b * sBt;

    const int tid  = threadIdx.x;
    const int lane = tid & 63;
    const int w    = tid >> 6;          // wave 0..7
    const int wr   = w >> 2;            // 0..1  (M half)
    const int wc   = w & 3;             // 0..3  (N quarter)
    const int lrow = lane >> 3;         // 0..7
    const int lcol = lane & 7;          // 0..7 (16B granule)
    const int fr   = lane & 15;
    const int kg   = lane >> 4;         // 0..3
    const int scol = (lcol ^ lrow) * 8; // pre-swizzled global source chunk

    f32x4 acc[8][4] = {};
    const int nt = K / 64;

    auto stageA = [&](int t) {
        const int buf = t & 1;
        const long kk = (long)t * 64;
#pragma unroll
        for (int inst = 0; inst < 4; ++inst) {
            const int row = w * 32 + inst * 8;
            const unsigned short* src = A + (i0 + row + lrow) * lda + kk + scol;
            __builtin_amdgcn_global_load_lds(
                (const __attribute__((address_space(1))) void*)src,
                (__attribute__((address_space(3))) void*)&As[buf][row][0], 16, 0, 0);
        }
    };
    auto stageB = [&](int t) {
        const int buf = t & 1;
        const long kk = (long)t * 64;
#pragma unroll
        for (int inst = 0; inst < 4; ++inst) {
            const int row = w * 32 + inst * 8;
            const unsigned short* src = Bt + (j0 + row + lrow) * ldbt + kk + scol;
            __builtin_amdgcn_global_load_lds(
                (const __attribute__((address_space(1))) void*)src,
                (__attribute__((address_space(3))) void*)&Bs[buf][row][0], 16, 0, 0);
        }
    };

    // prologue: A(0), B(0), B(1); wait A(0)+B(0), leave B(1) in flight
    stageA(0); stageB(0); stageB(1);
    asm volatile("s_waitcnt vmcnt(4)" ::: "memory");
    __builtin_amdgcn_s_barrier();
    asm volatile("" ::: "memory");

    for (int t = 0; t < nt; ++t) {
        const int buf = t & 1;
        const int ch0 = (kg ^ (fr & 7)) * 8;        // kk2=0 swizzled chunk
        const int ch1 = ((4 + kg) ^ (fr & 7)) * 8;  // kk2=1

        // ---- P0: reads A[m0-3,k0] + B[k0]; stage A(t+1)
        bf16x8 af0[4], bf0[4];
#pragma unroll
        for (int m = 0; m < 4; ++m)
            af0[m] = *(const bf16x8*)&As[buf][wr * 128 + m * 16 + fr][ch0];
#pragma unroll
        for (int n = 0; n < 4; ++n)
            bf0[n] = *(const bf16x8*)&Bs[buf][wc * 64 + n * 16 + fr][ch0];
        if (t + 1 < nt) stageA(t + 1);   // into As[(t+1)&1], freed at P3(t-1)
        __builtin_amdgcn_s_barrier();
        asm volatile("s_waitcnt lgkmcnt(0)" ::: "memory");
        __builtin_amdgcn_sched_barrier(0);
        __builtin_amdgcn_s_setprio(1);
#pragma unroll
        for (int m = 0; m < 4; ++m)
#pragma unroll
            for (int n = 0; n < 4; ++n)
                acc[m][n] = __builtin_amdgcn_mfma_f32_16x16x32_bf16(
                    af0[m], bf0[n], acc[m][n], 0, 0, 0);
        __builtin_amdgcn_s_setprio(0);
        __builtin_amdgcn_s_barrier();
        asm volatile("" ::: "memory");

        // ---- P1: reads A[m4-7,k0]; reuse bf0
        bf16x8 af1[4];
#pragma unroll
        for (int m = 0; m < 4; ++m)
            af1[m] = *(const bf16x8*)&As[buf][wr * 128 + 64 + m * 16 + fr][ch0];
        __builtin_amdgcn_s_barrier();
        asm volatile("s_waitcnt lgkmcnt(0)" ::: "memory");
        __builtin_amdgcn_sched_barrier(0);
        __builtin_amdgcn_s_setprio(1);
#pragma unroll
        for (int m = 0; m < 4; ++m)
#pragma unroll
            for (int n = 0; n < 4; ++n)
                acc[4 + m][n] = __builtin_amdgcn_mfma_f32_16x16x32_bf16(
                    af1[m], bf0[n], acc[4 + m][n], 0, 0, 0);
        __builtin_amdgcn_s_setprio(0);
        __builtin_amdgcn_s_barrier();
        asm volatile("" ::: "memory");

        // ---- P2: reads A[m0-3,k1] + B[k1]
        bf16x8 af2[4], bf1[4];
#pragma unroll
        for (int m = 0; m < 4; ++m)
            af2[m] = *(const bf16x8*)&As[buf][wr * 128 + m * 16 + fr][ch1];
#pragma unroll
        for (int n = 0; n < 4; ++n)
            bf1[n] = *(const bf16x8*)&Bs[buf][wc * 64 + n * 16 + fr][ch1];
        __builtin_amdgcn_s_barrier();
        asm volatile("s_waitcnt lgkmcnt(0)" ::: "memory");
        __builtin_amdgcn_sched_barrier(0);
        __builtin_amdgcn_s_setprio(1);
#pragma unroll
        for (int m = 0; m < 4; ++m)
#pragma unroll
            for (int n = 0; n < 4; ++n)
                acc[m][n] = __builtin_amdgcn_mfma_f32_16x16x32_bf16(
                    af2[m], bf1[n], acc[m][n], 0, 0, 0);
        __builtin_amdgcn_s_setprio(0);
        __builtin_amdgcn_s_barrier();
        asm volatile("" ::: "memory");

        // ---- P3: reads A[m4-7,k1]; stage B(t+2) (B(t) fully read at P2);
        //          vmcnt(4) certifies A(t+1)+B(t+1) for next tile's P0
        bf16x8 af3[4];
#pragma unroll
        for (int m = 0; m < 4; ++m)
            af3[m] = *(const bf16x8*)&As[buf][wr * 128 + 64 + m * 16 + fr][ch1];
        if (t + 2 < nt) stageB(t + 2);   // into Bs[t&1], freed at P2's end-bar
        if (t < nt - 2) asm volatile("s_waitcnt vmcnt(4)" ::: "memory");
        else            asm volatile("s_waitcnt vmcnt(0)" ::: "memory");
        __builtin_amdgcn_s_barrier();
        asm volatile("s_waitcnt lgkmcnt(0)" ::: "memory");
        __builtin_amdgcn_sched_barrier(0);
        __builtin_amdgcn_s_setprio(1);
#pragma unroll
        for (int m = 0; m < 4; ++m)
#pragma unroll
            for (int n = 0; n < 4; ++n)
                acc[4 + m][n] = __builtin_amdgcn_mfma_f32_16x16x32_bf16(
                    af3[m], bf1[n], acc[4 + m][n], 0, 0, 0);
        __builtin_amdgcn_s_setprio(0);
        __builtin_amdgcn_s_barrier();
        asm volatile("" ::: "memory");
    }

    // ---- epilogue: C/D layout col = lane&15, row = (lane>>4)*4 + q
    float* C32 = Cg + (long)b * sC;
#pragma unroll
    for (int m = 0; m < 8; ++m) {
        const long rbase = i0 + wr * 128 + m * 16 + kg * 4;
#pragma unroll
        for (int n = 0; n < 4; ++n) {
            const long col = j0 + wc * 64 + n * 16 + fr;
#pragma unroll
            for (int q = 0; q < 4; ++q)
                C32[(rbase + q) * ldc + col] = acc[m][n][q];
        }
    }
}

// ---------------------------------------------------------------------------
// 128 x BN deep-pipelined bf16 MFMA GEMM (proven rounds 9-11) — gram + chain.
//  OUTMODE: 0 fp32 out; 1 bf16 out (+ADD_I); 2 fp32 slice partials;
//           3 TRI compact fp32 partial.
// ---------------------------------------------------------------------------
template<int OUTMODE, int BN, bool TRI, bool ADD_I>
__global__ __launch_bounds__(256)
void gemm_db(const unsigned short* __restrict__ Ag,
             const unsigned short* __restrict__ Btg,
             void* __restrict__ Cg,
             int K, int zdiv, int lda, int ldbt, int ldc,
             long sA, long sBt, long sC)
{
    constexpr int NF = BN / 32;             // B fragments per wave (2 or 4)
    __shared__ unsigned short As[2][128][64];
    __shared__ unsigned short Bs[2][BN][64];

    const int gx = gridDim.x, gy = gridDim.y;
    const int nwg = gx * gy * gridDim.z;
    int id = blockIdx.x + gx * (blockIdx.y + gy * blockIdx.z);
    id = (id & 7) * (nwg >> 3) + (id >> 3);

    int z, tlin = 0;
    long i0, j0;
    if (TRI) {
        z = id / 36;
        tlin = id % 36;
        int t = tlin, ti = 0;
        while (t > ti) { t -= ti + 1; ++ti; }
        i0 = (long)ti * 128;
        j0 = (long)t * 128;
    } else {
        const int bx = id % gx;
        const int rest = id / gx;
        const int by = rest % gy;
        z = rest / gy;
        i0 = (long)by * 128;
        j0 = (long)bx * BN;
    }
    const int b = z / zdiv;
    const long koff = (long)(z % zdiv) * K;

    const unsigned short* A  = Ag  + (long)b * sA  + koff;
    const unsigned short* Bt = Btg + (long)b * sBt + koff;

    const int tid  = threadIdx.x;
    const int lane = tid & 63;
    const int w    = tid >> 6;          // wave 0..3
    const int wr   = w >> 1, wc = w & 1;
    const int lrow = lane >> 3;         // 0..7
    const int lcol = lane & 7;          // 0..7 (16B granule)
    const int fr   = lane & 15;
    const int kg   = lane >> 4;         // 0..3
    const int scol = (lcol ^ lrow) * 8; // pre-swizzled global source chunk

    f32x4 acc[4][NF] = {};

    const int nt = K / 64;              // >= 2 always

    auto stage = [&](int t, int buf) {
        const long kk = (long)t * 64;
#pragma unroll
        for (int inst = 0; inst < 4; ++inst) {
            const int row = w * 32 + inst * 8;
            const unsigned short* srcA = A + (i0 + row + lrow) * lda + kk + scol;
            __builtin_amdgcn_global_load_lds(
                (const __attribute__((address_space(1))) void*)srcA,
                (__attribute__((address_space(3))) void*)&As[buf][row][0], 16, 0, 0);
        }
#pragma unroll
        for (int inst = 0; inst < NF; ++inst) {
            const int row = w * (8 * NF) + inst * 8;
            const unsigned short* srcB = Bt + (j0 + row + lrow) * ldbt + kk + scol;
            __builtin_amdgcn_global_load_lds(
                (const __attribute__((address_space(1))) void*)srcB,
                (__attribute__((address_space(3))) void*)&Bs[buf][row][0], 16, 0, 0);
        }
    };

    stage(0, 0);
    stage(1, 1);

    for (int t = 0; t < nt; ++t) {
        const int buf = t & 1;
        if (t < nt - 1) {
            if constexpr (BN == 128)
                asm volatile("s_waitcnt vmcnt(8)" ::: "memory");
            else
                asm volatile("s_waitcnt vmcnt(6)" ::: "memory");
        } else {
            asm volatile("s_waitcnt vmcnt(0)" ::: "memory");
        }
        __builtin_amdgcn_s_barrier();
        asm volatile("" ::: "memory");

        bf16x8 af0[4], bf0[NF], af1[4], bf1[NF];
        const int ch0 = (kg ^ (fr & 7)) * 8;
        const int ch1 = ((4 + kg) ^ (fr & 7)) * 8;
#pragma unroll
        for (int m = 0; m < 4; ++m)
            af0[m] = *(const bf16x8*)&As[buf][wr * 64 + m * 16 + fr][ch0];
#pragma unroll
        for (int n = 0; n < NF; ++n)
            bf0[n] = *(const bf16x8*)&Bs[buf][wc * (BN / 2) + n * 16 + fr][ch0];
#pragma unroll
        for (int m = 0; m < 4; ++m)
            af1[m] = *(const bf16x8*)&As[buf][wr * 64 + m * 16 + fr][ch1];
#pragma unroll
        for (int n = 0; n < NF; ++n)
            bf1[n] = *(const bf16x8*)&Bs[buf][wc * (BN / 2) + n * 16 + fr][ch1];

        __builtin_amdgcn_s_setprio(1);
#pragma unroll
        for (int m = 0; m < 4; ++m)
#pragma unroll
            for (int n = 0; n < NF; ++n)
                acc[m][n] = __builtin_amdgcn_mfma_f32_16x16x32_bf16(
                    af0[m], bf0[n], acc[m][n], 0, 0, 0);
        __builtin_amdgcn_s_setprio(0);

        asm volatile("s_waitcnt lgkmcnt(0)" ::: "memory");
        __builtin_amdgcn_sched_barrier(0);
        __builtin_amdgcn_s_barrier();
        asm volatile("" ::: "memory");

        if (t + 2 < nt) stage(t + 2, buf);
        __builtin_amdgcn_sched_barrier(0);

        __builtin_amdgcn_s_setprio(1);
#pragma unroll
        for (int m = 0; m < 4; ++m)
#pragma unroll
            for (int n = 0; n < NF; ++n)
                acc[m][n] = __builtin_amdgcn_mfma_f32_16x16x32_bf16(
                    af1[m], bf1[n], acc[m][n], 0, 0, 0);
        __builtin_amdgcn_s_setprio(0);
    }

    if (OUTMODE == 3) {
        float* Cp = (float*)Cg + (long)z * TRI_SLICE + (long)tlin * 16384;
#pragma unroll
        for (int m = 0; m < 4; ++m) {
            const int lrb = wr * 64 + m * 16 + kg * 4;
#pragma unroll
            for (int n = 0; n < NF; ++n) {
                const int lc = wc * (BN / 2) + n * 16 + fr;
#pragma unroll
                for (int q = 0; q < 4; ++q)
                    Cp[(lrb + q) * 128 + lc] = acc[m][n][q];
            }
        }
        return;
    }

    unsigned short* C16 = (OUTMODE == 1) ? ((unsigned short*)Cg + (long)b * sC) : nullptr;
    float*          C32 = (OUTMODE == 0) ? ((float*)Cg + (long)b * sC)
                        : (OUTMODE == 2) ? ((float*)Cg + (long)z * sC) : nullptr;
#pragma unroll
    for (int m = 0; m < 4; ++m) {
        const long rbase = i0 + wr * 64 + m * 16 + kg * 4;
#pragma unroll
        for (int n = 0; n < NF; ++n) {
            const long col = j0 + wc * (BN / 2) + n * 16 + fr;
#pragma unroll
            for (int q = 0; q < 4; ++q) {
                const long r = rbase + q;
                float v = acc[m][n][q];
                if (ADD_I && r == col) v += 1.0f;
                if (OUTMODE == 1) C16[r * ldc + col] = f2bf(v);
                else              C32[r * ldc + col] = v;
            }
        }
    }
}

// ---------------------------------------------------------------------------
__global__ __launch_bounds__(256)
void reduce_cast_tri(const float* __restrict__ part, unsigned short* __restrict__ outG,
                     int split)
{
    const long DD = (long)DIM * DIM;
    int id = blockIdx.x * 256 + threadIdx.x;
    const int b  = id / 147456;          // 36*128*32
    int rem      = id % 147456;
    const int tlin = rem / 4096;
    const int rr = rem % 4096;
    const int r  = rr >> 5;
    const int c4 = rr & 31;
    int t = tlin, ti = 0;
    while (t > ti) { t -= ti + 1; ++ti; }
    const long off = (long)tlin * 16384 + r * 128 + c4 * 4;

    float4 s = make_float4(0.f, 0.f, 0.f, 0.f);
    for (int sp = 0; sp < split; ++sp) {
        float4 v = *(const float4*)&part[(long)(b * split + sp) * TRI_SLICE + off];
        s.x += v.x; s.y += v.y; s.z += v.z; s.w += v.w;
    }
    ushort4 o;
    o.x = f2bf(s.x); o.y = f2bf(s.y); o.z = f2bf(s.z); o.w = f2bf(s.w);
    *(ushort4*)&outG[b * DD + ((long)ti * 128 + r) * DIM + (long)t * 128 + c4 * 4] = o;
}

__global__ __launch_bounds__(256)
void reduce_cast_lin(const float* __restrict__ part, unsigned short* __restrict__ out,
                     int split, long len4)
{
    long i = (long)blockIdx.x * 256 + threadIdx.x;
    const long slab = i / len4;
    const long r = i % len4;
    float4 s = make_float4(0.f, 0.f, 0.f, 0.f);
    for (int sp = 0; sp < split; ++sp) {
        float4 v = ((const float4*)part)[(slab * split + sp) * len4 + r];
        s.x += v.x; s.y += v.y; s.z += v.z; s.w += v.w;
    }
    ushort4 o;
    o.x = f2bf(s.x); o.y = f2bf(s.y); o.z = f2bf(s.z); o.w = f2bf(s.w);
    ((ushort4*)out)[i] = o;
}

__global__ __launch_bounds__(256)
void sym_mirror(unsigned short* __restrict__ G)
{
    __shared__ unsigned short t[32][36];
    const long DD = (long)DIM * DIM;
    unsigned short* Gb = G + (long)blockIdx.z * DD;

    int u = blockIdx.y;
    int tj = 1;
    while (u >= tj) { u -= tj; ++tj; }
    const int ti = u;                    // ti < tj

    const int sr = blockIdx.x >> 2;
    const int sc = blockIdx.x & 3;
    const int row = threadIdx.x >> 3;
    const int cid = threadIdx.x & 7;

    const long srow = (long)tj * 128 + sr * 32 + row;
    const long scol = (long)ti * 128 + sc * 32 + cid * 4;
    ushort4 v = *(const ushort4*)&Gb[srow * DIM + scol];
    t[row][cid * 4 + 0] = v.x; t[row][cid * 4 + 1] = v.y;
    t[row][cid * 4 + 2] = v.z; t[row][cid * 4 + 3] = v.w;
    __syncthreads();

    const long drow = (long)ti * 128 + sc * 32 + row;
    const long dcol = (long)tj * 128 + sr * 32 + cid * 4;
    ushort4 o;
    o.x = t[cid * 4 + 0][row];
    o.y = t[cid * 4 + 1][row];
    o.z = t[cid * 4 + 2][row];
    o.w = t[cid * 4 + 3][row];
    *(ushort4*)&Gb[drow * DIM + dcol] = o;
}

__global__ __launch_bounds__(256)
void transpose_cast(const float* __restrict__ src, unsigned short* __restrict__ dst,
                    unsigned short* __restrict__ dstT, int R, int C)
{
    __shared__ unsigned short t[32][33];
    const int b = blockIdx.z;
    const long base = (long)b * R * C;
    const int r0 = blockIdx.y * 32;
    const int c0 = blockIdx.x * 32;
    const int row = threadIdx.x >> 3;
    const int cid = threadIdx.x & 7;

    float4 v = *(const float4*)&src[base + (long)(r0 + row) * C + c0 + cid * 4];
    ushort4 h;
    h.x = f2bf(v.x); h.y = f2bf(v.y); h.z = f2bf(v.z); h.w = f2bf(v.w);
    if (dst) *(ushort4*)&dst[base + (long)(r0 + row) * C + c0 + cid * 4] = h;
    t[row][cid * 4 + 0] = h.x; t[row][cid * 4 + 1] = h.y;
    t[row][cid * 4 + 2] = h.z; t[row][cid * 4 + 3] = h.w;
    __syncthreads();

    ushort4 o;
    o.x = t[cid * 4 + 0][row];
    o.y = t[cid * 4 + 1][row];
    o.z = t[cid * 4 + 2][row];
    o.w = t[cid * 4 + 3][row];
    *(ushort4*)&dstT[base + (long)(c0 + row) * R + r0 + cid * 4] = o;
}

__global__ __launch_bounds__(256)
void cast3(const float* __restrict__ s0, const float* __restrict__ s1,
           const float* __restrict__ s2, unsigned short* __restrict__ d0,
           unsigned short* __restrict__ d1, unsigned short* __restrict__ d2, int n4)
{
    const float* s = (blockIdx.y == 0) ? s0 : (blockIdx.y == 1) ? s1 : s2;
    unsigned short* d = (blockIdx.y == 0) ? d0 : (blockIdx.y == 1) ? d1 : d2;
    int i = blockIdx.x * 256 + threadIdx.x;
    if (i >= n4) return;
    float4 v = ((const float4*)s)[i];
    ushort4 o;
    o.x = f2bf(v.x); o.y = f2bf(v.y); o.z = f2bf(v.z); o.w = f2bf(v.w);
    ((ushort4*)d)[i] = o;
}

// ---------------------------------------------------------------------------
extern "C" void kernel_launch(void* const* d_in, const int* in_sizes, int n_in,
                              void* d_out, int out_size, void* d_ws, size_t ws_size,
                              hipStream_t stream)
{
    const float* x  = (const float*)d_in[0];
    const float* Wq = (const float*)d_in[1];
    const float* Wk = (const float*)d_in[2];
    const float* Wv = (const float*)d_in[3];
    const float* P  = (const float*)d_in[4];
    float* out = (float*)d_out;

    const long DD = (long)DIM * DIM;
    const long SD = (long)SEQ * DIM;

    // workspace layout (MiB offsets) — identical to rounds 7-11 (proven):
    //   [0,32) xb | [32,64) xTb -> Hb[32,40) Ntb[40,48) regB[48,64)
    //   [64,72) Gb | [72,84) weights | [84,84+split*9) regA gram partials
    uint8_t* ws = (uint8_t*)d_ws;
    unsigned short* xb   = (unsigned short*)(ws);
    unsigned short* xTb  = (unsigned short*)(ws + (32ul << 20));
    unsigned short* Hb   = (unsigned short*)(ws + (32ul << 20));
    unsigned short* Ntb  = (unsigned short*)(ws + (40ul << 20));
    float*          regB = (float*)(ws + (48ul << 20));
    unsigned short* Gb   = (unsigned short*)(ws + (64ul << 20));
    unsigned short* Wqb  = (unsigned short*)(ws + (72ul << 20));
    unsigned short* Ptb  = (unsigned short*)(ws + (74ul << 20));
    unsigned short* Wkb  = (unsigned short*)(ws + (76ul << 20));
    unsigned short* Wvb  = (unsigned short*)(ws + (78ul << 20));
    unsigned short* Ub   = (unsigned short*)(ws + (80ul << 20));
    unsigned short* W2Tb = (unsigned short*)(ws + (82ul << 20));
    float*          regA = (float*)(ws + (84ul << 20));

    const int split = (ws_size >= (156ul << 20)) ? 8 : 4;

    // 1) x -> xb, xTb ; P -> Pt ; Wq/Wk/Wv -> bf16
    transpose_cast<<<dim3(DIM / 32, SEQ / 32, BATCH), 256, 0, stream>>>(
        x, xb, xTb, SEQ, DIM);
    transpose_cast<<<dim3(DIM / 32, DIM / 32, 1), 256, 0, stream>>>(
        P, nullptr, Ptb, DIM, DIM);
    cast3<<<dim3((int)(DD / 4 / 256), 3), 256, 0, stream>>>(
        Wq, Wk, Wv, Wqb, Wkb, Wvb, (int)(DD / 4));

    // 2) G_b = xT_b @ xT_b^T — lower-triangle tiles, split-K compact partials
    gemm_db<3, 128, true, false><<<dim3(36 * split * BATCH, 1, 1), 256, 0, stream>>>(
        xTb, xTb, regA, SEQ / split, split, SEQ, SEQ, DIM, SD, SD, 0);
    reduce_cast_tri<<<dim3(BATCH * 36 * 128 * 32 / 256), 256, 0, stream>>>(
        regA, Gb, split);
    sym_mirror<<<dim3(16, 28, BATCH), 256, 0, stream>>>(Gb);

    // 3) {U, W2T} split-K2: U = Wq@Wk^T ; W2T = Pt@Wv^T  (partials in regB)
    gemm_db<2, 64, false, false><<<dim3(16, 8, 4), 256, 0, stream>>>(
        Wqb, Wkb, regB, DIM / 2, 2, DIM, DIM, DIM, DD, DD, DD);
    reduce_cast_lin<<<dim3((int)(2 * DD / 4 / 256)), 256, 0, stream>>>(
        regB, Ub, 2, DD / 4);

    // 4) H_b = U @ G_b^T  (G symmetric)
    gemm_db<1, 64, false, false><<<dim3(16, 8, BATCH), 256, 0, stream>>>(
        Ub, Gb, Hb, DIM, 1, DIM, DIM, DIM, 0, DD, DD);

    // 5) Nt_b = W2T @ H_b^T + I   (residual folded in)
    gemm_db<1, 64, false, true><<<dim3(16, 8, BATCH), 256, 0, stream>>>(
        W2Tb, Hb, Ntb, DIM, 1, DIM, DIM, DIM, 0, DD, DD);

    // 6) out_b = xb_b @ Nt_b^T  (fp32 out, 256x256 8-phase pipeline)
    gemm_8p<<<dim3(DIM / 256, SEQ / 256, BATCH), 512, 0, stream>>>(
        xb, Ntb, out, DIM, DIM, DIM, DIM, SD, DD, SD);
}